// Round 4
// baseline (417.445 us; speedup 1.0000x reference)
//
#include <hip/hip_runtime.h>
#include <hip/hip_bf16.h>

#define N_NODESC 50000
#define N_EDGESC 1600000
#define NUM_GRAPHSC 64
#define SLICE_W 6250          // 50000 / 8
#define BCAP 230000           // per-slice bucket capacity
#define CH_EPB 2048           // edges per block in cvt_bucket
#define EPB2 8192             // entries per chunk in subpart
#define SUBW 196              // nodes per sub-bucket
#define NSUB 32               // sub-buckets per slice (8*32=256 total)
#define SBCAP 8192            // per-sub-bucket capacity

typedef __hip_bfloat16 bf16;
typedef short short8 __attribute__((ext_vector_type(8)));
typedef float floatx4 __attribute__((ext_vector_type(4)));

__device__ __forceinline__ float ldf(const void* p, long i, int fp32) {
    return fp32 ? ((const float*)p)[i] : __bfloat162float(((const bf16*)p)[i]);
}
__device__ __forceinline__ short f2s(float v) {
    bf16 h = __float2bfloat16(v);
    return *(short*)&h;
}
__device__ __forceinline__ unsigned pack2(float lo, float hi) {
    bf16 a = __float2bfloat16(lo), b = __float2bfloat16(hi);
    unsigned ua = *(unsigned short*)&a, ub = *(unsigned short*)&b;
    return (ub << 16) | ua;
}
__device__ __forceinline__ float ulo(unsigned u) { return __uint_as_float(u << 16); }
__device__ __forceinline__ float uhi(unsigned u) { return __uint_as_float(u & 0xffff0000u); }

// ---------------- dtype detection ----------------
__global__ void detect_k(const void* __restrict__ prot,
                         const void* __restrict__ eidx,
                         int* __restrict__ flags) {
    if (blockIdx.x == 0 && threadIdx.x == 0) {
        const bf16* pb = (const bf16*)prot;
        int sane = 0;
        for (int i = 0; i < 64; ++i) {
            float a = fabsf(__bfloat162float(pb[2 * i]));
            if (a > 1e-8f && a < 1e4f) sane++;
        }
        flags[0] = (sane >= 48) ? 0 : 1;
        const unsigned* u = (const unsigned*)eidx;
        int zhi = 0;
        for (int i = 0; i < 32; ++i)
            if (u[2 * i + 1] == 0u) zhi++;
        flags[1] = (zhi >= 30) ? 1 : 0;
    }
}

// ---------------- fused: weight prep + workspace zero + batch cvt ----------------
__global__ __launch_bounds__(256) void prep2_k(const void* __restrict__ W1,
                                               const void* __restrict__ W2,
                                               const int* __restrict__ flags,
                                               short* __restrict__ w1f,
                                               float* __restrict__ w1r,
                                               short* __restrict__ w2f,
                                               int* __restrict__ zreg, int nzero, int nzblk,
                                               const void* __restrict__ batch,
                                               int* __restrict__ b32) {
    const int fp32 = flags[0];
    const int b = blockIdx.x, tid = threadIdx.x;
    if (b < 64) {
        int idx = b * 256 + tid;                    // 16384
        int kp = idx >> 7, n = idx & 127;
        int krow = kp < 64 ? kp : 66 + (kp - 64);
        float v = ldf(W1, (long)krow * 128 + n, fp32);
        int c = n >> 4, nn = n & 15, t = kp >> 5, q = (kp >> 3) & 3, j = kp & 7;
        w1f[(((c * 4 + t) * 4 + q) * 16 + nn) * 8 + j] = f2s(v);
    } else if (b == 64) {
        int which = tid >> 7, n = tid & 127;        // W1 rows 64,65 (spatial)
        w1r[which * 128 + n] = ldf(W1, (long)(64 + which) * 128 + n, fp32);
    } else if (b < 97) {
        int idx = (b - 65) * 256 + tid;             // 8192
        int k = idx >> 6, n = idx & 63;
        float v = ldf(W2, (long)k * 64 + n, fp32);
        int c = n >> 4, nn = n & 15, t = k >> 5, q = (k >> 3) & 3, j = k & 7;
        w2f[(((c * 4 + t) * 4 + q) * 16 + nn) * 8 + j] = f2s(v);
    } else if (b < 97 + nzblk) {
        int i = (b - 97) * 256 + tid;
        if (i < nzero) zreg[i] = 0;
    } else {
        const int i64f = flags[1];
        int i = (b - 97 - nzblk) * 256 + tid;
        if (i < N_NODESC)
            b32[i] = i64f ? (int)((const long long*)batch)[i] : ((const int*)batch)[i];
    }
}

// ---------------- convert + LDS-compacted slice partition ----------------
__global__ __launch_bounds__(256) void cvt_bucket_k(const void* __restrict__ eidx,
                                                    const int* __restrict__ flags,
                                                    int* __restrict__ bcur,
                                                    unsigned* __restrict__ bucket) {
    const int i64f = flags[1];
    const int tid = threadIdx.x;
    const long e0 = (long)blockIdx.x * CH_EPB;
    __shared__ int cnt[9];
    __shared__ int gbase[8];
    __shared__ int cur[8];
    __shared__ unsigned buf[CH_EPB];
    if (tid < 8) cnt[tid] = 0;
    __syncthreads();
    unsigned ev[8];
    int bk[8];
    #pragma unroll
    for (int i = 0; i < 8; ++i) {
        long e = e0 + i * 256 + tid;
        bk[i] = -1;
        if (e < N_EDGESC) {
            int s, d;
            if (i64f) {
                s = (int)((const long long*)eidx)[e];
                d = (int)((const long long*)eidx)[N_EDGESC + e];
            } else {
                s = ((const int*)eidx)[e];
                d = ((const int*)eidx)[N_EDGESC + e];
            }
            int b = d / SLICE_W;
            bk[i] = b;
            ev[i] = (unsigned)s | ((unsigned)(d - b * SLICE_W) << 16);
            atomicAdd(&cnt[b], 1);
        }
    }
    __syncthreads();
    if (tid == 0) {
        int run = 0;
        #pragma unroll
        for (int b = 0; b < 8; ++b) { int c = cnt[b]; cnt[b] = run; run += c; }
        cnt[8] = run;
    }
    __syncthreads();
    if (tid < 8) {
        int c = cnt[tid + 1] - cnt[tid];
        gbase[tid] = c ? atomicAdd(&bcur[tid], c) : 0;
        cur[tid] = cnt[tid];
    }
    __syncthreads();
    #pragma unroll
    for (int i = 0; i < 8; ++i) {
        if (bk[i] >= 0) {
            int p = atomicAdd(&cur[bk[i]], 1);
            buf[p] = ev[i];
        }
    }
    __syncthreads();
    const int total = cnt[8];
    for (int p = tid; p < total; p += 256) {
        int b = 7;
        #pragma unroll
        for (int q = 6; q >= 0; --q)
            if (p < cnt[q + 1]) b = q;
        bucket[(long)b * BCAP + gbase[b] + (p - cnt[b])] = buf[p];
    }
}

// ---------------- sub-partition: slice bucket -> 32 sub-buckets of 196 nodes ----------------
__global__ __launch_bounds__(256) void subpart_k(const unsigned* __restrict__ bucket,
                                                 const int* __restrict__ bcur,
                                                 int* __restrict__ scnt,
                                                 unsigned* __restrict__ bucket2) {
    const int slice = blockIdx.x & 7;
    const int blk = blockIdx.x >> 3;   // 0..31
    const int tid = threadIdx.x;
    const int cnt = bcur[slice];
    const unsigned* B = bucket + (long)slice * BCAP;
    __shared__ unsigned buf[EPB2];
    __shared__ int cnt2[NSUB + 1], gbase[NSUB], cur[NSUB];
    for (int start = blk * EPB2; start < cnt; start += 32 * EPB2) {
        const int csize = min(EPB2, cnt - start);
        if (tid < NSUB) cnt2[tid] = 0;
        __syncthreads();
        for (int i = tid; i < csize; i += 256) {
            unsigned v = B[start + i];
            atomicAdd(&cnt2[(v >> 16) / SUBW], 1);
        }
        __syncthreads();
        if (tid == 0) {
            int run = 0;
            #pragma unroll
            for (int s = 0; s < NSUB; ++s) { int c = cnt2[s]; cnt2[s] = run; run += c; }
            cnt2[NSUB] = run;
        }
        __syncthreads();
        if (tid < NSUB) {
            int c = cnt2[tid + 1] - cnt2[tid];
            gbase[tid] = c ? atomicAdd(&scnt[slice * NSUB + tid], c) : 0;
            cur[tid] = cnt2[tid];
        }
        __syncthreads();
        for (int i = tid; i < csize; i += 256) {
            unsigned v = B[start + i];
            int off = (int)(v >> 16);
            int sub = off / SUBW;
            unsigned nv = (v & 0xffffu) | ((unsigned)(off - sub * SUBW) << 16);
            int p = atomicAdd(&cur[sub], 1);
            buf[p] = nv;
        }
        __syncthreads();
        const int total = cnt2[NSUB];
        for (int p = tid; p < total; p += 256) {
            int lo = 0, hi = NSUB;
            while (hi - lo > 1) { int mid = (lo + hi) >> 1; if (p >= cnt2[mid]) lo = mid; else hi = mid; }
            bucket2[((long)slice * NSUB + lo) * SBCAP + gbase[lo] + (p - cnt2[lo])] = buf[p];
        }
        __syncthreads();
    }
}

// ---------------- fused CSR build: histogram + decoupled-lookback scan + scatter ----------------
// One block per sub-bucket (256 blocks == 256 scan tiles, node-contiguous, all
// resident on 256 CUs -> spin-safe). state[sb] packs flag(2b)|value(30b):
// 0 = unpublished, 1 = aggregate, 2 = inclusive prefix.
__global__ __launch_bounds__(256) void csr_k(const unsigned* __restrict__ bucket2,
                                             const int* __restrict__ scnt,
                                             int* __restrict__ state,
                                             int* __restrict__ row_start,
                                             unsigned short* __restrict__ col) {
    const int sb = blockIdx.x;
    const int slice = sb >> 5, sub = sb & 31;
    const int tid = threadIdx.x;
    const int lane = tid & 63;
    const int cnt = scnt[sb];
    const unsigned* B = bucket2 + (long)sb * SBCAP;
    __shared__ int lh[SUBW];
    __shared__ int sc[256];
    __shared__ int sprefix_sh;
    const int width = min(SUBW, SLICE_W - sub * SUBW);
    const int nodebase = slice * SLICE_W + sub * SUBW;
    for (int i = tid; i < SUBW; i += 256) lh[i] = 0;
    __syncthreads();
    for (int e = tid; e < cnt; e += 256) atomicAdd(&lh[B[e] >> 16], 1);
    __syncthreads();
    const int myc = (tid < SUBW) ? lh[tid] : 0;
    sc[tid] = myc;
    __syncthreads();
    for (int off = 1; off < 256; off <<= 1) {
        int t = (tid >= off) ? sc[tid - off] : 0;
        __syncthreads();
        sc[tid] += t;
        __syncthreads();
    }
    const int total = sc[255];
    if (tid == 0)
        __hip_atomic_store(&state[sb], (int)((1u << 30) | (unsigned)total),
                           __ATOMIC_RELEASE, __HIP_MEMORY_SCOPE_AGENT);
    if (tid < 64) {
        int prefix = 0;
        if (sb > 0) {
            int base = sb;
            for (;;) {
                int t = base - 1 - lane;
                int v = 0;
                if (t >= 0) {
                    for (;;) {
                        v = __hip_atomic_load(&state[t], __ATOMIC_ACQUIRE,
                                              __HIP_MEMORY_SCOPE_AGENT);
                        if ((unsigned)v >= (1u << 30)) break;
                        __builtin_amdgcn_s_sleep(1);
                    }
                }
                int flag = (int)(((unsigned)v) >> 30);
                int val = v & 0x3fffffff;
                unsigned long long pmask = __ballot(flag == 2 && t >= 0);
                int stop_tid = pmask ? (__ffsll((long long)pmask) - 1) : 64;
                int contrib = 0;
                if (t >= 0 && lane <= stop_tid) contrib = val;
                #pragma unroll
                for (int off = 32; off; off >>= 1) contrib += __shfl_xor(contrib, off, 64);
                prefix += contrib;
                if (pmask || base <= 64) break;
                base -= 64;
            }
        }
        if (tid == 0) {
            sprefix_sh = prefix;
            __hip_atomic_store(&state[sb],
                               (int)((2u << 30) | (unsigned)(prefix + total)),
                               __ATOMIC_RELEASE, __HIP_MEMORY_SCOPE_AGENT);
        }
    }
    __syncthreads();
    const int sprefix = sprefix_sh;
    if (tid < width) row_start[nodebase + tid] = sprefix + sc[tid] - myc;
    if (sb == 255 && tid == 0) row_start[N_NODESC] = sprefix + total;
    if (tid < SUBW) lh[tid] = sprefix + sc[tid] - myc;   // cursor
    __syncthreads();
    for (int e = tid; e < cnt; e += 256) {
        unsigned v = B[e];
        int pos = atomicAdd(&lh[v >> 16], 1);
        col[pos] = (unsigned short)(v & 0xffffu);
    }
}

// ---------------- Layer 1 GEMM via MFMA + fused logits (head-split outputs) ----------------

__global__ __launch_bounds__(256) void gemm1_k(
        const void* __restrict__ prot, const void* __restrict__ sp,
        const void* __restrict__ lri,
        const short* __restrict__ w1f, const float* __restrict__ w1r,
        const void* __restrict__ as1, const void* __restrict__ ad1,
        const int* __restrict__ flags,
        short* __restrict__ xph0, short* __restrict__ xph1,
        float* __restrict__ alsrc, float* __restrict__ aldst) {
    const int fp32 = flags[0];
    const int tid = threadIdx.x;
    const int nb = blockIdx.x * 32;
    __shared__ __align__(16) short xs[32][136];   // K order: prot 0..63, lri 0..63
    __shared__ float xsp[32][2];                  // spatial remainder
    __shared__ float sredc[32][8], dredc[32][8];  // [row][col-block]

    if (!fp32) {
        #pragma unroll
        for (int i = 0; i < 2; ++i) {
            int cidx = i * 256 + tid;             // 512 chunks of 8 shorts
            int r = cidx >> 4, cc = cidx & 15;
            int g = nb + r;
            short8 v = (short8){0, 0, 0, 0, 0, 0, 0, 0};
            if (g < N_NODESC) {
                const short* srcp = (cc < 8)
                    ? (const short*)prot + (long)g * 64 + cc * 8
                    : (const short*)lri + (long)g * 64 + (cc - 8) * 8;
                v = *(const short8*)srcp;
            }
            *(short8*)&xs[r][cc * 8] = v;
        }
    } else {
        #pragma unroll
        for (int i = 0; i < 16; ++i) {
            int idx = i * 256 + tid;
            int r = idx >> 7, k = idx & 127;
            int g = nb + r;
            float v = 0.f;
            if (g < N_NODESC)
                v = (k < 64) ? ((const float*)prot)[(long)g * 64 + k]
                             : ((const float*)lri)[(long)g * 64 + (k - 64)];
            xs[r][k] = f2s(v);
        }
    }
    if (tid < 64) {
        int r = tid >> 1, which = tid & 1;
        int g = nb + r;
        xsp[r][which] = (g < N_NODESC) ? ldf(sp, (long)g * 2 + which, fp32) : 0.f;
    }
    __syncthreads();

    const int wid = tid >> 6, lane = tid & 63;
    const int quad = lane >> 4, l16 = lane & 15;
    floatx4 acc[2][2];
    #pragma unroll
    for (int a = 0; a < 2; ++a)
        #pragma unroll
        for (int b = 0; b < 2; ++b) acc[a][b] = (floatx4){0.f, 0.f, 0.f, 0.f};

    const int c0 = 2 * wid;
    #pragma unroll
    for (int t = 0; t < 4; ++t) {
        short8 a0 = *(const short8*)&xs[l16][t * 32 + quad * 8];
        short8 a1 = *(const short8*)&xs[16 + l16][t * 32 + quad * 8];
        short8 b0 = *(const short8*)&w1f[(((c0 * 4 + t) * 4 + quad) * 16 + l16) * 8];
        short8 b1 = *(const short8*)&w1f[((((c0 + 1) * 4 + t) * 4 + quad) * 16 + l16) * 8];
        acc[0][0] = __builtin_amdgcn_mfma_f32_16x16x32_bf16(a0, b0, acc[0][0], 0, 0, 0);
        acc[0][1] = __builtin_amdgcn_mfma_f32_16x16x32_bf16(a0, b1, acc[0][1], 0, 0, 0);
        acc[1][0] = __builtin_amdgcn_mfma_f32_16x16x32_bf16(a1, b0, acc[1][0], 0, 0, 0);
        acc[1][1] = __builtin_amdgcn_mfma_f32_16x16x32_bf16(a1, b1, acc[1][1], 0, 0, 0);
    }
    #pragma unroll
    for (int ci = 0; ci < 2; ++ci) {
        int colg = (c0 + ci) * 16 + l16;
        float w0 = w1r[colg], w1v = w1r[128 + colg];
        float asv = ldf(as1, colg, fp32), adv = ldf(ad1, colg, fp32);
        short* xpd = (colg < 64) ? xph0 : xph1;
        const int cc = colg & 63;
        #pragma unroll
        for (int rt = 0; rt < 2; ++rt) {
            float sv[4], dv[4];
            #pragma unroll
            for (int reg = 0; reg < 4; ++reg) {
                int row = rt * 16 + quad * 4 + reg;
                int g = nb + row;
                float v = acc[rt][ci][reg] + xsp[row][0] * w0 + xsp[row][1] * w1v;
                if (g < N_NODESC) xpd[(long)g * 64 + cc] = f2s(v);
                sv[reg] = v * asv;
                dv[reg] = v * adv;
            }
            #pragma unroll
            for (int off = 1; off < 16; off <<= 1) {
                #pragma unroll
                for (int reg = 0; reg < 4; ++reg) {
                    sv[reg] += __shfl_xor(sv[reg], off, 64);
                    dv[reg] += __shfl_xor(dv[reg], off, 64);
                }
            }
            if (l16 == 0) {
                #pragma unroll
                for (int reg = 0; reg < 4; ++reg) {
                    int row = rt * 16 + quad * 4 + reg;
                    sredc[row][c0 + ci] = sv[reg];
                    dredc[row][c0 + ci] = dv[reg];
                }
            }
        }
    }
    __syncthreads();
    if (tid < 64) {
        int r = tid >> 1, h = tid & 1;
        int g = nb + r;
        if (g < N_NODESC) {
            alsrc[(long)h * N_NODESC + g] = sredc[r][4 * h] + sredc[r][4 * h + 1] +
                                            sredc[r][4 * h + 2] + sredc[r][4 * h + 3];
            aldst[(long)h * N_NODESC + g] = dredc[r][4 * h] + dredc[r][4 * h + 1] +
                                            dredc[r][4 * h + 2] + dredc[r][4 * h + 3];
        }
    }
}

// ---------------- Layer 1 aggregation: PER-HEAD pass (6.4MB working set) ----------------
// Lane roles: e = lane>>3 (8 edges per pass), c = lane&7 covers 16B (8 cols)
// of the 128B per-head xp row. Merge with shfl_xor(8|16|32); self seeded e==0.
// 50000 = 4*12500 exactly -> no invalid nodes.

__global__ __launch_bounds__(256) void agg1h_k(
        const int* __restrict__ row_start, const unsigned short* __restrict__ col,
        const short* __restrict__ xph, const float* __restrict__ alsh,
        const float* __restrict__ aldh, const void* __restrict__ b1,
        const int* __restrict__ flags, int head, unsigned* __restrict__ h1b32) {
    const int fp32 = flags[0];
    const int wid = threadIdx.x >> 6;
    const int lane = threadIdx.x & 63;
    const int n = blockIdx.x * 4 + wid;
    __shared__ float2 pbuf[4][64];
    float2* mybuf = pbuf[wid];
    const int e = lane >> 3;
    const int c = lane & 7;
    const char* xpb = (const char*)xph;
    const int c16 = c * 16;
    const float ad = aldh[n];
    float e0 = alsh[n] + ad;
    e0 = e0 > 0.f ? e0 : 0.2f * e0;
    const float pself = __expf(e0);
    const float pinit = e == 0 ? pself : 0.f;
    uint4 us = *(const uint4*)(xpb + (long)n * 128 + c16);
    float acc0 = pinit * ulo(us.x), acc1 = pinit * uhi(us.x);
    float acc2 = pinit * ulo(us.y), acc3 = pinit * uhi(us.y);
    float acc4 = pinit * ulo(us.z), acc5 = pinit * uhi(us.z);
    float acc6 = pinit * ulo(us.w), acc7 = pinit * uhi(us.w);
    float lp = 0.f;
    const int beg = row_start[n], end = row_start[n + 1];
    for (int base = beg; base < end; base += 64) {
        const int idx = base + lane;
        int s = 0;
        float p = 0.f;
        if (idx < end) {
            s = (int)col[idx];
            float t = alsh[s] + ad;
            t = t > 0.f ? t : 0.2f * t;
            p = __expf(t);
        }
        lp += p;
        mybuf[lane] = make_float2(p, __int_as_float(s << 7));
        int cnt = end - base; if (cnt > 64) cnt = 64;
        int octs = (cnt + 7) >> 3;
        int j = 0;
        for (; j + 4 <= octs; j += 4) {
            int a4[4]; float p4[4]; uint4 x[4];
            #pragma unroll
            for (int q = 0; q < 4; ++q) {
                float2 bv = mybuf[8 * (j + q) + e];
                a4[q] = __float_as_int(bv.y);
                p4[q] = bv.x;
            }
            #pragma unroll
            for (int q = 0; q < 4; ++q)
                x[q] = *(const uint4*)(xpb + a4[q] + c16);
            #pragma unroll
            for (int q = 0; q < 4; ++q) {
                acc0 = fmaf(p4[q], ulo(x[q].x), acc0);
                acc1 = fmaf(p4[q], uhi(x[q].x), acc1);
                acc2 = fmaf(p4[q], ulo(x[q].y), acc2);
                acc3 = fmaf(p4[q], uhi(x[q].y), acc3);
                acc4 = fmaf(p4[q], ulo(x[q].z), acc4);
                acc5 = fmaf(p4[q], uhi(x[q].z), acc5);
                acc6 = fmaf(p4[q], ulo(x[q].w), acc6);
                acc7 = fmaf(p4[q], uhi(x[q].w), acc7);
            }
        }
        for (; j < octs; ++j) {
            float2 bv = mybuf[8 * j + e];
            uint4 x = *(const uint4*)(xpb + __float_as_int(bv.y) + c16);
            float pv = bv.x;
            acc0 = fmaf(pv, ulo(x.x), acc0);
            acc1 = fmaf(pv, uhi(x.x), acc1);
            acc2 = fmaf(pv, ulo(x.y), acc2);
            acc3 = fmaf(pv, uhi(x.y), acc3);
            acc4 = fmaf(pv, ulo(x.z), acc4);
            acc5 = fmaf(pv, uhi(x.z), acc5);
            acc6 = fmaf(pv, ulo(x.w), acc6);
            acc7 = fmaf(pv, uhi(x.w), acc7);
        }
    }
    #pragma unroll
    for (int off = 32; off; off >>= 1) lp += __shfl_xor(lp, off, 64);
    #pragma unroll
    for (int off = 8; off <= 32; off <<= 1) {
        acc0 += __shfl_xor(acc0, off, 64);
        acc1 += __shfl_xor(acc1, off, 64);
        acc2 += __shfl_xor(acc2, off, 64);
        acc3 += __shfl_xor(acc3, off, 64);
        acc4 += __shfl_xor(acc4, off, 64);
        acc5 += __shfl_xor(acc5, off, 64);
        acc6 += __shfl_xor(acc6, off, 64);
        acc7 += __shfl_xor(acc7, off, 64);
    }
    if (lane < 8) {
        const float rl = 1.f / (lp + pself);
        const long bb = (long)head * 64 + 8 * c;
        float o0 = acc0 * rl + ldf(b1, bb + 0, fp32);
        float o1 = acc1 * rl + ldf(b1, bb + 1, fp32);
        float o2 = acc2 * rl + ldf(b1, bb + 2, fp32);
        float o3 = acc3 * rl + ldf(b1, bb + 3, fp32);
        float o4 = acc4 * rl + ldf(b1, bb + 4, fp32);
        float o5 = acc5 * rl + ldf(b1, bb + 5, fp32);
        float o6 = acc6 * rl + ldf(b1, bb + 6, fp32);
        float o7 = acc7 * rl + ldf(b1, bb + 7, fp32);
        uint4 o;
        o.x = pack2(o0, o1); o.y = pack2(o2, o3);
        o.z = pack2(o4, o5); o.w = pack2(o6, o7);
        *(uint4*)((char*)h1b32 + (long)n * 256 + head * 128 + c16) = o;
    }
}

// ---------------- Layer 2 GEMM via MFMA + fused logits (shuffle reduce) ----------------

__global__ __launch_bounds__(256) void gemm2_k(
        const unsigned* __restrict__ h1b32, const short* __restrict__ w2f,
        const void* __restrict__ as2, const void* __restrict__ ad2,
        const int* __restrict__ flags,
        short* __restrict__ xp2b, float* __restrict__ alsrc, float* __restrict__ aldst) {
    const int fp32 = flags[0];
    const int tid = threadIdx.x;
    const int nb = blockIdx.x * 32;
    __shared__ __align__(16) short xs[32][136];
    __shared__ float sredc[32][4], dredc[32][4];

    #pragma unroll
    for (int i = 0; i < 8; ++i) {
        int idx = i * 256 + tid;
        int r = idx >> 6, ii = idx & 63;
        int g = nb + r;
        unsigned val = (g < N_NODESC) ? h1b32[(long)g * 64 + ii] : 0u;
        ((unsigned*)&xs[r][0])[ii] = val;
    }
    __syncthreads();

    const int wid = tid >> 6, lane = tid & 63;
    const int quad = lane >> 4, l16 = lane & 15;
    floatx4 acc0 = (floatx4){0.f, 0.f, 0.f, 0.f};
    floatx4 acc1 = (floatx4){0.f, 0.f, 0.f, 0.f};
    #pragma unroll
    for (int t = 0; t < 4; ++t) {
        short8 a0 = *(const short8*)&xs[l16][t * 32 + quad * 8];
        short8 a1 = *(const short8*)&xs[16 + l16][t * 32 + quad * 8];
        short8 b = *(const short8*)&w2f[(((wid * 4 + t) * 4 + quad) * 16 + l16) * 8];
        acc0 = __builtin_amdgcn_mfma_f32_16x16x32_bf16(a0, b, acc0, 0, 0, 0);
        acc1 = __builtin_amdgcn_mfma_f32_16x16x32_bf16(a1, b, acc1, 0, 0, 0);
    }
    const int colg = wid * 16 + l16;
    const float asv = ldf(as2, colg, fp32), adv = ldf(ad2, colg, fp32);
    float sv0[4], dv0[4], sv1[4], dv1[4];
    #pragma unroll
    for (int reg = 0; reg < 4; ++reg) {
        int r0 = quad * 4 + reg;
        int g0 = nb + r0;
        int g1 = g0 + 16;
        if (g0 < N_NODESC) xp2b[(long)g0 * 64 + colg] = f2s(acc0[reg]);
        if (g1 < N_NODESC) xp2b[(long)g1 * 64 + colg] = f2s(acc1[reg]);
        sv0[reg] = acc0[reg] * asv; dv0[reg] = acc0[reg] * adv;
        sv1[reg] = acc1[reg] * asv; dv1[reg] = acc1[reg] * adv;
    }
    #pragma unroll
    for (int off = 1; off < 16; off <<= 1) {
        #pragma unroll
        for (int reg = 0; reg < 4; ++reg) {
            sv0[reg] += __shfl_xor(sv0[reg], off, 64);
            dv0[reg] += __shfl_xor(dv0[reg], off, 64);
            sv1[reg] += __shfl_xor(sv1[reg], off, 64);
            dv1[reg] += __shfl_xor(dv1[reg], off, 64);
        }
    }
    if (l16 == 0) {
        #pragma unroll
        for (int reg = 0; reg < 4; ++reg) {
            int r0 = quad * 4 + reg;
            sredc[r0][wid] = sv0[reg];      dredc[r0][wid] = dv0[reg];
            sredc[r0 + 16][wid] = sv1[reg]; dredc[r0 + 16][wid] = dv1[reg];
        }
    }
    __syncthreads();
    if (tid < 32) {
        int g = nb + tid;
        if (g < N_NODESC) {
            alsrc[g] = sredc[tid][0] + sredc[tid][1] + sredc[tid][2] + sredc[tid][3];
            aldst[g] = dredc[tid][0] + dredc[tid][1] + dredc[tid][2] + dredc[tid][3];
        }
    }
}

// ---------------- Layer 2 aggregation with FUSED mean-pool accumulation ----------------
// Same oct-edge gather as agg1h; epilogue accumulates biased rows directly into
// pooled[] (block-level LDS partial when all 4 nodes share a graph — the common
// case since batch is sorted). h2 never materializes.

__global__ __launch_bounds__(256) void agg2p_k(
        const int* __restrict__ row_start, const unsigned short* __restrict__ col,
        const short* __restrict__ xp2b, const float* __restrict__ alsrc,
        const float* __restrict__ aldst, const void* __restrict__ b2v,
        const int* __restrict__ flags, const int* __restrict__ batch32,
        float* __restrict__ pooled, float* __restrict__ counts) {
    const int fp32 = flags[0];
    const int tid = threadIdx.x;
    const int wid = tid >> 6;
    const int lane = tid & 63;
    const int n = blockIdx.x * 4 + wid;
    __shared__ float2 pbuf[4][64];
    __shared__ float psum[64];
    __shared__ int ginfo[2];
    if (tid < 64) psum[tid] = 0.f;
    if (tid == 0) {
        int g0 = batch32[blockIdx.x * 4];
        int g3 = batch32[blockIdx.x * 4 + 3];
        ginfo[0] = g0;
        ginfo[1] = (g0 == g3);
    }
    __syncthreads();
    float2* mybuf = pbuf[wid];
    const int e = lane >> 3;
    const int c = lane & 7;
    const char* xpb = (const char*)xp2b;
    const int c16 = c * 16;
    const float ad = aldst[n];
    float e0 = alsrc[n] + ad;
    e0 = e0 > 0.f ? e0 : 0.2f * e0;
    const float pself = __expf(e0);
    const float pinit = e == 0 ? pself : 0.f;
    uint4 us = *(const uint4*)(xpb + (long)n * 128 + c16);
    float acc0 = pinit * ulo(us.x), acc1 = pinit * uhi(us.x);
    float acc2 = pinit * ulo(us.y), acc3 = pinit * uhi(us.y);
    float acc4 = pinit * ulo(us.z), acc5 = pinit * uhi(us.z);
    float acc6 = pinit * ulo(us.w), acc7 = pinit * uhi(us.w);
    float lp = 0.f;
    const int beg = row_start[n], end = row_start[n + 1];
    for (int base = beg; base < end; base += 64) {
        const int idx = base + lane;
        int s = 0;
        float p = 0.f;
        if (idx < end) {
            s = (int)col[idx];
            float t = alsrc[s] + ad;
            t = t > 0.f ? t : 0.2f * t;
            p = __expf(t);
        }
        lp += p;
        mybuf[lane] = make_float2(p, __int_as_float(s << 7));
        int cnt = end - base; if (cnt > 64) cnt = 64;
        int octs = (cnt + 7) >> 3;
        int j = 0;
        for (; j + 4 <= octs; j += 4) {
            int a4[4]; float p4[4]; uint4 x[4];
            #pragma unroll
            for (int q = 0; q < 4; ++q) {
                float2 bv = mybuf[8 * (j + q) + e];
                a4[q] = __float_as_int(bv.y);
                p4[q] = bv.x;
            }
            #pragma unroll
            for (int q = 0; q < 4; ++q)
                x[q] = *(const uint4*)(xpb + a4[q] + c16);
            #pragma unroll
            for (int q = 0; q < 4; ++q) {
                acc0 = fmaf(p4[q], ulo(x[q].x), acc0);
                acc1 = fmaf(p4[q], uhi(x[q].x), acc1);
                acc2 = fmaf(p4[q], ulo(x[q].y), acc2);
                acc3 = fmaf(p4[q], uhi(x[q].y), acc3);
                acc4 = fmaf(p4[q], ulo(x[q].z), acc4);
                acc5 = fmaf(p4[q], uhi(x[q].z), acc5);
                acc6 = fmaf(p4[q], ulo(x[q].w), acc6);
                acc7 = fmaf(p4[q], uhi(x[q].w), acc7);
            }
        }
        for (; j < octs; ++j) {
            float2 bv = mybuf[8 * j + e];
            uint4 x = *(const uint4*)(xpb + __float_as_int(bv.y) + c16);
            float pv = bv.x;
            acc0 = fmaf(pv, ulo(x.x), acc0);
            acc1 = fmaf(pv, uhi(x.x), acc1);
            acc2 = fmaf(pv, ulo(x.y), acc2);
            acc3 = fmaf(pv, uhi(x.y), acc3);
            acc4 = fmaf(pv, ulo(x.z), acc4);
            acc5 = fmaf(pv, uhi(x.z), acc5);
            acc6 = fmaf(pv, ulo(x.w), acc6);
            acc7 = fmaf(pv, uhi(x.w), acc7);
        }
    }
    #pragma unroll
    for (int off = 32; off; off >>= 1) lp += __shfl_xor(lp, off, 64);
    #pragma unroll
    for (int off = 8; off <= 32; off <<= 1) {
        acc0 += __shfl_xor(acc0, off, 64);
        acc1 += __shfl_xor(acc1, off, 64);
        acc2 += __shfl_xor(acc2, off, 64);
        acc3 += __shfl_xor(acc3, off, 64);
        acc4 += __shfl_xor(acc4, off, 64);
        acc5 += __shfl_xor(acc5, off, 64);
        acc6 += __shfl_xor(acc6, off, 64);
        acc7 += __shfl_xor(acc7, off, 64);
    }
    float o[8];
    if (lane < 8) {
        const float rl = 1.f / (lp + pself);
        o[0] = acc0 * rl + ldf(b2v, 8 * c + 0, fp32);
        o[1] = acc1 * rl + ldf(b2v, 8 * c + 1, fp32);
        o[2] = acc2 * rl + ldf(b2v, 8 * c + 2, fp32);
        o[3] = acc3 * rl + ldf(b2v, 8 * c + 3, fp32);
        o[4] = acc4 * rl + ldf(b2v, 8 * c + 4, fp32);
        o[5] = acc5 * rl + ldf(b2v, 8 * c + 5, fp32);
        o[6] = acc6 * rl + ldf(b2v, 8 * c + 6, fp32);
        o[7] = acc7 * rl + ldf(b2v, 8 * c + 7, fp32);
    }
    if (ginfo[1]) {
        if (lane < 8) {
            #pragma unroll
            for (int j = 0; j < 8; ++j) atomicAdd(&psum[8 * c + j], o[j]);
        }
        __syncthreads();
        if (tid < 64) atomicAdd(&pooled[ginfo[0] * 64 + tid], psum[tid]);
        if (tid == 0) atomicAdd(&counts[ginfo[0]], 4.f);
    } else {
        int g = batch32[n];
        if (lane < 8) {
            #pragma unroll
            for (int j = 0; j < 8; ++j) atomicAdd(&pooled[g * 64 + 8 * c + j], o[j]);
        }
        if (lane == 0) atomicAdd(&counts[g], 1.f);
    }
}

// ---------------- decoder MLP ----------------

__global__ __launch_bounds__(64) void dec_k(const float* __restrict__ pooled,
                                            const float* __restrict__ counts,
                                            const void* __restrict__ Wd1, const void* __restrict__ bd1,
                                            const void* __restrict__ Wd2, const void* __restrict__ bd2,
                                            const int* __restrict__ flags,
                                            void* __restrict__ out) {
    const int fp32 = flags[0];
    const int g = blockIdx.x, j = threadIdx.x;
    __shared__ float p[64], dh[64];
    float cnt = counts[g];
    cnt = cnt < 1.f ? 1.f : cnt;
    p[j] = pooled[g * 64 + j] / cnt;
    __syncthreads();
    float acc = ldf(bd1, j, fp32);
    for (int k = 0; k < 64; ++k) acc += p[k] * ldf(Wd1, k * 64 + j, fp32);
    dh[j] = acc > 0.f ? acc : 0.f;
    __syncthreads();
    if (j < 32) {
        float o = ldf(bd2, j, fp32);
        for (int k = 0; k < 64; ++k) o += dh[k] * ldf(Wd2, k * 32 + j, fp32);
        if (fp32) ((float*)out)[g * 32 + j] = o;
        else      ((bf16*)out)[g * 32 + j] = __float2bfloat16(o);
    }
}

extern "C" void kernel_launch(void* const* d_in, const int* in_sizes, int n_in,
                              void* d_out, int out_size, void* d_ws, size_t ws_size,
                              hipStream_t stream) {
    (void)in_sizes; (void)n_in; (void)out_size; (void)ws_size;
    const void* prot = d_in[0];
    const void* sp   = d_in[1];
    const void* lri  = d_in[2];
    const void* eidx = d_in[3];
    const void* batch= d_in[4];
    const void* W1   = d_in[5];
    const void* as1  = d_in[6];
    const void* ad1  = d_in[7];
    const void* b1   = d_in[8];
    const void* W2   = d_in[9];
    const void* as2  = d_in[10];
    const void* ad2  = d_in[11];
    const void* b2v  = d_in[12];
    const void* Wd1  = d_in[13];
    const void* bd1  = d_in[14];
    const void* Wd2  = d_in[15];
    const void* bd2  = d_in[16];

    char* w = (char*)d_ws;
    auto alloc = [&](size_t bytes) -> void* {
        char* p = w;
        w += (bytes + 255) & ~(size_t)255;
        return (void*)p;
    };
    int*   flags     = (int*)alloc(2 * 4);
    // --- contiguous zero region: pooled .. state ---
    float* pooled    = (float*)alloc((size_t)NUM_GRAPHSC * 64 * 4);
    float* counts    = (float*)alloc((size_t)NUM_GRAPHSC * 4);
    int*   bcur      = (int*)alloc((size_t)8 * 4);
    int*   scnt      = (int*)alloc((size_t)256 * 4);
    int*   state     = (int*)alloc((size_t)256 * 4);
    char*  zero_end  = w;
    // ----------------------------------------------
    int*   batch32   = (int*)alloc((size_t)N_NODESC * 4);
    int*   row_start = (int*)alloc((size_t)(N_NODESC + 1) * 4);
    unsigned* bucket = (unsigned*)alloc((size_t)8 * BCAP * 4);
    unsigned* bucket2= (unsigned*)alloc((size_t)256 * SBCAP * 4);
    unsigned short* col = (unsigned short*)alloc((size_t)N_EDGESC * 2);
    short* w1f       = (short*)alloc((size_t)16384 * 2);
    float* w1r       = (float*)alloc((size_t)256 * 4);
    short* w2f       = (short*)alloc((size_t)8192 * 2);
    short* xph0      = (short*)alloc((size_t)N_NODESC * 64 * 2);
    short* xph1      = (short*)alloc((size_t)N_NODESC * 64 * 2);
    float* alsrc1    = (float*)alloc((size_t)N_NODESC * 2 * 4);
    float* aldst1    = (float*)alloc((size_t)N_NODESC * 2 * 4);
    short* h1b       = (short*)alloc((size_t)N_NODESC * 128 * 2);
    short* xp2b      = (short*)alloc((size_t)N_NODESC * 64 * 2);
    float* alsrc2    = (float*)alloc((size_t)N_NODESC * 4);
    float* aldst2    = (float*)alloc((size_t)N_NODESC * 4);

    const int nzero = (int)((zero_end - (char*)pooled) / 4);
    const int nzblk = (nzero + 255) / 256;
    const int nbat  = (N_NODESC + 255) / 256;

    detect_k<<<1, 64, 0, stream>>>(prot, eidx, flags);
    prep2_k<<<97 + nzblk + nbat, 256, 0, stream>>>(W1, W2, flags, w1f, w1r, w2f,
                                                   (int*)pooled, nzero, nzblk,
                                                   batch, batch32);
    cvt_bucket_k<<<(N_EDGESC + CH_EPB - 1) / CH_EPB, 256, 0, stream>>>(eidx, flags, bcur, bucket);
    subpart_k<<<8 * 32, 256, 0, stream>>>(bucket, bcur, scnt, bucket2);
    csr_k<<<256, 256, 0, stream>>>(bucket2, scnt, state, row_start, col);

    const int nblk = (N_NODESC + 31) / 32;
    gemm1_k<<<nblk, 256, 0, stream>>>(prot, sp, lri, w1f, w1r, as1, ad1, flags,
                                      xph0, xph1, alsrc1, aldst1);
    agg1h_k<<<N_NODESC / 4, 256, 0, stream>>>(row_start, col, xph0,
                                              alsrc1, aldst1, b1, flags, 0,
                                              (unsigned*)h1b);
    agg1h_k<<<N_NODESC / 4, 256, 0, stream>>>(row_start, col, xph1,
                                              alsrc1 + N_NODESC, aldst1 + N_NODESC,
                                              b1, flags, 1, (unsigned*)h1b);
    gemm2_k<<<nblk, 256, 0, stream>>>((const unsigned*)h1b, w2f, as2, ad2, flags,
                                      xp2b, alsrc2, aldst2);
    agg2p_k<<<N_NODESC / 4, 256, 0, stream>>>(row_start, col, xp2b, alsrc2, aldst2,
                                              b2v, flags, batch32, pooled, counts);
    dec_k<<<NUM_GRAPHSC, 64, 0, stream>>>(pooled, counts, Wd1, bd1, Wd2, bd2, flags, d_out);
}

// Round 5
// 351.729 us; speedup vs baseline: 1.1868x; 1.1868x over previous
//
#include <hip/hip_runtime.h>
#include <hip/hip_bf16.h>

#define N_NODESC 50000
#define N_EDGESC 1600000
#define NUM_GRAPHSC 64
#define SLICE_W 6250          // 50000 / 8
#define BCAP 230000           // per-slice bucket capacity
#define CH_EPB 2048           // edges per block in cvt_bucket
#define EPB2 8192             // entries per chunk in subpart
#define SUBW 196              // nodes per sub-bucket
#define NSUB 32               // sub-buckets per slice (8*32=256 total)
#define SBCAP 8192            // per-sub-bucket capacity
#define POOL_REP 32           // pooled replicas to kill atomic contention

typedef __hip_bfloat16 bf16;
typedef short short8 __attribute__((ext_vector_type(8)));
typedef float floatx4 __attribute__((ext_vector_type(4)));

__device__ __forceinline__ float ldf(const void* p, long i, int fp32) {
    return fp32 ? ((const float*)p)[i] : __bfloat162float(((const bf16*)p)[i]);
}
__device__ __forceinline__ short f2s(float v) {
    bf16 h = __float2bfloat16(v);
    return *(short*)&h;
}
__device__ __forceinline__ unsigned pack2(float lo, float hi) {
    bf16 a = __float2bfloat16(lo), b = __float2bfloat16(hi);
    unsigned ua = *(unsigned short*)&a, ub = *(unsigned short*)&b;
    return (ub << 16) | ua;
}
__device__ __forceinline__ float ulo(unsigned u) { return __uint_as_float(u << 16); }
__device__ __forceinline__ float uhi(unsigned u) { return __uint_as_float(u & 0xffff0000u); }

// ---------------- dtype detection ----------------
__global__ void detect_k(const void* __restrict__ prot,
                         const void* __restrict__ eidx,
                         int* __restrict__ flags) {
    if (blockIdx.x == 0 && threadIdx.x == 0) {
        const bf16* pb = (const bf16*)prot;
        int sane = 0;
        for (int i = 0; i < 64; ++i) {
            float a = fabsf(__bfloat162float(pb[2 * i]));
            if (a > 1e-8f && a < 1e4f) sane++;
        }
        flags[0] = (sane >= 48) ? 0 : 1;
        const unsigned* u = (const unsigned*)eidx;
        int zhi = 0;
        for (int i = 0; i < 32; ++i)
            if (u[2 * i + 1] == 0u) zhi++;
        flags[1] = (zhi >= 30) ? 1 : 0;
    }
}

// ---------------- fused: weight prep + workspace zero + batch cvt ----------------
__global__ __launch_bounds__(256) void prep2_k(const void* __restrict__ W1,
                                               const void* __restrict__ W2,
                                               const int* __restrict__ flags,
                                               short* __restrict__ w1f,
                                               float* __restrict__ w1r,
                                               short* __restrict__ w2f,
                                               int* __restrict__ zreg, int nzero, int nzblk,
                                               const void* __restrict__ batch,
                                               int* __restrict__ b32) {
    const int fp32 = flags[0];
    const int b = blockIdx.x, tid = threadIdx.x;
    if (b < 64) {
        int idx = b * 256 + tid;                    // 16384
        int kp = idx >> 7, n = idx & 127;
        int krow = kp < 64 ? kp : 66 + (kp - 64);
        float v = ldf(W1, (long)krow * 128 + n, fp32);
        int c = n >> 4, nn = n & 15, t = kp >> 5, q = (kp >> 3) & 3, j = kp & 7;
        w1f[(((c * 4 + t) * 4 + q) * 16 + nn) * 8 + j] = f2s(v);
    } else if (b == 64) {
        int which = tid >> 7, n = tid & 127;        // W1 rows 64,65 (spatial)
        w1r[which * 128 + n] = ldf(W1, (long)(64 + which) * 128 + n, fp32);
    } else if (b < 97) {
        int idx = (b - 65) * 256 + tid;             // 8192
        int k = idx >> 6, n = idx & 63;
        float v = ldf(W2, (long)k * 64 + n, fp32);
        int c = n >> 4, nn = n & 15, t = k >> 5, q = (k >> 3) & 3, j = k & 7;
        w2f[(((c * 4 + t) * 4 + q) * 16 + nn) * 8 + j] = f2s(v);
    } else if (b < 97 + nzblk) {
        int i = (b - 97) * 256 + tid;
        if (i < nzero) zreg[i] = 0;
    } else {
        const int i64f = flags[1];
        int i = (b - 97 - nzblk) * 256 + tid;
        if (i < N_NODESC)
            b32[i] = i64f ? (int)((const long long*)batch)[i] : ((const int*)batch)[i];
    }
}

// ---------------- convert + LDS-compacted slice partition ----------------
__global__ __launch_bounds__(256) void cvt_bucket_k(const void* __restrict__ eidx,
                                                    const int* __restrict__ flags,
                                                    int* __restrict__ bcur,
                                                    unsigned* __restrict__ bucket) {
    const int i64f = flags[1];
    const int tid = threadIdx.x;
    const long e0 = (long)blockIdx.x * CH_EPB;
    __shared__ int cnt[9];
    __shared__ int gbase[8];
    __shared__ int cur[8];
    __shared__ unsigned buf[CH_EPB];
    if (tid < 8) cnt[tid] = 0;
    __syncthreads();
    unsigned ev[8];
    int bk[8];
    #pragma unroll
    for (int i = 0; i < 8; ++i) {
        long e = e0 + i * 256 + tid;
        bk[i] = -1;
        if (e < N_EDGESC) {
            int s, d;
            if (i64f) {
                s = (int)((const long long*)eidx)[e];
                d = (int)((const long long*)eidx)[N_EDGESC + e];
            } else {
                s = ((const int*)eidx)[e];
                d = ((const int*)eidx)[N_EDGESC + e];
            }
            int b = d / SLICE_W;
            bk[i] = b;
            ev[i] = (unsigned)s | ((unsigned)(d - b * SLICE_W) << 16);
            atomicAdd(&cnt[b], 1);
        }
    }
    __syncthreads();
    if (tid == 0) {
        int run = 0;
        #pragma unroll
        for (int b = 0; b < 8; ++b) { int c = cnt[b]; cnt[b] = run; run += c; }
        cnt[8] = run;
    }
    __syncthreads();
    if (tid < 8) {
        int c = cnt[tid + 1] - cnt[tid];
        gbase[tid] = c ? atomicAdd(&bcur[tid], c) : 0;
        cur[tid] = cnt[tid];
    }
    __syncthreads();
    #pragma unroll
    for (int i = 0; i < 8; ++i) {
        if (bk[i] >= 0) {
            int p = atomicAdd(&cur[bk[i]], 1);
            buf[p] = ev[i];
        }
    }
    __syncthreads();
    const int total = cnt[8];
    for (int p = tid; p < total; p += 256) {
        int b = 7;
        #pragma unroll
        for (int q = 6; q >= 0; --q)
            if (p < cnt[q + 1]) b = q;
        bucket[(long)b * BCAP + gbase[b] + (p - cnt[b])] = buf[p];
    }
}

// ---------------- sub-partition: slice bucket -> 32 sub-buckets of 196 nodes ----------------
__global__ __launch_bounds__(256) void subpart_k(const unsigned* __restrict__ bucket,
                                                 const int* __restrict__ bcur,
                                                 int* __restrict__ scnt,
                                                 unsigned* __restrict__ bucket2) {
    const int slice = blockIdx.x & 7;
    const int blk = blockIdx.x >> 3;   // 0..31
    const int tid = threadIdx.x;
    const int cnt = bcur[slice];
    const unsigned* B = bucket + (long)slice * BCAP;
    __shared__ unsigned buf[EPB2];
    __shared__ int cnt2[NSUB + 1], gbase[NSUB], cur[NSUB];
    for (int start = blk * EPB2; start < cnt; start += 32 * EPB2) {
        const int csize = min(EPB2, cnt - start);
        if (tid < NSUB) cnt2[tid] = 0;
        __syncthreads();
        for (int i = tid; i < csize; i += 256) {
            unsigned v = B[start + i];
            atomicAdd(&cnt2[(v >> 16) / SUBW], 1);
        }
        __syncthreads();
        if (tid == 0) {
            int run = 0;
            #pragma unroll
            for (int s = 0; s < NSUB; ++s) { int c = cnt2[s]; cnt2[s] = run; run += c; }
            cnt2[NSUB] = run;
        }
        __syncthreads();
        if (tid < NSUB) {
            int c = cnt2[tid + 1] - cnt2[tid];
            gbase[tid] = c ? atomicAdd(&scnt[slice * NSUB + tid], c) : 0;
            cur[tid] = cnt2[tid];
        }
        __syncthreads();
        for (int i = tid; i < csize; i += 256) {
            unsigned v = B[start + i];
            int off = (int)(v >> 16);
            int sub = off / SUBW;
            unsigned nv = (v & 0xffffu) | ((unsigned)(off - sub * SUBW) << 16);
            int p = atomicAdd(&cur[sub], 1);
            buf[p] = nv;
        }
        __syncthreads();
        const int total = cnt2[NSUB];
        for (int p = tid; p < total; p += 256) {
            int lo = 0, hi = NSUB;
            while (hi - lo > 1) { int mid = (lo + hi) >> 1; if (p >= cnt2[mid]) lo = mid; else hi = mid; }
            bucket2[((long)slice * NSUB + lo) * SBCAP + gbase[lo] + (p - cnt2[lo])] = buf[p];
        }
        __syncthreads();
    }
}

// ---------------- fused CSR build: histogram + decoupled-lookback scan + scatter ----------------
__global__ __launch_bounds__(256) void csr_k(const unsigned* __restrict__ bucket2,
                                             const int* __restrict__ scnt,
                                             int* __restrict__ state,
                                             int* __restrict__ row_start,
                                             unsigned short* __restrict__ col) {
    const int sb = blockIdx.x;
    const int slice = sb >> 5, sub = sb & 31;
    const int tid = threadIdx.x;
    const int lane = tid & 63;
    const int cnt = scnt[sb];
    const unsigned* B = bucket2 + (long)sb * SBCAP;
    __shared__ int lh[SUBW];
    __shared__ int sc[256];
    __shared__ int sprefix_sh;
    const int width = min(SUBW, SLICE_W - sub * SUBW);
    const int nodebase = slice * SLICE_W + sub * SUBW;
    for (int i = tid; i < SUBW; i += 256) lh[i] = 0;
    __syncthreads();
    for (int e = tid; e < cnt; e += 256) atomicAdd(&lh[B[e] >> 16], 1);
    __syncthreads();
    const int myc = (tid < SUBW) ? lh[tid] : 0;
    sc[tid] = myc;
    __syncthreads();
    for (int off = 1; off < 256; off <<= 1) {
        int t = (tid >= off) ? sc[tid - off] : 0;
        __syncthreads();
        sc[tid] += t;
        __syncthreads();
    }
    const int total = sc[255];
    if (tid == 0)
        __hip_atomic_store(&state[sb], (int)((1u << 30) | (unsigned)total),
                           __ATOMIC_RELEASE, __HIP_MEMORY_SCOPE_AGENT);
    if (tid < 64) {
        int prefix = 0;
        if (sb > 0) {
            int base = sb;
            for (;;) {
                int t = base - 1 - lane;
                int v = 0;
                if (t >= 0) {
                    for (;;) {
                        v = __hip_atomic_load(&state[t], __ATOMIC_ACQUIRE,
                                              __HIP_MEMORY_SCOPE_AGENT);
                        if ((unsigned)v >= (1u << 30)) break;
                        __builtin_amdgcn_s_sleep(1);
                    }
                }
                int flag = (int)(((unsigned)v) >> 30);
                int val = v & 0x3fffffff;
                unsigned long long pmask = __ballot(flag == 2 && t >= 0);
                int stop_tid = pmask ? (__ffsll((long long)pmask) - 1) : 64;
                int contrib = 0;
                if (t >= 0 && lane <= stop_tid) contrib = val;
                #pragma unroll
                for (int off = 32; off; off >>= 1) contrib += __shfl_xor(contrib, off, 64);
                prefix += contrib;
                if (pmask || base <= 64) break;
                base -= 64;
            }
        }
        if (tid == 0) {
            sprefix_sh = prefix;
            __hip_atomic_store(&state[sb],
                               (int)((2u << 30) | (unsigned)(prefix + total)),
                               __ATOMIC_RELEASE, __HIP_MEMORY_SCOPE_AGENT);
        }
    }
    __syncthreads();
    const int sprefix = sprefix_sh;
    if (tid < width) row_start[nodebase + tid] = sprefix + sc[tid] - myc;
    if (sb == 255 && tid == 0) row_start[N_NODESC] = sprefix + total;
    if (tid < SUBW) lh[tid] = sprefix + sc[tid] - myc;   // cursor
    __syncthreads();
    for (int e = tid; e < cnt; e += 256) {
        unsigned v = B[e];
        int pos = atomicAdd(&lh[v >> 16], 1);
        col[pos] = (unsigned short)(v & 0xffffu);
    }
}

// ---------------- Layer 1 GEMM via MFMA + fused logits (head-split outputs) ----------------

__global__ __launch_bounds__(256) void gemm1_k(
        const void* __restrict__ prot, const void* __restrict__ sp,
        const void* __restrict__ lri,
        const short* __restrict__ w1f, const float* __restrict__ w1r,
        const void* __restrict__ as1, const void* __restrict__ ad1,
        const int* __restrict__ flags,
        short* __restrict__ xph0, short* __restrict__ xph1,
        float* __restrict__ alsrc, float* __restrict__ aldst) {
    const int fp32 = flags[0];
    const int tid = threadIdx.x;
    const int nb = blockIdx.x * 32;
    __shared__ __align__(16) short xs[32][136];   // K order: prot 0..63, lri 0..63
    __shared__ float xsp[32][2];                  // spatial remainder
    __shared__ float sredc[32][8], dredc[32][8];  // [row][col-block]

    if (!fp32) {
        #pragma unroll
        for (int i = 0; i < 2; ++i) {
            int cidx = i * 256 + tid;             // 512 chunks of 8 shorts
            int r = cidx >> 4, cc = cidx & 15;
            int g = nb + r;
            short8 v = (short8){0, 0, 0, 0, 0, 0, 0, 0};
            if (g < N_NODESC) {
                const short* srcp = (cc < 8)
                    ? (const short*)prot + (long)g * 64 + cc * 8
                    : (const short*)lri + (long)g * 64 + (cc - 8) * 8;
                v = *(const short8*)srcp;
            }
            *(short8*)&xs[r][cc * 8] = v;
        }
    } else {
        #pragma unroll
        for (int i = 0; i < 16; ++i) {
            int idx = i * 256 + tid;
            int r = idx >> 7, k = idx & 127;
            int g = nb + r;
            float v = 0.f;
            if (g < N_NODESC)
                v = (k < 64) ? ((const float*)prot)[(long)g * 64 + k]
                             : ((const float*)lri)[(long)g * 64 + (k - 64)];
            xs[r][k] = f2s(v);
        }
    }
    if (tid < 64) {
        int r = tid >> 1, which = tid & 1;
        int g = nb + r;
        xsp[r][which] = (g < N_NODESC) ? ldf(sp, (long)g * 2 + which, fp32) : 0.f;
    }
    __syncthreads();

    const int wid = tid >> 6, lane = tid & 63;
    const int quad = lane >> 4, l16 = lane & 15;
    floatx4 acc[2][2];
    #pragma unroll
    for (int a = 0; a < 2; ++a)
        #pragma unroll
        for (int b = 0; b < 2; ++b) acc[a][b] = (floatx4){0.f, 0.f, 0.f, 0.f};

    const int c0 = 2 * wid;
    #pragma unroll
    for (int t = 0; t < 4; ++t) {
        short8 a0 = *(const short8*)&xs[l16][t * 32 + quad * 8];
        short8 a1 = *(const short8*)&xs[16 + l16][t * 32 + quad * 8];
        short8 b0 = *(const short8*)&w1f[(((c0 * 4 + t) * 4 + quad) * 16 + l16) * 8];
        short8 b1 = *(const short8*)&w1f[((((c0 + 1) * 4 + t) * 4 + quad) * 16 + l16) * 8];
        acc[0][0] = __builtin_amdgcn_mfma_f32_16x16x32_bf16(a0, b0, acc[0][0], 0, 0, 0);
        acc[0][1] = __builtin_amdgcn_mfma_f32_16x16x32_bf16(a0, b1, acc[0][1], 0, 0, 0);
        acc[1][0] = __builtin_amdgcn_mfma_f32_16x16x32_bf16(a1, b0, acc[1][0], 0, 0, 0);
        acc[1][1] = __builtin_amdgcn_mfma_f32_16x16x32_bf16(a1, b1, acc[1][1], 0, 0, 0);
    }
    #pragma unroll
    for (int ci = 0; ci < 2; ++ci) {
        int colg = (c0 + ci) * 16 + l16;
        float w0 = w1r[colg], w1v = w1r[128 + colg];
        float asv = ldf(as1, colg, fp32), adv = ldf(ad1, colg, fp32);
        short* xpd = (colg < 64) ? xph0 : xph1;
        const int cc = colg & 63;
        #pragma unroll
        for (int rt = 0; rt < 2; ++rt) {
            float sv[4], dv[4];
            #pragma unroll
            for (int reg = 0; reg < 4; ++reg) {
                int row = rt * 16 + quad * 4 + reg;
                int g = nb + row;
                float v = acc[rt][ci][reg] + xsp[row][0] * w0 + xsp[row][1] * w1v;
                if (g < N_NODESC) xpd[(long)g * 64 + cc] = f2s(v);
                sv[reg] = v * asv;
                dv[reg] = v * adv;
            }
            #pragma unroll
            for (int off = 1; off < 16; off <<= 1) {
                #pragma unroll
                for (int reg = 0; reg < 4; ++reg) {
                    sv[reg] += __shfl_xor(sv[reg], off, 64);
                    dv[reg] += __shfl_xor(dv[reg], off, 64);
                }
            }
            if (l16 == 0) {
                #pragma unroll
                for (int reg = 0; reg < 4; ++reg) {
                    int row = rt * 16 + quad * 4 + reg;
                    sredc[row][c0 + ci] = sv[reg];
                    dredc[row][c0 + ci] = dv[reg];
                }
            }
        }
    }
    __syncthreads();
    if (tid < 64) {
        int r = tid >> 1, h = tid & 1;
        int g = nb + r;
        if (g < N_NODESC) {
            alsrc[(long)h * N_NODESC + g] = sredc[r][4 * h] + sredc[r][4 * h + 1] +
                                            sredc[r][4 * h + 2] + sredc[r][4 * h + 3];
            aldst[(long)h * N_NODESC + g] = dredc[r][4 * h] + dredc[r][4 * h + 1] +
                                            dredc[r][4 * h + 2] + dredc[r][4 * h + 3];
        }
    }
}

// ---------------- Layer 1 aggregation: PER-HEAD pass (6.4MB working set) ----------------

__global__ __launch_bounds__(256) void agg1h_k(
        const int* __restrict__ row_start, const unsigned short* __restrict__ col,
        const short* __restrict__ xph, const float* __restrict__ alsh,
        const float* __restrict__ aldh, const void* __restrict__ b1,
        const int* __restrict__ flags, int head, unsigned* __restrict__ h1b32) {
    const int fp32 = flags[0];
    const int wid = threadIdx.x >> 6;
    const int lane = threadIdx.x & 63;
    const int n = blockIdx.x * 4 + wid;
    __shared__ float2 pbuf[4][64];
    float2* mybuf = pbuf[wid];
    const int e = lane >> 3;
    const int c = lane & 7;
    const char* xpb = (const char*)xph;
    const int c16 = c * 16;
    const float ad = aldh[n];
    float e0 = alsh[n] + ad;
    e0 = e0 > 0.f ? e0 : 0.2f * e0;
    const float pself = __expf(e0);
    const float pinit = e == 0 ? pself : 0.f;
    uint4 us = *(const uint4*)(xpb + (long)n * 128 + c16);
    float acc0 = pinit * ulo(us.x), acc1 = pinit * uhi(us.x);
    float acc2 = pinit * ulo(us.y), acc3 = pinit * uhi(us.y);
    float acc4 = pinit * ulo(us.z), acc5 = pinit * uhi(us.z);
    float acc6 = pinit * ulo(us.w), acc7 = pinit * uhi(us.w);
    float lp = 0.f;
    const int beg = row_start[n], end = row_start[n + 1];
    for (int base = beg; base < end; base += 64) {
        const int idx = base + lane;
        int s = 0;
        float p = 0.f;
        if (idx < end) {
            s = (int)col[idx];
            float t = alsh[s] + ad;
            t = t > 0.f ? t : 0.2f * t;
            p = __expf(t);
        }
        lp += p;
        mybuf[lane] = make_float2(p, __int_as_float(s << 7));
        int cnt = end - base; if (cnt > 64) cnt = 64;
        int octs = (cnt + 7) >> 3;
        int j = 0;
        for (; j + 4 <= octs; j += 4) {
            int a4[4]; float p4[4]; uint4 x[4];
            #pragma unroll
            for (int q = 0; q < 4; ++q) {
                float2 bv = mybuf[8 * (j + q) + e];
                a4[q] = __float_as_int(bv.y);
                p4[q] = bv.x;
            }
            #pragma unroll
            for (int q = 0; q < 4; ++q)
                x[q] = *(const uint4*)(xpb + a4[q] + c16);
            #pragma unroll
            for (int q = 0; q < 4; ++q) {
                acc0 = fmaf(p4[q], ulo(x[q].x), acc0);
                acc1 = fmaf(p4[q], uhi(x[q].x), acc1);
                acc2 = fmaf(p4[q], ulo(x[q].y), acc2);
                acc3 = fmaf(p4[q], uhi(x[q].y), acc3);
                acc4 = fmaf(p4[q], ulo(x[q].z), acc4);
                acc5 = fmaf(p4[q], uhi(x[q].z), acc5);
                acc6 = fmaf(p4[q], ulo(x[q].w), acc6);
                acc7 = fmaf(p4[q], uhi(x[q].w), acc7);
            }
        }
        for (; j < octs; ++j) {
            float2 bv = mybuf[8 * j + e];
            uint4 x = *(const uint4*)(xpb + __float_as_int(bv.y) + c16);
            float pv = bv.x;
            acc0 = fmaf(pv, ulo(x.x), acc0);
            acc1 = fmaf(pv, uhi(x.x), acc1);
            acc2 = fmaf(pv, ulo(x.y), acc2);
            acc3 = fmaf(pv, uhi(x.y), acc3);
            acc4 = fmaf(pv, ulo(x.z), acc4);
            acc5 = fmaf(pv, uhi(x.z), acc5);
            acc6 = fmaf(pv, ulo(x.w), acc6);
            acc7 = fmaf(pv, uhi(x.w), acc7);
        }
    }
    #pragma unroll
    for (int off = 32; off; off >>= 1) lp += __shfl_xor(lp, off, 64);
    #pragma unroll
    for (int off = 8; off <= 32; off <<= 1) {
        acc0 += __shfl_xor(acc0, off, 64);
        acc1 += __shfl_xor(acc1, off, 64);
        acc2 += __shfl_xor(acc2, off, 64);
        acc3 += __shfl_xor(acc3, off, 64);
        acc4 += __shfl_xor(acc4, off, 64);
        acc5 += __shfl_xor(acc5, off, 64);
        acc6 += __shfl_xor(acc6, off, 64);
        acc7 += __shfl_xor(acc7, off, 64);
    }
    if (lane < 8) {
        const float rl = 1.f / (lp + pself);
        const long bb = (long)head * 64 + 8 * c;
        float o0 = acc0 * rl + ldf(b1, bb + 0, fp32);
        float o1 = acc1 * rl + ldf(b1, bb + 1, fp32);
        float o2 = acc2 * rl + ldf(b1, bb + 2, fp32);
        float o3 = acc3 * rl + ldf(b1, bb + 3, fp32);
        float o4 = acc4 * rl + ldf(b1, bb + 4, fp32);
        float o5 = acc5 * rl + ldf(b1, bb + 5, fp32);
        float o6 = acc6 * rl + ldf(b1, bb + 6, fp32);
        float o7 = acc7 * rl + ldf(b1, bb + 7, fp32);
        uint4 o;
        o.x = pack2(o0, o1); o.y = pack2(o2, o3);
        o.z = pack2(o4, o5); o.w = pack2(o6, o7);
        *(uint4*)((char*)h1b32 + (long)n * 256 + head * 128 + c16) = o;
    }
}

// ---------------- Layer 2 GEMM via MFMA + fused logits (shuffle reduce) ----------------

__global__ __launch_bounds__(256) void gemm2_k(
        const unsigned* __restrict__ h1b32, const short* __restrict__ w2f,
        const void* __restrict__ as2, const void* __restrict__ ad2,
        const int* __restrict__ flags,
        short* __restrict__ xp2b, float* __restrict__ alsrc, float* __restrict__ aldst) {
    const int fp32 = flags[0];
    const int tid = threadIdx.x;
    const int nb = blockIdx.x * 32;
    __shared__ __align__(16) short xs[32][136];
    __shared__ float sredc[32][4], dredc[32][4];

    #pragma unroll
    for (int i = 0; i < 8; ++i) {
        int idx = i * 256 + tid;
        int r = idx >> 6, ii = idx & 63;
        int g = nb + r;
        unsigned val = (g < N_NODESC) ? h1b32[(long)g * 64 + ii] : 0u;
        ((unsigned*)&xs[r][0])[ii] = val;
    }
    __syncthreads();

    const int wid = tid >> 6, lane = tid & 63;
    const int quad = lane >> 4, l16 = lane & 15;
    floatx4 acc0 = (floatx4){0.f, 0.f, 0.f, 0.f};
    floatx4 acc1 = (floatx4){0.f, 0.f, 0.f, 0.f};
    #pragma unroll
    for (int t = 0; t < 4; ++t) {
        short8 a0 = *(const short8*)&xs[l16][t * 32 + quad * 8];
        short8 a1 = *(const short8*)&xs[16 + l16][t * 32 + quad * 8];
        short8 b = *(const short8*)&w2f[(((wid * 4 + t) * 4 + quad) * 16 + l16) * 8];
        acc0 = __builtin_amdgcn_mfma_f32_16x16x32_bf16(a0, b, acc0, 0, 0, 0);
        acc1 = __builtin_amdgcn_mfma_f32_16x16x32_bf16(a1, b, acc1, 0, 0, 0);
    }
    const int colg = wid * 16 + l16;
    const float asv = ldf(as2, colg, fp32), adv = ldf(ad2, colg, fp32);
    float sv0[4], dv0[4], sv1[4], dv1[4];
    #pragma unroll
    for (int reg = 0; reg < 4; ++reg) {
        int r0 = quad * 4 + reg;
        int g0 = nb + r0;
        int g1 = g0 + 16;
        if (g0 < N_NODESC) xp2b[(long)g0 * 64 + colg] = f2s(acc0[reg]);
        if (g1 < N_NODESC) xp2b[(long)g1 * 64 + colg] = f2s(acc1[reg]);
        sv0[reg] = acc0[reg] * asv; dv0[reg] = acc0[reg] * adv;
        sv1[reg] = acc1[reg] * asv; dv1[reg] = acc1[reg] * adv;
    }
    #pragma unroll
    for (int off = 1; off < 16; off <<= 1) {
        #pragma unroll
        for (int reg = 0; reg < 4; ++reg) {
            sv0[reg] += __shfl_xor(sv0[reg], off, 64);
            dv0[reg] += __shfl_xor(dv0[reg], off, 64);
            sv1[reg] += __shfl_xor(sv1[reg], off, 64);
            dv1[reg] += __shfl_xor(dv1[reg], off, 64);
        }
    }
    if (l16 == 0) {
        #pragma unroll
        for (int reg = 0; reg < 4; ++reg) {
            int r0 = quad * 4 + reg;
            sredc[r0][wid] = sv0[reg];      dredc[r0][wid] = dv0[reg];
            sredc[r0 + 16][wid] = sv1[reg]; dredc[r0 + 16][wid] = dv1[reg];
        }
    }
    __syncthreads();
    if (tid < 32) {
        int g = nb + tid;
        if (g < N_NODESC) {
            alsrc[g] = sredc[tid][0] + sredc[tid][1] + sredc[tid][2] + sredc[tid][3];
            aldst[g] = dredc[tid][0] + dredc[tid][1] + dredc[tid][2] + dredc[tid][3];
        }
    }
}

// ---------------- Layer 2 aggregation with FUSED mean-pool (replicated atomics) ----------------
// pooled has POOL_REP replicas; each block lands on replica blockIdx&31 ->
// per-address atomic chain depth ~6 instead of ~195. dec_k sums replicas.

__global__ __launch_bounds__(256) void agg2p_k(
        const int* __restrict__ row_start, const unsigned short* __restrict__ col,
        const short* __restrict__ xp2b, const float* __restrict__ alsrc,
        const float* __restrict__ aldst, const void* __restrict__ b2v,
        const int* __restrict__ flags, const int* __restrict__ batch32,
        float* __restrict__ pooled, float* __restrict__ counts) {
    const int fp32 = flags[0];
    const int tid = threadIdx.x;
    const int wid = tid >> 6;
    const int lane = tid & 63;
    const int n = blockIdx.x * 4 + wid;
    const int rep = blockIdx.x & (POOL_REP - 1);
    __shared__ float2 pbuf[4][64];
    __shared__ float psum[64];
    __shared__ int ginfo[2];
    if (tid < 64) psum[tid] = 0.f;
    if (tid == 0) {
        int g0 = batch32[blockIdx.x * 4];
        int g3 = batch32[blockIdx.x * 4 + 3];
        ginfo[0] = g0;
        ginfo[1] = (g0 == g3);
    }
    __syncthreads();
    float2* mybuf = pbuf[wid];
    const int e = lane >> 3;
    const int c = lane & 7;
    const char* xpb = (const char*)xp2b;
    const int c16 = c * 16;
    const float ad = aldst[n];
    float e0 = alsrc[n] + ad;
    e0 = e0 > 0.f ? e0 : 0.2f * e0;
    const float pself = __expf(e0);
    const float pinit = e == 0 ? pself : 0.f;
    uint4 us = *(const uint4*)(xpb + (long)n * 128 + c16);
    float acc0 = pinit * ulo(us.x), acc1 = pinit * uhi(us.x);
    float acc2 = pinit * ulo(us.y), acc3 = pinit * uhi(us.y);
    float acc4 = pinit * ulo(us.z), acc5 = pinit * uhi(us.z);
    float acc6 = pinit * ulo(us.w), acc7 = pinit * uhi(us.w);
    float lp = 0.f;
    const int beg = row_start[n], end = row_start[n + 1];
    for (int base = beg; base < end; base += 64) {
        const int idx = base + lane;
        int s = 0;
        float p = 0.f;
        if (idx < end) {
            s = (int)col[idx];
            float t = alsrc[s] + ad;
            t = t > 0.f ? t : 0.2f * t;
            p = __expf(t);
        }
        lp += p;
        mybuf[lane] = make_float2(p, __int_as_float(s << 7));
        int cnt = end - base; if (cnt > 64) cnt = 64;
        int octs = (cnt + 7) >> 3;
        int j = 0;
        for (; j + 4 <= octs; j += 4) {
            int a4[4]; float p4[4]; uint4 x[4];
            #pragma unroll
            for (int q = 0; q < 4; ++q) {
                float2 bv = mybuf[8 * (j + q) + e];
                a4[q] = __float_as_int(bv.y);
                p4[q] = bv.x;
            }
            #pragma unroll
            for (int q = 0; q < 4; ++q)
                x[q] = *(const uint4*)(xpb + a4[q] + c16);
            #pragma unroll
            for (int q = 0; q < 4; ++q) {
                acc0 = fmaf(p4[q], ulo(x[q].x), acc0);
                acc1 = fmaf(p4[q], uhi(x[q].x), acc1);
                acc2 = fmaf(p4[q], ulo(x[q].y), acc2);
                acc3 = fmaf(p4[q], uhi(x[q].y), acc3);
                acc4 = fmaf(p4[q], ulo(x[q].z), acc4);
                acc5 = fmaf(p4[q], uhi(x[q].z), acc5);
                acc6 = fmaf(p4[q], ulo(x[q].w), acc6);
                acc7 = fmaf(p4[q], uhi(x[q].w), acc7);
            }
        }
        for (; j < octs; ++j) {
            float2 bv = mybuf[8 * j + e];
            uint4 x = *(const uint4*)(xpb + __float_as_int(bv.y) + c16);
            float pv = bv.x;
            acc0 = fmaf(pv, ulo(x.x), acc0);
            acc1 = fmaf(pv, uhi(x.x), acc1);
            acc2 = fmaf(pv, ulo(x.y), acc2);
            acc3 = fmaf(pv, uhi(x.y), acc3);
            acc4 = fmaf(pv, ulo(x.z), acc4);
            acc5 = fmaf(pv, uhi(x.z), acc5);
            acc6 = fmaf(pv, ulo(x.w), acc6);
            acc7 = fmaf(pv, uhi(x.w), acc7);
        }
    }
    #pragma unroll
    for (int off = 32; off; off >>= 1) lp += __shfl_xor(lp, off, 64);
    #pragma unroll
    for (int off = 8; off <= 32; off <<= 1) {
        acc0 += __shfl_xor(acc0, off, 64);
        acc1 += __shfl_xor(acc1, off, 64);
        acc2 += __shfl_xor(acc2, off, 64);
        acc3 += __shfl_xor(acc3, off, 64);
        acc4 += __shfl_xor(acc4, off, 64);
        acc5 += __shfl_xor(acc5, off, 64);
        acc6 += __shfl_xor(acc6, off, 64);
        acc7 += __shfl_xor(acc7, off, 64);
    }
    float o[8];
    if (lane < 8) {
        const float rl = 1.f / (lp + pself);
        o[0] = acc0 * rl + ldf(b2v, 8 * c + 0, fp32);
        o[1] = acc1 * rl + ldf(b2v, 8 * c + 1, fp32);
        o[2] = acc2 * rl + ldf(b2v, 8 * c + 2, fp32);
        o[3] = acc3 * rl + ldf(b2v, 8 * c + 3, fp32);
        o[4] = acc4 * rl + ldf(b2v, 8 * c + 4, fp32);
        o[5] = acc5 * rl + ldf(b2v, 8 * c + 5, fp32);
        o[6] = acc6 * rl + ldf(b2v, 8 * c + 6, fp32);
        o[7] = acc7 * rl + ldf(b2v, 8 * c + 7, fp32);
    }
    if (ginfo[1]) {
        if (lane < 8) {
            #pragma unroll
            for (int j = 0; j < 8; ++j) atomicAdd(&psum[8 * c + j], o[j]);
        }
        __syncthreads();
        if (tid < 64)
            atomicAdd(&pooled[((long)rep * NUM_GRAPHSC + ginfo[0]) * 64 + tid], psum[tid]);
        if (tid == 0) atomicAdd(&counts[rep * NUM_GRAPHSC + ginfo[0]], 4.f);
    } else {
        int g = batch32[n];
        if (lane < 8) {
            #pragma unroll
            for (int j = 0; j < 8; ++j)
                atomicAdd(&pooled[((long)rep * NUM_GRAPHSC + g) * 64 + 8 * c + j], o[j]);
        }
        if (lane == 0) atomicAdd(&counts[rep * NUM_GRAPHSC + g], 1.f);
    }
}

// ---------------- decoder MLP (sums pooled replicas) ----------------

__global__ __launch_bounds__(64) void dec_k(const float* __restrict__ pooled,
                                            const float* __restrict__ counts,
                                            const void* __restrict__ Wd1, const void* __restrict__ bd1,
                                            const void* __restrict__ Wd2, const void* __restrict__ bd2,
                                            const int* __restrict__ flags,
                                            void* __restrict__ out) {
    const int fp32 = flags[0];
    const int g = blockIdx.x, j = threadIdx.x;
    __shared__ float p[64], dh[64];
    float cnt = 0.f, ps = 0.f;
    #pragma unroll
    for (int r = 0; r < POOL_REP; ++r) {
        ps += pooled[((long)r * NUM_GRAPHSC + g) * 64 + j];
        if (j == 0) cnt += counts[r * NUM_GRAPHSC + g];
    }
    __shared__ float cnt_sh;
    if (j == 0) cnt_sh = cnt < 1.f ? 1.f : cnt;
    __syncthreads();
    p[j] = ps / cnt_sh;
    __syncthreads();
    float acc = ldf(bd1, j, fp32);
    for (int k = 0; k < 64; ++k) acc += p[k] * ldf(Wd1, k * 64 + j, fp32);
    dh[j] = acc > 0.f ? acc : 0.f;
    __syncthreads();
    if (j < 32) {
        float o = ldf(bd2, j, fp32);
        for (int k = 0; k < 64; ++k) o += dh[k] * ldf(Wd2, k * 32 + j, fp32);
        if (fp32) ((float*)out)[g * 32 + j] = o;
        else      ((bf16*)out)[g * 32 + j] = __float2bfloat16(o);
    }
}

extern "C" void kernel_launch(void* const* d_in, const int* in_sizes, int n_in,
                              void* d_out, int out_size, void* d_ws, size_t ws_size,
                              hipStream_t stream) {
    (void)in_sizes; (void)n_in; (void)out_size; (void)ws_size;
    const void* prot = d_in[0];
    const void* sp   = d_in[1];
    const void* lri  = d_in[2];
    const void* eidx = d_in[3];
    const void* batch= d_in[4];
    const void* W1   = d_in[5];
    const void* as1  = d_in[6];
    const void* ad1  = d_in[7];
    const void* b1   = d_in[8];
    const void* W2   = d_in[9];
    const void* as2  = d_in[10];
    const void* ad2  = d_in[11];
    const void* b2v  = d_in[12];
    const void* Wd1  = d_in[13];
    const void* bd1  = d_in[14];
    const void* Wd2  = d_in[15];
    const void* bd2  = d_in[16];

    char* w = (char*)d_ws;
    auto alloc = [&](size_t bytes) -> void* {
        char* p = w;
        w += (bytes + 255) & ~(size_t)255;
        return (void*)p;
    };
    int*   flags     = (int*)alloc(2 * 4);
    // --- contiguous zero region: pooled .. state ---
    float* pooled    = (float*)alloc((size_t)POOL_REP * NUM_GRAPHSC * 64 * 4);
    float* counts    = (float*)alloc((size_t)POOL_REP * NUM_GRAPHSC * 4);
    int*   bcur      = (int*)alloc((size_t)8 * 4);
    int*   scnt      = (int*)alloc((size_t)256 * 4);
    int*   state     = (int*)alloc((size_t)256 * 4);
    char*  zero_end  = w;
    // ----------------------------------------------
    int*   batch32   = (int*)alloc((size_t)N_NODESC * 4);
    int*   row_start = (int*)alloc((size_t)(N_NODESC + 1) * 4);
    unsigned* bucket = (unsigned*)alloc((size_t)8 * BCAP * 4);
    unsigned* bucket2= (unsigned*)alloc((size_t)256 * SBCAP * 4);
    unsigned short* col = (unsigned short*)alloc((size_t)N_EDGESC * 2);
    short* w1f       = (short*)alloc((size_t)16384 * 2);
    float* w1r       = (float*)alloc((size_t)256 * 4);
    short* w2f       = (short*)alloc((size_t)8192 * 2);
    short* xph0      = (short*)alloc((size_t)N_NODESC * 64 * 2);
    short* xph1      = (short*)alloc((size_t)N_NODESC * 64 * 2);
    float* alsrc1    = (float*)alloc((size_t)N_NODESC * 2 * 4);
    float* aldst1    = (float*)alloc((size_t)N_NODESC * 2 * 4);
    short* h1b       = (short*)alloc((size_t)N_NODESC * 128 * 2);
    short* xp2b      = (short*)alloc((size_t)N_NODESC * 64 * 2);
    float* alsrc2    = (float*)alloc((size_t)N_NODESC * 4);
    float* aldst2    = (float*)alloc((size_t)N_NODESC * 4);

    const int nzero = (int)((zero_end - (char*)pooled) / 4);
    const int nzblk = (nzero + 255) / 256;
    const int nbat  = (N_NODESC + 255) / 256;

    detect_k<<<1, 64, 0, stream>>>(prot, eidx, flags);
    prep2_k<<<97 + nzblk + nbat, 256, 0, stream>>>(W1, W2, flags, w1f, w1r, w2f,
                                                   (int*)pooled, nzero, nzblk,
                                                   batch, batch32);
    cvt_bucket_k<<<(N_EDGESC + CH_EPB - 1) / CH_EPB, 256, 0, stream>>>(eidx, flags, bcur, bucket);
    subpart_k<<<8 * 32, 256, 0, stream>>>(bucket, bcur, scnt, bucket2);
    csr_k<<<256, 256, 0, stream>>>(bucket2, scnt, state, row_start, col);

    const int nblk = (N_NODESC + 31) / 32;
    gemm1_k<<<nblk, 256, 0, stream>>>(prot, sp, lri, w1f, w1r, as1, ad1, flags,
                                      xph0, xph1, alsrc1, aldst1);
    agg1h_k<<<N_NODESC / 4, 256, 0, stream>>>(row_start, col, xph0,
                                              alsrc1, aldst1, b1, flags, 0,
                                              (unsigned*)h1b);
    agg1h_k<<<N_NODESC / 4, 256, 0, stream>>>(row_start, col, xph1,
                                              alsrc1 + N_NODESC, aldst1 + N_NODESC,
                                              b1, flags, 1, (unsigned*)h1b);
    gemm2_k<<<nblk, 256, 0, stream>>>((const unsigned*)h1b, w2f, as2, ad2, flags,
                                      xp2b, alsrc2, aldst2);
    agg2p_k<<<N_NODESC / 4, 256, 0, stream>>>(row_start, col, xp2b, alsrc2, aldst2,
                                              b2v, flags, batch32, pooled, counts);
    dec_k<<<NUM_GRAPHSC, 64, 0, stream>>>(pooled, counts, Wd1, bd1, Wd2, bd2, flags, d_out);
}

// Round 6
// 331.872 us; speedup vs baseline: 1.2578x; 1.0598x over previous
//
#include <hip/hip_runtime.h>
#include <hip/hip_bf16.h>

#define N_NODESC 50000
#define N_EDGESC 1600000
#define NUM_GRAPHSC 64
#define SLICE_W 6250          // 50000 / 8
#define BCAP 230000           // per-slice bucket capacity
#define CH_EPB 2048           // edges per block in cvt_bucket
#define EPB2 8192             // entries per chunk in subpart
#define SUBW 196              // nodes per sub-bucket
#define NSUB 32               // sub-buckets per slice (8*32=256 total)
#define SBCAP 8192            // per-sub-bucket capacity
#define POOL_REP 32           // pooled replicas to kill atomic contention
#define AGG_NB 6250           // 50000 / 8 nodes per block (split-wave)

typedef __hip_bfloat16 bf16;
typedef short short8 __attribute__((ext_vector_type(8)));
typedef float floatx4 __attribute__((ext_vector_type(4)));

__device__ __forceinline__ float ldf(const void* p, long i, int fp32) {
    return fp32 ? ((const float*)p)[i] : __bfloat162float(((const bf16*)p)[i]);
}
__device__ __forceinline__ short f2s(float v) {
    bf16 h = __float2bfloat16(v);
    return *(short*)&h;
}
__device__ __forceinline__ unsigned pack2(float lo, float hi) {
    bf16 a = __float2bfloat16(lo), b = __float2bfloat16(hi);
    unsigned ua = *(unsigned short*)&a, ub = *(unsigned short*)&b;
    return (ub << 16) | ua;
}
__device__ __forceinline__ float ulo(unsigned u) { return __uint_as_float(u << 16); }
__device__ __forceinline__ float uhi(unsigned u) { return __uint_as_float(u & 0xffff0000u); }

// ---------------- dtype detection ----------------
__global__ void detect_k(const void* __restrict__ prot,
                         const void* __restrict__ eidx,
                         int* __restrict__ flags) {
    if (blockIdx.x == 0 && threadIdx.x == 0) {
        const bf16* pb = (const bf16*)prot;
        int sane = 0;
        for (int i = 0; i < 64; ++i) {
            float a = fabsf(__bfloat162float(pb[2 * i]));
            if (a > 1e-8f && a < 1e4f) sane++;
        }
        flags[0] = (sane >= 48) ? 0 : 1;
        const unsigned* u = (const unsigned*)eidx;
        int zhi = 0;
        for (int i = 0; i < 32; ++i)
            if (u[2 * i + 1] == 0u) zhi++;
        flags[1] = (zhi >= 30) ? 1 : 0;
    }
}

// ---------------- fused: weight prep + workspace zero + batch cvt ----------------
__global__ __launch_bounds__(256) void prep2_k(const void* __restrict__ W1,
                                               const void* __restrict__ W2,
                                               const int* __restrict__ flags,
                                               short* __restrict__ w1f,
                                               float* __restrict__ w1r,
                                               short* __restrict__ w2f,
                                               int* __restrict__ zreg, int nzero, int nzblk,
                                               const void* __restrict__ batch,
                                               int* __restrict__ b32) {
    const int fp32 = flags[0];
    const int b = blockIdx.x, tid = threadIdx.x;
    if (b < 64) {
        int idx = b * 256 + tid;                    // 16384
        int kp = idx >> 7, n = idx & 127;
        int krow = kp < 64 ? kp : 66 + (kp - 64);
        float v = ldf(W1, (long)krow * 128 + n, fp32);
        int c = n >> 4, nn = n & 15, t = kp >> 5, q = (kp >> 3) & 3, j = kp & 7;
        w1f[(((c * 4 + t) * 4 + q) * 16 + nn) * 8 + j] = f2s(v);
    } else if (b == 64) {
        int which = tid >> 7, n = tid & 127;        // W1 rows 64,65 (spatial)
        w1r[which * 128 + n] = ldf(W1, (long)(64 + which) * 128 + n, fp32);
    } else if (b < 97) {
        int idx = (b - 65) * 256 + tid;             // 8192
        int k = idx >> 6, n = idx & 63;
        float v = ldf(W2, (long)k * 64 + n, fp32);
        int c = n >> 4, nn = n & 15, t = k >> 5, q = (k >> 3) & 3, j = k & 7;
        w2f[(((c * 4 + t) * 4 + q) * 16 + nn) * 8 + j] = f2s(v);
    } else if (b < 97 + nzblk) {
        int i = (b - 97) * 256 + tid;
        if (i < nzero) zreg[i] = 0;
    } else {
        const int i64f = flags[1];
        int i = (b - 97 - nzblk) * 256 + tid;
        if (i < N_NODESC)
            b32[i] = i64f ? (int)((const long long*)batch)[i] : ((const int*)batch)[i];
    }
}

// ---------------- convert + LDS-compacted slice partition ----------------
__global__ __launch_bounds__(256) void cvt_bucket_k(const void* __restrict__ eidx,
                                                    const int* __restrict__ flags,
                                                    int* __restrict__ bcur,
                                                    unsigned* __restrict__ bucket) {
    const int i64f = flags[1];
    const int tid = threadIdx.x;
    const long e0 = (long)blockIdx.x * CH_EPB;
    __shared__ int cnt[9];
    __shared__ int gbase[8];
    __shared__ int cur[8];
    __shared__ unsigned buf[CH_EPB];
    if (tid < 8) cnt[tid] = 0;
    __syncthreads();
    unsigned ev[8];
    int bk[8];
    #pragma unroll
    for (int i = 0; i < 8; ++i) {
        long e = e0 + i * 256 + tid;
        bk[i] = -1;
        if (e < N_EDGESC) {
            int s, d;
            if (i64f) {
                s = (int)((const long long*)eidx)[e];
                d = (int)((const long long*)eidx)[N_EDGESC + e];
            } else {
                s = ((const int*)eidx)[e];
                d = ((const int*)eidx)[N_EDGESC + e];
            }
            int b = d / SLICE_W;
            bk[i] = b;
            ev[i] = (unsigned)s | ((unsigned)(d - b * SLICE_W) << 16);
            atomicAdd(&cnt[b], 1);
        }
    }
    __syncthreads();
    if (tid == 0) {
        int run = 0;
        #pragma unroll
        for (int b = 0; b < 8; ++b) { int c = cnt[b]; cnt[b] = run; run += c; }
        cnt[8] = run;
    }
    __syncthreads();
    if (tid < 8) {
        int c = cnt[tid + 1] - cnt[tid];
        gbase[tid] = c ? atomicAdd(&bcur[tid], c) : 0;
        cur[tid] = cnt[tid];
    }
    __syncthreads();
    #pragma unroll
    for (int i = 0; i < 8; ++i) {
        if (bk[i] >= 0) {
            int p = atomicAdd(&cur[bk[i]], 1);
            buf[p] = ev[i];
        }
    }
    __syncthreads();
    const int total = cnt[8];
    for (int p = tid; p < total; p += 256) {
        int b = 7;
        #pragma unroll
        for (int q = 6; q >= 0; --q)
            if (p < cnt[q + 1]) b = q;
        bucket[(long)b * BCAP + gbase[b] + (p - cnt[b])] = buf[p];
    }
}

// ---------------- sub-partition: slice bucket -> 32 sub-buckets of 196 nodes ----------------
__global__ __launch_bounds__(256) void subpart_k(const unsigned* __restrict__ bucket,
                                                 const int* __restrict__ bcur,
                                                 int* __restrict__ scnt,
                                                 unsigned* __restrict__ bucket2) {
    const int slice = blockIdx.x & 7;
    const int blk = blockIdx.x >> 3;   // 0..31
    const int tid = threadIdx.x;
    const int cnt = bcur[slice];
    const unsigned* B = bucket + (long)slice * BCAP;
    __shared__ unsigned buf[EPB2];
    __shared__ int cnt2[NSUB + 1], gbase[NSUB], cur[NSUB];
    for (int start = blk * EPB2; start < cnt; start += 32 * EPB2) {
        const int csize = min(EPB2, cnt - start);
        if (tid < NSUB) cnt2[tid] = 0;
        __syncthreads();
        for (int i = tid; i < csize; i += 256) {
            unsigned v = B[start + i];
            atomicAdd(&cnt2[(v >> 16) / SUBW], 1);
        }
        __syncthreads();
        if (tid == 0) {
            int run = 0;
            #pragma unroll
            for (int s = 0; s < NSUB; ++s) { int c = cnt2[s]; cnt2[s] = run; run += c; }
            cnt2[NSUB] = run;
        }
        __syncthreads();
        if (tid < NSUB) {
            int c = cnt2[tid + 1] - cnt2[tid];
            gbase[tid] = c ? atomicAdd(&scnt[slice * NSUB + tid], c) : 0;
            cur[tid] = cnt2[tid];
        }
        __syncthreads();
        for (int i = tid; i < csize; i += 256) {
            unsigned v = B[start + i];
            int off = (int)(v >> 16);
            int sub = off / SUBW;
            unsigned nv = (v & 0xffffu) | ((unsigned)(off - sub * SUBW) << 16);
            int p = atomicAdd(&cur[sub], 1);
            buf[p] = nv;
        }
        __syncthreads();
        const int total = cnt2[NSUB];
        for (int p = tid; p < total; p += 256) {
            int lo = 0, hi = NSUB;
            while (hi - lo > 1) { int mid = (lo + hi) >> 1; if (p >= cnt2[mid]) lo = mid; else hi = mid; }
            bucket2[((long)slice * NSUB + lo) * SBCAP + gbase[lo] + (p - cnt2[lo])] = buf[p];
        }
        __syncthreads();
    }
}

// ---------------- fused CSR build: histogram + decoupled-lookback scan + scatter ----------------
__global__ __launch_bounds__(256) void csr_k(const unsigned* __restrict__ bucket2,
                                             const int* __restrict__ scnt,
                                             int* __restrict__ state,
                                             int* __restrict__ row_start,
                                             unsigned short* __restrict__ col) {
    const int sb = blockIdx.x;
    const int slice = sb >> 5, sub = sb & 31;
    const int tid = threadIdx.x;
    const int lane = tid & 63;
    const int cnt = scnt[sb];
    const unsigned* B = bucket2 + (long)sb * SBCAP;
    __shared__ int lh[SUBW];
    __shared__ int sc[256];
    __shared__ int sprefix_sh;
    const int width = min(SUBW, SLICE_W - sub * SUBW);
    const int nodebase = slice * SLICE_W + sub * SUBW;
    for (int i = tid; i < SUBW; i += 256) lh[i] = 0;
    __syncthreads();
    for (int e = tid; e < cnt; e += 256) atomicAdd(&lh[B[e] >> 16], 1);
    __syncthreads();
    const int myc = (tid < SUBW) ? lh[tid] : 0;
    sc[tid] = myc;
    __syncthreads();
    for (int off = 1; off < 256; off <<= 1) {
        int t = (tid >= off) ? sc[tid - off] : 0;
        __syncthreads();
        sc[tid] += t;
        __syncthreads();
    }
    const int total = sc[255];
    if (tid == 0)
        __hip_atomic_store(&state[sb], (int)((1u << 30) | (unsigned)total),
                           __ATOMIC_RELEASE, __HIP_MEMORY_SCOPE_AGENT);
    if (tid < 64) {
        int prefix = 0;
        if (sb > 0) {
            int base = sb;
            for (;;) {
                int t = base - 1 - lane;
                int v = 0;
                if (t >= 0) {
                    for (;;) {
                        v = __hip_atomic_load(&state[t], __ATOMIC_ACQUIRE,
                                              __HIP_MEMORY_SCOPE_AGENT);
                        if ((unsigned)v >= (1u << 30)) break;
                        __builtin_amdgcn_s_sleep(1);
                    }
                }
                int flag = (int)(((unsigned)v) >> 30);
                int val = v & 0x3fffffff;
                unsigned long long pmask = __ballot(flag == 2 && t >= 0);
                int stop_tid = pmask ? (__ffsll((long long)pmask) - 1) : 64;
                int contrib = 0;
                if (t >= 0 && lane <= stop_tid) contrib = val;
                #pragma unroll
                for (int off = 32; off; off >>= 1) contrib += __shfl_xor(contrib, off, 64);
                prefix += contrib;
                if (pmask || base <= 64) break;
                base -= 64;
            }
        }
        if (tid == 0) {
            sprefix_sh = prefix;
            __hip_atomic_store(&state[sb],
                               (int)((2u << 30) | (unsigned)(prefix + total)),
                               __ATOMIC_RELEASE, __HIP_MEMORY_SCOPE_AGENT);
        }
    }
    __syncthreads();
    const int sprefix = sprefix_sh;
    if (tid < width) row_start[nodebase + tid] = sprefix + sc[tid] - myc;
    if (sb == 255 && tid == 0) row_start[N_NODESC] = sprefix + total;
    if (tid < SUBW) lh[tid] = sprefix + sc[tid] - myc;   // cursor
    __syncthreads();
    for (int e = tid; e < cnt; e += 256) {
        unsigned v = B[e];
        int pos = atomicAdd(&lh[v >> 16], 1);
        col[pos] = (unsigned short)(v & 0xffffu);
    }
}

// ---------------- Layer 1 GEMM via MFMA + fused logits (head-split outputs) ----------------

__global__ __launch_bounds__(256) void gemm1_k(
        const void* __restrict__ prot, const void* __restrict__ sp,
        const void* __restrict__ lri,
        const short* __restrict__ w1f, const float* __restrict__ w1r,
        const void* __restrict__ as1, const void* __restrict__ ad1,
        const int* __restrict__ flags,
        short* __restrict__ xph0, short* __restrict__ xph1,
        float* __restrict__ alsrc, float* __restrict__ aldst) {
    const int fp32 = flags[0];
    const int tid = threadIdx.x;
    const int nb = blockIdx.x * 32;
    __shared__ __align__(16) short xs[32][136];   // K order: prot 0..63, lri 0..63
    __shared__ float xsp[32][2];                  // spatial remainder
    __shared__ float sredc[32][8], dredc[32][8];  // [row][col-block]

    if (!fp32) {
        #pragma unroll
        for (int i = 0; i < 2; ++i) {
            int cidx = i * 256 + tid;             // 512 chunks of 8 shorts
            int r = cidx >> 4, cc = cidx & 15;
            int g = nb + r;
            short8 v = (short8){0, 0, 0, 0, 0, 0, 0, 0};
            if (g < N_NODESC) {
                const short* srcp = (cc < 8)
                    ? (const short*)prot + (long)g * 64 + cc * 8
                    : (const short*)lri + (long)g * 64 + (cc - 8) * 8;
                v = *(const short8*)srcp;
            }
            *(short8*)&xs[r][cc * 8] = v;
        }
    } else {
        #pragma unroll
        for (int i = 0; i < 16; ++i) {
            int idx = i * 256 + tid;
            int r = idx >> 7, k = idx & 127;
            int g = nb + r;
            float v = 0.f;
            if (g < N_NODESC)
                v = (k < 64) ? ((const float*)prot)[(long)g * 64 + k]
                             : ((const float*)lri)[(long)g * 64 + (k - 64)];
            xs[r][k] = f2s(v);
        }
    }
    if (tid < 64) {
        int r = tid >> 1, which = tid & 1;
        int g = nb + r;
        xsp[r][which] = (g < N_NODESC) ? ldf(sp, (long)g * 2 + which, fp32) : 0.f;
    }
    __syncthreads();

    const int wid = tid >> 6, lane = tid & 63;
    const int quad = lane >> 4, l16 = lane & 15;
    floatx4 acc[2][2];
    #pragma unroll
    for (int a = 0; a < 2; ++a)
        #pragma unroll
        for (int b = 0; b < 2; ++b) acc[a][b] = (floatx4){0.f, 0.f, 0.f, 0.f};

    const int c0 = 2 * wid;
    #pragma unroll
    for (int t = 0; t < 4; ++t) {
        short8 a0 = *(const short8*)&xs[l16][t * 32 + quad * 8];
        short8 a1 = *(const short8*)&xs[16 + l16][t * 32 + quad * 8];
        short8 b0 = *(const short8*)&w1f[(((c0 * 4 + t) * 4 + quad) * 16 + l16) * 8];
        short8 b1 = *(const short8*)&w1f[((((c0 + 1) * 4 + t) * 4 + quad) * 16 + l16) * 8];
        acc[0][0] = __builtin_amdgcn_mfma_f32_16x16x32_bf16(a0, b0, acc[0][0], 0, 0, 0);
        acc[0][1] = __builtin_amdgcn_mfma_f32_16x16x32_bf16(a0, b1, acc[0][1], 0, 0, 0);
        acc[1][0] = __builtin_amdgcn_mfma_f32_16x16x32_bf16(a1, b0, acc[1][0], 0, 0, 0);
        acc[1][1] = __builtin_amdgcn_mfma_f32_16x16x32_bf16(a1, b1, acc[1][1], 0, 0, 0);
    }
    #pragma unroll
    for (int ci = 0; ci < 2; ++ci) {
        int colg = (c0 + ci) * 16 + l16;
        float w0 = w1r[colg], w1v = w1r[128 + colg];
        float asv = ldf(as1, colg, fp32), adv = ldf(ad1, colg, fp32);
        short* xpd = (colg < 64) ? xph0 : xph1;
        const int cc = colg & 63;
        #pragma unroll
        for (int rt = 0; rt < 2; ++rt) {
            float sv[4], dv[4];
            #pragma unroll
            for (int reg = 0; reg < 4; ++reg) {
                int row = rt * 16 + quad * 4 + reg;
                int g = nb + row;
                float v = acc[rt][ci][reg] + xsp[row][0] * w0 + xsp[row][1] * w1v;
                if (g < N_NODESC) xpd[(long)g * 64 + cc] = f2s(v);
                sv[reg] = v * asv;
                dv[reg] = v * adv;
            }
            #pragma unroll
            for (int off = 1; off < 16; off <<= 1) {
                #pragma unroll
                for (int reg = 0; reg < 4; ++reg) {
                    sv[reg] += __shfl_xor(sv[reg], off, 64);
                    dv[reg] += __shfl_xor(dv[reg], off, 64);
                }
            }
            if (l16 == 0) {
                #pragma unroll
                for (int reg = 0; reg < 4; ++reg) {
                    int row = rt * 16 + quad * 4 + reg;
                    sredc[row][c0 + ci] = sv[reg];
                    dredc[row][c0 + ci] = dv[reg];
                }
            }
        }
    }
    __syncthreads();
    if (tid < 64) {
        int r = tid >> 1, h = tid & 1;
        int g = nb + r;
        if (g < N_NODESC) {
            alsrc[(long)h * N_NODESC + g] = sredc[r][4 * h] + sredc[r][4 * h + 1] +
                                            sredc[r][4 * h + 2] + sredc[r][4 * h + 3];
            aldst[(long)h * N_NODESC + g] = dredc[r][4 * h] + dredc[r][4 * h + 1] +
                                            dredc[r][4 * h + 2] + dredc[r][4 * h + 3];
        }
    }
}

// ---------------- Layer 1 aggregation: split-wave, both heads in one launch ----------------
// Each 32-lane half-wave owns ONE node: e = (lane&31)>>3 edge slot (4 edges/pass),
// c = lane&7 -> 16B of the 128B per-head row. Two independent dependency chains
// per wave double memory-level parallelism. Blocks 0..6249 head0, 6250.. head1
// (dispatch order preserves the per-head working-set phase). Shuffle offsets
// <=16 never cross the 32-lane boundary. Self seeded in e==0 only.

__global__ __launch_bounds__(256) void agg1s_k(
        const int* __restrict__ row_start, const unsigned short* __restrict__ col,
        const short* __restrict__ xph0, const short* __restrict__ xph1,
        const float* __restrict__ als, const float* __restrict__ ald,
        const void* __restrict__ b1, const int* __restrict__ flags,
        unsigned* __restrict__ h1b32) {
    const int fp32 = flags[0];
    const int tid = threadIdx.x;
    const int wid = tid >> 6;
    const int lane = tid & 63;
    const int hw = lane >> 5;         // half-wave = node parity
    const int hl = lane & 31;
    const int head = blockIdx.x >= AGG_NB;
    const int b = blockIdx.x - head * AGG_NB;
    const int n = b * 8 + wid * 2 + hw;
    __shared__ float2 pbuf[4][2][32];
    float2* mybuf = pbuf[wid][hw];
    const short* xph = head ? xph1 : xph0;
    const float* alsh = als + (long)head * N_NODESC;
    const float* aldh = ald + (long)head * N_NODESC;
    const int e = hl >> 3;
    const int c = hl & 7;
    const char* xpb = (const char*)xph;
    const int c16 = c * 16;
    const float ad = aldh[n];
    float e0 = alsh[n] + ad;
    e0 = e0 > 0.f ? e0 : 0.2f * e0;
    const float pself = __expf(e0);
    const float pinit = e == 0 ? pself : 0.f;
    uint4 us = *(const uint4*)(xpb + (long)n * 128 + c16);
    float acc0 = pinit * ulo(us.x), acc1 = pinit * uhi(us.x);
    float acc2 = pinit * ulo(us.y), acc3 = pinit * uhi(us.y);
    float acc4 = pinit * ulo(us.z), acc5 = pinit * uhi(us.z);
    float acc6 = pinit * ulo(us.w), acc7 = pinit * uhi(us.w);
    float lp = 0.f;
    const int beg = row_start[n], end = row_start[n + 1];
    for (int base = beg; base < end; base += 32) {
        const int idx = base + hl;
        int s = 0;
        float p = 0.f;
        if (idx < end) {
            s = (int)col[idx];
            float t = alsh[s] + ad;
            t = t > 0.f ? t : 0.2f * t;
            p = __expf(t);
        }
        lp += p;
        mybuf[hl] = make_float2(p, __int_as_float(s << 7));
        int cnt = end - base; if (cnt > 32) cnt = 32;
        int quads = (cnt + 3) >> 2;
        int j = 0;
        for (; j + 4 <= quads; j += 4) {
            int a4[4]; float p4[4]; uint4 x[4];
            #pragma unroll
            for (int q = 0; q < 4; ++q) {
                float2 bv = mybuf[4 * (j + q) + e];
                a4[q] = __float_as_int(bv.y);
                p4[q] = bv.x;
            }
            #pragma unroll
            for (int q = 0; q < 4; ++q)
                x[q] = *(const uint4*)(xpb + a4[q] + c16);
            #pragma unroll
            for (int q = 0; q < 4; ++q) {
                acc0 = fmaf(p4[q], ulo(x[q].x), acc0);
                acc1 = fmaf(p4[q], uhi(x[q].x), acc1);
                acc2 = fmaf(p4[q], ulo(x[q].y), acc2);
                acc3 = fmaf(p4[q], uhi(x[q].y), acc3);
                acc4 = fmaf(p4[q], ulo(x[q].z), acc4);
                acc5 = fmaf(p4[q], uhi(x[q].z), acc5);
                acc6 = fmaf(p4[q], ulo(x[q].w), acc6);
                acc7 = fmaf(p4[q], uhi(x[q].w), acc7);
            }
        }
        for (; j < quads; ++j) {
            float2 bv = mybuf[4 * j + e];
            uint4 x = *(const uint4*)(xpb + __float_as_int(bv.y) + c16);
            float pv = bv.x;
            acc0 = fmaf(pv, ulo(x.x), acc0);
            acc1 = fmaf(pv, uhi(x.x), acc1);
            acc2 = fmaf(pv, ulo(x.y), acc2);
            acc3 = fmaf(pv, uhi(x.y), acc3);
            acc4 = fmaf(pv, ulo(x.z), acc4);
            acc5 = fmaf(pv, uhi(x.z), acc5);
            acc6 = fmaf(pv, ulo(x.w), acc6);
            acc7 = fmaf(pv, uhi(x.w), acc7);
        }
    }
    #pragma unroll
    for (int off = 16; off; off >>= 1) lp += __shfl_xor(lp, off, 64);
    #pragma unroll
    for (int off = 8; off <= 16; off <<= 1) {
        acc0 += __shfl_xor(acc0, off, 64);
        acc1 += __shfl_xor(acc1, off, 64);
        acc2 += __shfl_xor(acc2, off, 64);
        acc3 += __shfl_xor(acc3, off, 64);
        acc4 += __shfl_xor(acc4, off, 64);
        acc5 += __shfl_xor(acc5, off, 64);
        acc6 += __shfl_xor(acc6, off, 64);
        acc7 += __shfl_xor(acc7, off, 64);
    }
    if (hl < 8) {
        const float rl = 1.f / (lp + pself);
        const long bb = (long)head * 64 + 8 * c;
        float o0 = acc0 * rl + ldf(b1, bb + 0, fp32);
        float o1 = acc1 * rl + ldf(b1, bb + 1, fp32);
        float o2 = acc2 * rl + ldf(b1, bb + 2, fp32);
        float o3 = acc3 * rl + ldf(b1, bb + 3, fp32);
        float o4 = acc4 * rl + ldf(b1, bb + 4, fp32);
        float o5 = acc5 * rl + ldf(b1, bb + 5, fp32);
        float o6 = acc6 * rl + ldf(b1, bb + 6, fp32);
        float o7 = acc7 * rl + ldf(b1, bb + 7, fp32);
        uint4 o;
        o.x = pack2(o0, o1); o.y = pack2(o2, o3);
        o.z = pack2(o4, o5); o.w = pack2(o6, o7);
        *(uint4*)((char*)h1b32 + (long)n * 256 + head * 128 + c16) = o;
    }
}

// ---------------- Layer 2 GEMM via MFMA + fused logits (shuffle reduce) ----------------

__global__ __launch_bounds__(256) void gemm2_k(
        const unsigned* __restrict__ h1b32, const short* __restrict__ w2f,
        const void* __restrict__ as2, const void* __restrict__ ad2,
        const int* __restrict__ flags,
        short* __restrict__ xp2b, float* __restrict__ alsrc, float* __restrict__ aldst) {
    const int fp32 = flags[0];
    const int tid = threadIdx.x;
    const int nb = blockIdx.x * 32;
    __shared__ __align__(16) short xs[32][136];
    __shared__ float sredc[32][4], dredc[32][4];

    #pragma unroll
    for (int i = 0; i < 8; ++i) {
        int idx = i * 256 + tid;
        int r = idx >> 6, ii = idx & 63;
        int g = nb + r;
        unsigned val = (g < N_NODESC) ? h1b32[(long)g * 64 + ii] : 0u;
        ((unsigned*)&xs[r][0])[ii] = val;
    }
    __syncthreads();

    const int wid = tid >> 6, lane = tid & 63;
    const int quad = lane >> 4, l16 = lane & 15;
    floatx4 acc0 = (floatx4){0.f, 0.f, 0.f, 0.f};
    floatx4 acc1 = (floatx4){0.f, 0.f, 0.f, 0.f};
    #pragma unroll
    for (int t = 0; t < 4; ++t) {
        short8 a0 = *(const short8*)&xs[l16][t * 32 + quad * 8];
        short8 a1 = *(const short8*)&xs[16 + l16][t * 32 + quad * 8];
        short8 b = *(const short8*)&w2f[(((wid * 4 + t) * 4 + quad) * 16 + l16) * 8];
        acc0 = __builtin_amdgcn_mfma_f32_16x16x32_bf16(a0, b, acc0, 0, 0, 0);
        acc1 = __builtin_amdgcn_mfma_f32_16x16x32_bf16(a1, b, acc1, 0, 0, 0);
    }
    const int colg = wid * 16 + l16;
    const float asv = ldf(as2, colg, fp32), adv = ldf(ad2, colg, fp32);
    float sv0[4], dv0[4], sv1[4], dv1[4];
    #pragma unroll
    for (int reg = 0; reg < 4; ++reg) {
        int r0 = quad * 4 + reg;
        int g0 = nb + r0;
        int g1 = g0 + 16;
        if (g0 < N_NODESC) xp2b[(long)g0 * 64 + colg] = f2s(acc0[reg]);
        if (g1 < N_NODESC) xp2b[(long)g1 * 64 + colg] = f2s(acc1[reg]);
        sv0[reg] = acc0[reg] * asv; dv0[reg] = acc0[reg] * adv;
        sv1[reg] = acc1[reg] * asv; dv1[reg] = acc1[reg] * adv;
    }
    #pragma unroll
    for (int off = 1; off < 16; off <<= 1) {
        #pragma unroll
        for (int reg = 0; reg < 4; ++reg) {
            sv0[reg] += __shfl_xor(sv0[reg], off, 64);
            dv0[reg] += __shfl_xor(dv0[reg], off, 64);
            sv1[reg] += __shfl_xor(sv1[reg], off, 64);
            dv1[reg] += __shfl_xor(dv1[reg], off, 64);
        }
    }
    if (l16 == 0) {
        #pragma unroll
        for (int reg = 0; reg < 4; ++reg) {
            int r0 = quad * 4 + reg;
            sredc[r0][wid] = sv0[reg];      dredc[r0][wid] = dv0[reg];
            sredc[r0 + 16][wid] = sv1[reg]; dredc[r0 + 16][wid] = dv1[reg];
        }
    }
    __syncthreads();
    if (tid < 32) {
        int g = nb + tid;
        if (g < N_NODESC) {
            alsrc[g] = sredc[tid][0] + sredc[tid][1] + sredc[tid][2] + sredc[tid][3];
            aldst[g] = dredc[tid][0] + dredc[tid][1] + dredc[tid][2] + dredc[tid][3];
        }
    }
}

// ---------------- Layer 2 aggregation: split-wave + fused mean-pool (replicated) ----------------

__global__ __launch_bounds__(256) void agg2p_k(
        const int* __restrict__ row_start, const unsigned short* __restrict__ col,
        const short* __restrict__ xp2b, const float* __restrict__ alsrc,
        const float* __restrict__ aldst, const void* __restrict__ b2v,
        const int* __restrict__ flags, const int* __restrict__ batch32,
        float* __restrict__ pooled, float* __restrict__ counts) {
    const int fp32 = flags[0];
    const int tid = threadIdx.x;
    const int wid = tid >> 6;
    const int lane = tid & 63;
    const int hw = lane >> 5;
    const int hl = lane & 31;
    const int n = blockIdx.x * 8 + wid * 2 + hw;
    const int rep = blockIdx.x & (POOL_REP - 1);
    __shared__ float2 pbuf[4][2][32];
    __shared__ float psum[64];
    __shared__ int ginfo[2];
    if (tid < 64) psum[tid] = 0.f;
    if (tid == 0) {
        int g0 = batch32[blockIdx.x * 8];
        int g7 = batch32[blockIdx.x * 8 + 7];
        ginfo[0] = g0;
        ginfo[1] = (g0 == g7);
    }
    __syncthreads();
    float2* mybuf = pbuf[wid][hw];
    const int e = hl >> 3;
    const int c = hl & 7;
    const char* xpb = (const char*)xp2b;
    const int c16 = c * 16;
    const float ad = aldst[n];
    float e0 = alsrc[n] + ad;
    e0 = e0 > 0.f ? e0 : 0.2f * e0;
    const float pself = __expf(e0);
    const float pinit = e == 0 ? pself : 0.f;
    uint4 us = *(const uint4*)(xpb + (long)n * 128 + c16);
    float acc0 = pinit * ulo(us.x), acc1 = pinit * uhi(us.x);
    float acc2 = pinit * ulo(us.y), acc3 = pinit * uhi(us.y);
    float acc4 = pinit * ulo(us.z), acc5 = pinit * uhi(us.z);
    float acc6 = pinit * ulo(us.w), acc7 = pinit * uhi(us.w);
    float lp = 0.f;
    const int beg = row_start[n], end = row_start[n + 1];
    for (int base = beg; base < end; base += 32) {
        const int idx = base + hl;
        int s = 0;
        float p = 0.f;
        if (idx < end) {
            s = (int)col[idx];
            float t = alsrc[s] + ad;
            t = t > 0.f ? t : 0.2f * t;
            p = __expf(t);
        }
        lp += p;
        mybuf[hl] = make_float2(p, __int_as_float(s << 7));
        int cnt = end - base; if (cnt > 32) cnt = 32;
        int quads = (cnt + 3) >> 2;
        int j = 0;
        for (; j + 4 <= quads; j += 4) {
            int a4[4]; float p4[4]; uint4 x[4];
            #pragma unroll
            for (int q = 0; q < 4; ++q) {
                float2 bv = mybuf[4 * (j + q) + e];
                a4[q] = __float_as_int(bv.y);
                p4[q] = bv.x;
            }
            #pragma unroll
            for (int q = 0; q < 4; ++q)
                x[q] = *(const uint4*)(xpb + a4[q] + c16);
            #pragma unroll
            for (int q = 0; q < 4; ++q) {
                acc0 = fmaf(p4[q], ulo(x[q].x), acc0);
                acc1 = fmaf(p4[q], uhi(x[q].x), acc1);
                acc2 = fmaf(p4[q], ulo(x[q].y), acc2);
                acc3 = fmaf(p4[q], uhi(x[q].y), acc3);
                acc4 = fmaf(p4[q], ulo(x[q].z), acc4);
                acc5 = fmaf(p4[q], uhi(x[q].z), acc5);
                acc6 = fmaf(p4[q], ulo(x[q].w), acc6);
                acc7 = fmaf(p4[q], uhi(x[q].w), acc7);
            }
        }
        for (; j < quads; ++j) {
            float2 bv = mybuf[4 * j + e];
            uint4 x = *(const uint4*)(xpb + __float_as_int(bv.y) + c16);
            float pv = bv.x;
            acc0 = fmaf(pv, ulo(x.x), acc0);
            acc1 = fmaf(pv, uhi(x.x), acc1);
            acc2 = fmaf(pv, ulo(x.y), acc2);
            acc3 = fmaf(pv, uhi(x.y), acc3);
            acc4 = fmaf(pv, ulo(x.z), acc4);
            acc5 = fmaf(pv, uhi(x.z), acc5);
            acc6 = fmaf(pv, ulo(x.w), acc6);
            acc7 = fmaf(pv, uhi(x.w), acc7);
        }
    }
    #pragma unroll
    for (int off = 16; off; off >>= 1) lp += __shfl_xor(lp, off, 64);
    #pragma unroll
    for (int off = 8; off <= 16; off <<= 1) {
        acc0 += __shfl_xor(acc0, off, 64);
        acc1 += __shfl_xor(acc1, off, 64);
        acc2 += __shfl_xor(acc2, off, 64);
        acc3 += __shfl_xor(acc3, off, 64);
        acc4 += __shfl_xor(acc4, off, 64);
        acc5 += __shfl_xor(acc5, off, 64);
        acc6 += __shfl_xor(acc6, off, 64);
        acc7 += __shfl_xor(acc7, off, 64);
    }
    float o[8];
    if (hl < 8) {
        const float rl = 1.f / (lp + pself);
        o[0] = acc0 * rl + ldf(b2v, 8 * c + 0, fp32);
        o[1] = acc1 * rl + ldf(b2v, 8 * c + 1, fp32);
        o[2] = acc2 * rl + ldf(b2v, 8 * c + 2, fp32);
        o[3] = acc3 * rl + ldf(b2v, 8 * c + 3, fp32);
        o[4] = acc4 * rl + ldf(b2v, 8 * c + 4, fp32);
        o[5] = acc5 * rl + ldf(b2v, 8 * c + 5, fp32);
        o[6] = acc6 * rl + ldf(b2v, 8 * c + 6, fp32);
        o[7] = acc7 * rl + ldf(b2v, 8 * c + 7, fp32);
    }
    if (ginfo[1]) {
        if (hl < 8) {
            #pragma unroll
            for (int j = 0; j < 8; ++j) atomicAdd(&psum[8 * c + j], o[j]);
        }
        __syncthreads();
        if (tid < 64)
            atomicAdd(&pooled[((long)rep * NUM_GRAPHSC + ginfo[0]) * 64 + tid], psum[tid]);
        if (tid == 0) atomicAdd(&counts[rep * NUM_GRAPHSC + ginfo[0]], 8.f);
    } else {
        int g = batch32[n];
        if (hl < 8) {
            #pragma unroll
            for (int j = 0; j < 8; ++j)
                atomicAdd(&pooled[((long)rep * NUM_GRAPHSC + g) * 64 + 8 * c + j], o[j]);
        }
        if (hl == 0) atomicAdd(&counts[rep * NUM_GRAPHSC + g], 1.f);
    }
}

// ---------------- decoder MLP (sums pooled replicas) ----------------

__global__ __launch_bounds__(64) void dec_k(const float* __restrict__ pooled,
                                            const float* __restrict__ counts,
                                            const void* __restrict__ Wd1, const void* __restrict__ bd1,
                                            const void* __restrict__ Wd2, const void* __restrict__ bd2,
                                            const int* __restrict__ flags,
                                            void* __restrict__ out) {
    const int fp32 = flags[0];
    const int g = blockIdx.x, j = threadIdx.x;
    __shared__ float p[64], dh[64];
    float cnt = 0.f, ps = 0.f;
    #pragma unroll
    for (int r = 0; r < POOL_REP; ++r) {
        ps += pooled[((long)r * NUM_GRAPHSC + g) * 64 + j];
        if (j == 0) cnt += counts[r * NUM_GRAPHSC + g];
    }
    __shared__ float cnt_sh;
    if (j == 0) cnt_sh = cnt < 1.f ? 1.f : cnt;
    __syncthreads();
    p[j] = ps / cnt_sh;
    __syncthreads();
    float acc = ldf(bd1, j, fp32);
    for (int k = 0; k < 64; ++k) acc += p[k] * ldf(Wd1, k * 64 + j, fp32);
    dh[j] = acc > 0.f ? acc : 0.f;
    __syncthreads();
    if (j < 32) {
        float o = ldf(bd2, j, fp32);
        for (int k = 0; k < 64; ++k) o += dh[k] * ldf(Wd2, k * 32 + j, fp32);
        if (fp32) ((float*)out)[g * 32 + j] = o;
        else      ((bf16*)out)[g * 32 + j] = __float2bfloat16(o);
    }
}

extern "C" void kernel_launch(void* const* d_in, const int* in_sizes, int n_in,
                              void* d_out, int out_size, void* d_ws, size_t ws_size,
                              hipStream_t stream) {
    (void)in_sizes; (void)n_in; (void)out_size; (void)ws_size;
    const void* prot = d_in[0];
    const void* sp   = d_in[1];
    const void* lri  = d_in[2];
    const void* eidx = d_in[3];
    const void* batch= d_in[4];
    const void* W1   = d_in[5];
    const void* as1  = d_in[6];
    const void* ad1  = d_in[7];
    const void* b1   = d_in[8];
    const void* W2   = d_in[9];
    const void* as2  = d_in[10];
    const void* ad2  = d_in[11];
    const void* b2v  = d_in[12];
    const void* Wd1  = d_in[13];
    const void* bd1  = d_in[14];
    const void* Wd2  = d_in[15];
    const void* bd2  = d_in[16];

    char* w = (char*)d_ws;
    auto alloc = [&](size_t bytes) -> void* {
        char* p = w;
        w += (bytes + 255) & ~(size_t)255;
        return (void*)p;
    };
    int*   flags     = (int*)alloc(2 * 4);
    // --- contiguous zero region: pooled .. state ---
    float* pooled    = (float*)alloc((size_t)POOL_REP * NUM_GRAPHSC * 64 * 4);
    float* counts    = (float*)alloc((size_t)POOL_REP * NUM_GRAPHSC * 4);
    int*   bcur      = (int*)alloc((size_t)8 * 4);
    int*   scnt      = (int*)alloc((size_t)256 * 4);
    int*   state     = (int*)alloc((size_t)256 * 4);
    char*  zero_end  = w;
    // ----------------------------------------------
    int*   batch32   = (int*)alloc((size_t)N_NODESC * 4);
    int*   row_start = (int*)alloc((size_t)(N_NODESC + 1) * 4);
    unsigned* bucket = (unsigned*)alloc((size_t)8 * BCAP * 4);
    unsigned* bucket2= (unsigned*)alloc((size_t)256 * SBCAP * 4);
    unsigned short* col = (unsigned short*)alloc((size_t)N_EDGESC * 2);
    short* w1f       = (short*)alloc((size_t)16384 * 2);
    float* w1r       = (float*)alloc((size_t)256 * 4);
    short* w2f       = (short*)alloc((size_t)8192 * 2);
    short* xph0      = (short*)alloc((size_t)N_NODESC * 64 * 2);
    short* xph1      = (short*)alloc((size_t)N_NODESC * 64 * 2);
    float* alsrc1    = (float*)alloc((size_t)N_NODESC * 2 * 4);
    float* aldst1    = (float*)alloc((size_t)N_NODESC * 2 * 4);
    short* h1b       = (short*)alloc((size_t)N_NODESC * 128 * 2);
    short* xp2b      = (short*)alloc((size_t)N_NODESC * 64 * 2);
    float* alsrc2    = (float*)alloc((size_t)N_NODESC * 4);
    float* aldst2    = (float*)alloc((size_t)N_NODESC * 4);

    const int nzero = (int)((zero_end - (char*)pooled) / 4);
    const int nzblk = (nzero + 255) / 256;
    const int nbat  = (N_NODESC + 255) / 256;

    detect_k<<<1, 64, 0, stream>>>(prot, eidx, flags);
    prep2_k<<<97 + nzblk + nbat, 256, 0, stream>>>(W1, W2, flags, w1f, w1r, w2f,
                                                   (int*)pooled, nzero, nzblk,
                                                   batch, batch32);
    cvt_bucket_k<<<(N_EDGESC + CH_EPB - 1) / CH_EPB, 256, 0, stream>>>(eidx, flags, bcur, bucket);
    subpart_k<<<8 * 32, 256, 0, stream>>>(bucket, bcur, scnt, bucket2);
    csr_k<<<256, 256, 0, stream>>>(bucket2, scnt, state, row_start, col);

    const int nblk = (N_NODESC + 31) / 32;
    gemm1_k<<<nblk, 256, 0, stream>>>(prot, sp, lri, w1f, w1r, as1, ad1, flags,
                                      xph0, xph1, alsrc1, aldst1);
    agg1s_k<<<2 * AGG_NB, 256, 0, stream>>>(row_start, col, xph0, xph1,
                                            alsrc1, aldst1, b1, flags,
                                            (unsigned*)h1b);
    gemm2_k<<<nblk, 256, 0, stream>>>((const unsigned*)h1b, w2f, as2, ad2, flags,
                                      xp2b, alsrc2, aldst2);
    agg2p_k<<<AGG_NB, 256, 0, stream>>>(row_start, col, xp2b, alsrc2, aldst2,
                                        b2v, flags, batch32, pooled, counts);
    dec_k<<<NUM_GRAPHSC, 64, 0, stream>>>(pooled, counts, Wd1, bd1, Wd2, bd2, flags, d_out);
}

// Round 7
// 314.266 us; speedup vs baseline: 1.3283x; 1.0560x over previous
//
#include <hip/hip_runtime.h>
#include <hip/hip_bf16.h>

#define N_NODESC 50000
#define N_EDGESC 1600000
#define NUM_GRAPHSC 64
#define P_EPB 2048            // edges per block in part_k
#define SUBW 196              // nodes per sub-bucket (256 buckets cover 50000)
#define NSB 256               // number of sub-buckets
#define SBCAP 8192            // per-sub-bucket capacity (avg 6272, max ~6600)
#define POOL_REP 32           // pooled replicas to kill atomic contention
#define AGG_NB 6250           // 50000 / 8 nodes per block (split-wave)

typedef __hip_bfloat16 bf16;
typedef short short8 __attribute__((ext_vector_type(8)));
typedef float floatx4 __attribute__((ext_vector_type(4)));

__device__ __forceinline__ float ldf(const void* p, long i, int fp32) {
    return fp32 ? ((const float*)p)[i] : __bfloat162float(((const bf16*)p)[i]);
}
__device__ __forceinline__ short f2s(float v) {
    bf16 h = __float2bfloat16(v);
    return *(short*)&h;
}
__device__ __forceinline__ unsigned pack2(float lo, float hi) {
    bf16 a = __float2bfloat16(lo), b = __float2bfloat16(hi);
    unsigned ua = *(unsigned short*)&a, ub = *(unsigned short*)&b;
    return (ub << 16) | ua;
}
__device__ __forceinline__ float ulo(unsigned u) { return __uint_as_float(u << 16); }
__device__ __forceinline__ float uhi(unsigned u) { return __uint_as_float(u & 0xffff0000u); }

// ---------------- dtype detection ----------------
__global__ void detect_k(const void* __restrict__ prot,
                         const void* __restrict__ eidx,
                         int* __restrict__ flags) {
    if (blockIdx.x == 0 && threadIdx.x == 0) {
        const bf16* pb = (const bf16*)prot;
        int sane = 0;
        for (int i = 0; i < 64; ++i) {
            float a = fabsf(__bfloat162float(pb[2 * i]));
            if (a > 1e-8f && a < 1e4f) sane++;
        }
        flags[0] = (sane >= 48) ? 0 : 1;
        const unsigned* u = (const unsigned*)eidx;
        int zhi = 0;
        for (int i = 0; i < 32; ++i)
            if (u[2 * i + 1] == 0u) zhi++;
        flags[1] = (zhi >= 30) ? 1 : 0;
    }
}

// ---------------- fused: weight prep + workspace zero + batch cvt ----------------
__global__ __launch_bounds__(256) void prep2_k(const void* __restrict__ W1,
                                               const void* __restrict__ W2,
                                               const int* __restrict__ flags,
                                               short* __restrict__ w1f,
                                               float* __restrict__ w1r,
                                               short* __restrict__ w2f,
                                               int* __restrict__ zreg, int nzero, int nzblk,
                                               const void* __restrict__ batch,
                                               int* __restrict__ b32) {
    const int fp32 = flags[0];
    const int b = blockIdx.x, tid = threadIdx.x;
    if (b < 64) {
        int idx = b * 256 + tid;                    // 16384
        int kp = idx >> 7, n = idx & 127;
        int krow = kp < 64 ? kp : 66 + (kp - 64);
        float v = ldf(W1, (long)krow * 128 + n, fp32);
        int c = n >> 4, nn = n & 15, t = kp >> 5, q = (kp >> 3) & 3, j = kp & 7;
        w1f[(((c * 4 + t) * 4 + q) * 16 + nn) * 8 + j] = f2s(v);
    } else if (b == 64) {
        int which = tid >> 7, n = tid & 127;        // W1 rows 64,65 (spatial)
        w1r[which * 128 + n] = ldf(W1, (long)(64 + which) * 128 + n, fp32);
    } else if (b < 97) {
        int idx = (b - 65) * 256 + tid;             // 8192
        int k = idx >> 6, n = idx & 63;
        float v = ldf(W2, (long)k * 64 + n, fp32);
        int c = n >> 4, nn = n & 15, t = k >> 5, q = (k >> 3) & 3, j = k & 7;
        w2f[(((c * 4 + t) * 4 + q) * 16 + nn) * 8 + j] = f2s(v);
    } else if (b < 97 + nzblk) {
        int i = (b - 97) * 256 + tid;
        if (i < nzero) zreg[i] = 0;
    } else {
        const int i64f = flags[1];
        int i = (b - 97 - nzblk) * 256 + tid;
        if (i < N_NODESC)
            b32[i] = i64f ? (int)((const long long*)batch)[i] : ((const int*)batch)[i];
    }
}

// ---------------- direct 256-way partition: edge list -> bucket2 in ONE pass ----------------
// Replaces cvt_bucket + subpart. Per 2048-edge chunk: 256-bin LDS histogram ->
// 256-wide scan -> LDS compaction -> coalesced per-bucket writes.
// d/196 == (d>>2)/49 exactly (nested floor division).
__global__ __launch_bounds__(256) void part_k(const void* __restrict__ eidx,
                                              const int* __restrict__ flags,
                                              int* __restrict__ scnt,
                                              unsigned* __restrict__ bucket2) {
    const int i64f = flags[1];
    const int tid = threadIdx.x;
    const long e0 = (long)blockIdx.x * P_EPB;
    __shared__ int cnt[NSB + 1];
    __shared__ int sc[NSB];
    __shared__ int gbase[NSB];
    __shared__ int cur[NSB];
    __shared__ unsigned buf[P_EPB];
    cnt[tid] = 0;
    if (tid == 0) cnt[NSB] = 0;
    __syncthreads();
    unsigned ev[8];
    int bk[8];
    #pragma unroll
    for (int i = 0; i < 8; ++i) {
        long e = e0 + i * 256 + tid;
        bk[i] = -1;
        if (e < N_EDGESC) {
            int s, d;
            if (i64f) {
                s = (int)((const long long*)eidx)[e];
                d = (int)((const long long*)eidx)[N_EDGESC + e];
            } else {
                s = ((const int*)eidx)[e];
                d = ((const int*)eidx)[N_EDGESC + e];
            }
            int sub = (d >> 2) / 49;             // = d / 196 exact
            bk[i] = sub;
            ev[i] = (unsigned)s | ((unsigned)(d - sub * SUBW) << 16);
            atomicAdd(&cnt[sub], 1);
        }
    }
    __syncthreads();
    const int myc = cnt[tid];
    sc[tid] = myc;
    __syncthreads();
    for (int off = 1; off < NSB; off <<= 1) {
        int t = (tid >= off) ? sc[tid - off] : 0;
        __syncthreads();
        sc[tid] += t;
        __syncthreads();
    }
    cnt[tid] = sc[tid] - myc;                    // exclusive
    if (tid == NSB - 1) cnt[NSB] = sc[NSB - 1];  // total
    gbase[tid] = myc ? atomicAdd(&scnt[tid], myc) : 0;
    cur[tid] = sc[tid] - myc;
    __syncthreads();
    #pragma unroll
    for (int i = 0; i < 8; ++i) {
        if (bk[i] >= 0) {
            int p = atomicAdd(&cur[bk[i]], 1);
            buf[p] = ev[i];
        }
    }
    __syncthreads();
    const int total = cnt[NSB];
    for (int p = tid; p < total; p += 256) {
        int lo = 0, hi = NSB;
        while (hi - lo > 1) { int mid = (lo + hi) >> 1; if (p >= cnt[mid]) lo = mid; else hi = mid; }
        bucket2[(long)lo * SBCAP + gbase[lo] + (p - cnt[lo])] = buf[p];
    }
}

// ---------------- fused CSR build: histogram + decoupled-lookback scan + scatter ----------------
// One block per sub-bucket (256 blocks, all resident -> spin-safe). Uniform
// mapping: nodebase = sb*196, last bucket width 20.
__global__ __launch_bounds__(256) void csr_k(const unsigned* __restrict__ bucket2,
                                             const int* __restrict__ scnt,
                                             int* __restrict__ state,
                                             int* __restrict__ row_start,
                                             unsigned short* __restrict__ col) {
    const int sb = blockIdx.x;
    const int tid = threadIdx.x;
    const int lane = tid & 63;
    const int cnt = scnt[sb];
    const unsigned* B = bucket2 + (long)sb * SBCAP;
    __shared__ int lh[SUBW];
    __shared__ int sc[256];
    __shared__ int sprefix_sh;
    const int nodebase = sb * SUBW;
    const int width = min(SUBW, N_NODESC - nodebase);
    for (int i = tid; i < SUBW; i += 256) lh[i] = 0;
    __syncthreads();
    for (int e = tid; e < cnt; e += 256) atomicAdd(&lh[B[e] >> 16], 1);
    __syncthreads();
    const int myc = (tid < SUBW) ? lh[tid] : 0;
    sc[tid] = myc;
    __syncthreads();
    for (int off = 1; off < 256; off <<= 1) {
        int t = (tid >= off) ? sc[tid - off] : 0;
        __syncthreads();
        sc[tid] += t;
        __syncthreads();
    }
    const int total = sc[255];
    if (tid == 0)
        __hip_atomic_store(&state[sb], (int)((1u << 30) | (unsigned)total),
                           __ATOMIC_RELEASE, __HIP_MEMORY_SCOPE_AGENT);
    if (tid < 64) {
        int prefix = 0;
        if (sb > 0) {
            int base = sb;
            for (;;) {
                int t = base - 1 - lane;
                int v = 0;
                if (t >= 0) {
                    for (;;) {
                        v = __hip_atomic_load(&state[t], __ATOMIC_ACQUIRE,
                                              __HIP_MEMORY_SCOPE_AGENT);
                        if ((unsigned)v >= (1u << 30)) break;
                        __builtin_amdgcn_s_sleep(1);
                    }
                }
                int flag = (int)(((unsigned)v) >> 30);
                int val = v & 0x3fffffff;
                unsigned long long pmask = __ballot(flag == 2 && t >= 0);
                int stop_tid = pmask ? (__ffsll((long long)pmask) - 1) : 64;
                int contrib = 0;
                if (t >= 0 && lane <= stop_tid) contrib = val;
                #pragma unroll
                for (int off = 32; off; off >>= 1) contrib += __shfl_xor(contrib, off, 64);
                prefix += contrib;
                if (pmask || base <= 64) break;
                base -= 64;
            }
        }
        if (tid == 0) {
            sprefix_sh = prefix;
            __hip_atomic_store(&state[sb],
                               (int)((2u << 30) | (unsigned)(prefix + total)),
                               __ATOMIC_RELEASE, __HIP_MEMORY_SCOPE_AGENT);
        }
    }
    __syncthreads();
    const int sprefix = sprefix_sh;
    if (tid < width) row_start[nodebase + tid] = sprefix + sc[tid] - myc;
    if (sb == NSB - 1 && tid == 0) row_start[N_NODESC] = sprefix + total;
    if (tid < SUBW) lh[tid] = sprefix + sc[tid] - myc;   // cursor
    __syncthreads();
    for (int e = tid; e < cnt; e += 256) {
        unsigned v = B[e];
        int pos = atomicAdd(&lh[v >> 16], 1);
        col[pos] = (unsigned short)(v & 0xffffu);
    }
}

// ---------------- Layer 1 GEMM via MFMA + fused logits (head-split outputs) ----------------

__global__ __launch_bounds__(256) void gemm1_k(
        const void* __restrict__ prot, const void* __restrict__ sp,
        const void* __restrict__ lri,
        const short* __restrict__ w1f, const float* __restrict__ w1r,
        const void* __restrict__ as1, const void* __restrict__ ad1,
        const int* __restrict__ flags,
        short* __restrict__ xph0, short* __restrict__ xph1,
        float* __restrict__ alsrc, float* __restrict__ aldst) {
    const int fp32 = flags[0];
    const int tid = threadIdx.x;
    const int nb = blockIdx.x * 32;
    __shared__ __align__(16) short xs[32][136];   // K order: prot 0..63, lri 0..63
    __shared__ float xsp[32][2];                  // spatial remainder
    __shared__ float sredc[32][8], dredc[32][8];  // [row][col-block]

    if (!fp32) {
        #pragma unroll
        for (int i = 0; i < 2; ++i) {
            int cidx = i * 256 + tid;             // 512 chunks of 8 shorts
            int r = cidx >> 4, cc = cidx & 15;
            int g = nb + r;
            short8 v = (short8){0, 0, 0, 0, 0, 0, 0, 0};
            if (g < N_NODESC) {
                const short* srcp = (cc < 8)
                    ? (const short*)prot + (long)g * 64 + cc * 8
                    : (const short*)lri + (long)g * 64 + (cc - 8) * 8;
                v = *(const short8*)srcp;
            }
            *(short8*)&xs[r][cc * 8] = v;
        }
    } else {
        #pragma unroll
        for (int i = 0; i < 16; ++i) {
            int idx = i * 256 + tid;
            int r = idx >> 7, k = idx & 127;
            int g = nb + r;
            float v = 0.f;
            if (g < N_NODESC)
                v = (k < 64) ? ((const float*)prot)[(long)g * 64 + k]
                             : ((const float*)lri)[(long)g * 64 + (k - 64)];
            xs[r][k] = f2s(v);
        }
    }
    if (tid < 64) {
        int r = tid >> 1, which = tid & 1;
        int g = nb + r;
        xsp[r][which] = (g < N_NODESC) ? ldf(sp, (long)g * 2 + which, fp32) : 0.f;
    }
    __syncthreads();

    const int wid = tid >> 6, lane = tid & 63;
    const int quad = lane >> 4, l16 = lane & 15;
    floatx4 acc[2][2];
    #pragma unroll
    for (int a = 0; a < 2; ++a)
        #pragma unroll
        for (int b = 0; b < 2; ++b) acc[a][b] = (floatx4){0.f, 0.f, 0.f, 0.f};

    const int c0 = 2 * wid;
    #pragma unroll
    for (int t = 0; t < 4; ++t) {
        short8 a0 = *(const short8*)&xs[l16][t * 32 + quad * 8];
        short8 a1 = *(const short8*)&xs[16 + l16][t * 32 + quad * 8];
        short8 b0 = *(const short8*)&w1f[(((c0 * 4 + t) * 4 + quad) * 16 + l16) * 8];
        short8 b1 = *(const short8*)&w1f[((((c0 + 1) * 4 + t) * 4 + quad) * 16 + l16) * 8];
        acc[0][0] = __builtin_amdgcn_mfma_f32_16x16x32_bf16(a0, b0, acc[0][0], 0, 0, 0);
        acc[0][1] = __builtin_amdgcn_mfma_f32_16x16x32_bf16(a0, b1, acc[0][1], 0, 0, 0);
        acc[1][0] = __builtin_amdgcn_mfma_f32_16x16x32_bf16(a1, b0, acc[1][0], 0, 0, 0);
        acc[1][1] = __builtin_amdgcn_mfma_f32_16x16x32_bf16(a1, b1, acc[1][1], 0, 0, 0);
    }
    #pragma unroll
    for (int ci = 0; ci < 2; ++ci) {
        int colg = (c0 + ci) * 16 + l16;
        float w0 = w1r[colg], w1v = w1r[128 + colg];
        float asv = ldf(as1, colg, fp32), adv = ldf(ad1, colg, fp32);
        short* xpd = (colg < 64) ? xph0 : xph1;
        const int cc = colg & 63;
        #pragma unroll
        for (int rt = 0; rt < 2; ++rt) {
            float sv[4], dv[4];
            #pragma unroll
            for (int reg = 0; reg < 4; ++reg) {
                int row = rt * 16 + quad * 4 + reg;
                int g = nb + row;
                float v = acc[rt][ci][reg] + xsp[row][0] * w0 + xsp[row][1] * w1v;
                if (g < N_NODESC) xpd[(long)g * 64 + cc] = f2s(v);
                sv[reg] = v * asv;
                dv[reg] = v * adv;
            }
            #pragma unroll
            for (int off = 1; off < 16; off <<= 1) {
                #pragma unroll
                for (int reg = 0; reg < 4; ++reg) {
                    sv[reg] += __shfl_xor(sv[reg], off, 64);
                    dv[reg] += __shfl_xor(dv[reg], off, 64);
                }
            }
            if (l16 == 0) {
                #pragma unroll
                for (int reg = 0; reg < 4; ++reg) {
                    int row = rt * 16 + quad * 4 + reg;
                    sredc[row][c0 + ci] = sv[reg];
                    dredc[row][c0 + ci] = dv[reg];
                }
            }
        }
    }
    __syncthreads();
    if (tid < 64) {
        int r = tid >> 1, h = tid & 1;
        int g = nb + r;
        if (g < N_NODESC) {
            alsrc[(long)h * N_NODESC + g] = sredc[r][4 * h] + sredc[r][4 * h + 1] +
                                            sredc[r][4 * h + 2] + sredc[r][4 * h + 3];
            aldst[(long)h * N_NODESC + g] = dredc[r][4 * h] + dredc[r][4 * h + 1] +
                                            dredc[r][4 * h + 2] + dredc[r][4 * h + 3];
        }
    }
}

// ---------------- Layer 1 aggregation: split-wave, both heads in one launch ----------------

__global__ __launch_bounds__(256) void agg1s_k(
        const int* __restrict__ row_start, const unsigned short* __restrict__ col,
        const short* __restrict__ xph0, const short* __restrict__ xph1,
        const float* __restrict__ als, const float* __restrict__ ald,
        const void* __restrict__ b1, const int* __restrict__ flags,
        unsigned* __restrict__ h1b32) {
    const int fp32 = flags[0];
    const int tid = threadIdx.x;
    const int wid = tid >> 6;
    const int lane = tid & 63;
    const int hw = lane >> 5;         // half-wave = node parity
    const int hl = lane & 31;
    const int head = blockIdx.x >= AGG_NB;
    const int b = blockIdx.x - head * AGG_NB;
    const int n = b * 8 + wid * 2 + hw;
    __shared__ float2 pbuf[4][2][32];
    float2* mybuf = pbuf[wid][hw];
    const short* xph = head ? xph1 : xph0;
    const float* alsh = als + (long)head * N_NODESC;
    const float* aldh = ald + (long)head * N_NODESC;
    const int e = hl >> 3;
    const int c = hl & 7;
    const char* xpb = (const char*)xph;
    const int c16 = c * 16;
    const float ad = aldh[n];
    float e0 = alsh[n] + ad;
    e0 = e0 > 0.f ? e0 : 0.2f * e0;
    const float pself = __expf(e0);
    const float pinit = e == 0 ? pself : 0.f;
    uint4 us = *(const uint4*)(xpb + (long)n * 128 + c16);
    float acc0 = pinit * ulo(us.x), acc1 = pinit * uhi(us.x);
    float acc2 = pinit * ulo(us.y), acc3 = pinit * uhi(us.y);
    float acc4 = pinit * ulo(us.z), acc5 = pinit * uhi(us.z);
    float acc6 = pinit * ulo(us.w), acc7 = pinit * uhi(us.w);
    float lp = 0.f;
    const int beg = row_start[n], end = row_start[n + 1];
    for (int base = beg; base < end; base += 32) {
        const int idx = base + hl;
        int s = 0;
        float p = 0.f;
        if (idx < end) {
            s = (int)col[idx];
            float t = alsh[s] + ad;
            t = t > 0.f ? t : 0.2f * t;
            p = __expf(t);
        }
        lp += p;
        mybuf[hl] = make_float2(p, __int_as_float(s << 7));
        int cnt = end - base; if (cnt > 32) cnt = 32;
        int quads = (cnt + 3) >> 2;
        int j = 0;
        for (; j + 4 <= quads; j += 4) {
            int a4[4]; float p4[4]; uint4 x[4];
            #pragma unroll
            for (int q = 0; q < 4; ++q) {
                float2 bv = mybuf[4 * (j + q) + e];
                a4[q] = __float_as_int(bv.y);
                p4[q] = bv.x;
            }
            #pragma unroll
            for (int q = 0; q < 4; ++q)
                x[q] = *(const uint4*)(xpb + a4[q] + c16);
            #pragma unroll
            for (int q = 0; q < 4; ++q) {
                acc0 = fmaf(p4[q], ulo(x[q].x), acc0);
                acc1 = fmaf(p4[q], uhi(x[q].x), acc1);
                acc2 = fmaf(p4[q], ulo(x[q].y), acc2);
                acc3 = fmaf(p4[q], uhi(x[q].y), acc3);
                acc4 = fmaf(p4[q], ulo(x[q].z), acc4);
                acc5 = fmaf(p4[q], uhi(x[q].z), acc5);
                acc6 = fmaf(p4[q], ulo(x[q].w), acc6);
                acc7 = fmaf(p4[q], uhi(x[q].w), acc7);
            }
        }
        for (; j < quads; ++j) {
            float2 bv = mybuf[4 * j + e];
            uint4 x = *(const uint4*)(xpb + __float_as_int(bv.y) + c16);
            float pv = bv.x;
            acc0 = fmaf(pv, ulo(x.x), acc0);
            acc1 = fmaf(pv, uhi(x.x), acc1);
            acc2 = fmaf(pv, ulo(x.y), acc2);
            acc3 = fmaf(pv, uhi(x.y), acc3);
            acc4 = fmaf(pv, ulo(x.z), acc4);
            acc5 = fmaf(pv, uhi(x.z), acc5);
            acc6 = fmaf(pv, ulo(x.w), acc6);
            acc7 = fmaf(pv, uhi(x.w), acc7);
        }
    }
    #pragma unroll
    for (int off = 16; off; off >>= 1) lp += __shfl_xor(lp, off, 64);
    #pragma unroll
    for (int off = 8; off <= 16; off <<= 1) {
        acc0 += __shfl_xor(acc0, off, 64);
        acc1 += __shfl_xor(acc1, off, 64);
        acc2 += __shfl_xor(acc2, off, 64);
        acc3 += __shfl_xor(acc3, off, 64);
        acc4 += __shfl_xor(acc4, off, 64);
        acc5 += __shfl_xor(acc5, off, 64);
        acc6 += __shfl_xor(acc6, off, 64);
        acc7 += __shfl_xor(acc7, off, 64);
    }
    if (hl < 8) {
        const float rl = 1.f / (lp + pself);
        const long bb = (long)head * 64 + 8 * c;
        float o0 = acc0 * rl + ldf(b1, bb + 0, fp32);
        float o1 = acc1 * rl + ldf(b1, bb + 1, fp32);
        float o2 = acc2 * rl + ldf(b1, bb + 2, fp32);
        float o3 = acc3 * rl + ldf(b1, bb + 3, fp32);
        float o4 = acc4 * rl + ldf(b1, bb + 4, fp32);
        float o5 = acc5 * rl + ldf(b1, bb + 5, fp32);
        float o6 = acc6 * rl + ldf(b1, bb + 6, fp32);
        float o7 = acc7 * rl + ldf(b1, bb + 7, fp32);
        uint4 o;
        o.x = pack2(o0, o1); o.y = pack2(o2, o3);
        o.z = pack2(o4, o5); o.w = pack2(o6, o7);
        *(uint4*)((char*)h1b32 + (long)n * 256 + head * 128 + c16) = o;
    }
}

// ---------------- Layer 2 GEMM via MFMA + fused logits (shuffle reduce) ----------------

__global__ __launch_bounds__(256) void gemm2_k(
        const unsigned* __restrict__ h1b32, const short* __restrict__ w2f,
        const void* __restrict__ as2, const void* __restrict__ ad2,
        const int* __restrict__ flags,
        short* __restrict__ xp2b, float* __restrict__ alsrc, float* __restrict__ aldst) {
    const int fp32 = flags[0];
    const int tid = threadIdx.x;
    const int nb = blockIdx.x * 32;
    __shared__ __align__(16) short xs[32][136];
    __shared__ float sredc[32][4], dredc[32][4];

    #pragma unroll
    for (int i = 0; i < 8; ++i) {
        int idx = i * 256 + tid;
        int r = idx >> 6, ii = idx & 63;
        int g = nb + r;
        unsigned val = (g < N_NODESC) ? h1b32[(long)g * 64 + ii] : 0u;
        ((unsigned*)&xs[r][0])[ii] = val;
    }
    __syncthreads();

    const int wid = tid >> 6, lane = tid & 63;
    const int quad = lane >> 4, l16 = lane & 15;
    floatx4 acc0 = (floatx4){0.f, 0.f, 0.f, 0.f};
    floatx4 acc1 = (floatx4){0.f, 0.f, 0.f, 0.f};
    #pragma unroll
    for (int t = 0; t < 4; ++t) {
        short8 a0 = *(const short8*)&xs[l16][t * 32 + quad * 8];
        short8 a1 = *(const short8*)&xs[16 + l16][t * 32 + quad * 8];
        short8 b = *(const short8*)&w2f[(((wid * 4 + t) * 4 + quad) * 16 + l16) * 8];
        acc0 = __builtin_amdgcn_mfma_f32_16x16x32_bf16(a0, b, acc0, 0, 0, 0);
        acc1 = __builtin_amdgcn_mfma_f32_16x16x32_bf16(a1, b, acc1, 0, 0, 0);
    }
    const int colg = wid * 16 + l16;
    const float asv = ldf(as2, colg, fp32), adv = ldf(ad2, colg, fp32);
    float sv0[4], dv0[4], sv1[4], dv1[4];
    #pragma unroll
    for (int reg = 0; reg < 4; ++reg) {
        int r0 = quad * 4 + reg;
        int g0 = nb + r0;
        int g1 = g0 + 16;
        if (g0 < N_NODESC) xp2b[(long)g0 * 64 + colg] = f2s(acc0[reg]);
        if (g1 < N_NODESC) xp2b[(long)g1 * 64 + colg] = f2s(acc1[reg]);
        sv0[reg] = acc0[reg] * asv; dv0[reg] = acc0[reg] * adv;
        sv1[reg] = acc1[reg] * asv; dv1[reg] = acc1[reg] * adv;
    }
    #pragma unroll
    for (int off = 1; off < 16; off <<= 1) {
        #pragma unroll
        for (int reg = 0; reg < 4; ++reg) {
            sv0[reg] += __shfl_xor(sv0[reg], off, 64);
            dv0[reg] += __shfl_xor(dv0[reg], off, 64);
            sv1[reg] += __shfl_xor(sv1[reg], off, 64);
            dv1[reg] += __shfl_xor(dv1[reg], off, 64);
        }
    }
    if (l16 == 0) {
        #pragma unroll
        for (int reg = 0; reg < 4; ++reg) {
            int r0 = quad * 4 + reg;
            sredc[r0][wid] = sv0[reg];      dredc[r0][wid] = dv0[reg];
            sredc[r0 + 16][wid] = sv1[reg]; dredc[r0 + 16][wid] = dv1[reg];
        }
    }
    __syncthreads();
    if (tid < 32) {
        int g = nb + tid;
        if (g < N_NODESC) {
            alsrc[g] = sredc[tid][0] + sredc[tid][1] + sredc[tid][2] + sredc[tid][3];
            aldst[g] = dredc[tid][0] + dredc[tid][1] + dredc[tid][2] + dredc[tid][3];
        }
    }
}

// ---------------- Layer 2 aggregation: split-wave + fused mean-pool (replicated) ----------------

__global__ __launch_bounds__(256) void agg2p_k(
        const int* __restrict__ row_start, const unsigned short* __restrict__ col,
        const short* __restrict__ xp2b, const float* __restrict__ alsrc,
        const float* __restrict__ aldst, const void* __restrict__ b2v,
        const int* __restrict__ flags, const int* __restrict__ batch32,
        float* __restrict__ pooled, float* __restrict__ counts) {
    const int fp32 = flags[0];
    const int tid = threadIdx.x;
    const int wid = tid >> 6;
    const int lane = tid & 63;
    const int hw = lane >> 5;
    const int hl = lane & 31;
    const int n = blockIdx.x * 8 + wid * 2 + hw;
    const int rep = blockIdx.x & (POOL_REP - 1);
    __shared__ float2 pbuf[4][2][32];
    __shared__ float psum[64];
    __shared__ int ginfo[2];
    if (tid < 64) psum[tid] = 0.f;
    if (tid == 0) {
        int g0 = batch32[blockIdx.x * 8];
        int g7 = batch32[blockIdx.x * 8 + 7];
        ginfo[0] = g0;
        ginfo[1] = (g0 == g7);
    }
    __syncthreads();
    float2* mybuf = pbuf[wid][hw];
    const int e = hl >> 3;
    const int c = hl & 7;
    const char* xpb = (const char*)xp2b;
    const int c16 = c * 16;
    const float ad = aldst[n];
    float e0 = alsrc[n] + ad;
    e0 = e0 > 0.f ? e0 : 0.2f * e0;
    const float pself = __expf(e0);
    const float pinit = e == 0 ? pself : 0.f;
    uint4 us = *(const uint4*)(xpb + (long)n * 128 + c16);
    float acc0 = pinit * ulo(us.x), acc1 = pinit * uhi(us.x);
    float acc2 = pinit * ulo(us.y), acc3 = pinit * uhi(us.y);
    float acc4 = pinit * ulo(us.z), acc5 = pinit * uhi(us.z);
    float acc6 = pinit * ulo(us.w), acc7 = pinit * uhi(us.w);
    float lp = 0.f;
    const int beg = row_start[n], end = row_start[n + 1];
    for (int base = beg; base < end; base += 32) {
        const int idx = base + hl;
        int s = 0;
        float p = 0.f;
        if (idx < end) {
            s = (int)col[idx];
            float t = alsrc[s] + ad;
            t = t > 0.f ? t : 0.2f * t;
            p = __expf(t);
        }
        lp += p;
        mybuf[hl] = make_float2(p, __int_as_float(s << 7));
        int cnt = end - base; if (cnt > 32) cnt = 32;
        int quads = (cnt + 3) >> 2;
        int j = 0;
        for (; j + 4 <= quads; j += 4) {
            int a4[4]; float p4[4]; uint4 x[4];
            #pragma unroll
            for (int q = 0; q < 4; ++q) {
                float2 bv = mybuf[4 * (j + q) + e];
                a4[q] = __float_as_int(bv.y);
                p4[q] = bv.x;
            }
            #pragma unroll
            for (int q = 0; q < 4; ++q)
                x[q] = *(const uint4*)(xpb + a4[q] + c16);
            #pragma unroll
            for (int q = 0; q < 4; ++q) {
                acc0 = fmaf(p4[q], ulo(x[q].x), acc0);
                acc1 = fmaf(p4[q], uhi(x[q].x), acc1);
                acc2 = fmaf(p4[q], ulo(x[q].y), acc2);
                acc3 = fmaf(p4[q], uhi(x[q].y), acc3);
                acc4 = fmaf(p4[q], ulo(x[q].z), acc4);
                acc5 = fmaf(p4[q], uhi(x[q].z), acc5);
                acc6 = fmaf(p4[q], ulo(x[q].w), acc6);
                acc7 = fmaf(p4[q], uhi(x[q].w), acc7);
            }
        }
        for (; j < quads; ++j) {
            float2 bv = mybuf[4 * j + e];
            uint4 x = *(const uint4*)(xpb + __float_as_int(bv.y) + c16);
            float pv = bv.x;
            acc0 = fmaf(pv, ulo(x.x), acc0);
            acc1 = fmaf(pv, uhi(x.x), acc1);
            acc2 = fmaf(pv, ulo(x.y), acc2);
            acc3 = fmaf(pv, uhi(x.y), acc3);
            acc4 = fmaf(pv, ulo(x.z), acc4);
            acc5 = fmaf(pv, uhi(x.z), acc5);
            acc6 = fmaf(pv, ulo(x.w), acc6);
            acc7 = fmaf(pv, uhi(x.w), acc7);
        }
    }
    #pragma unroll
    for (int off = 16; off; off >>= 1) lp += __shfl_xor(lp, off, 64);
    #pragma unroll
    for (int off = 8; off <= 16; off <<= 1) {
        acc0 += __shfl_xor(acc0, off, 64);
        acc1 += __shfl_xor(acc1, off, 64);
        acc2 += __shfl_xor(acc2, off, 64);
        acc3 += __shfl_xor(acc3, off, 64);
        acc4 += __shfl_xor(acc4, off, 64);
        acc5 += __shfl_xor(acc5, off, 64);
        acc6 += __shfl_xor(acc6, off, 64);
        acc7 += __shfl_xor(acc7, off, 64);
    }
    float o[8];
    if (hl < 8) {
        const float rl = 1.f / (lp + pself);
        o[0] = acc0 * rl + ldf(b2v, 8 * c + 0, fp32);
        o[1] = acc1 * rl + ldf(b2v, 8 * c + 1, fp32);
        o[2] = acc2 * rl + ldf(b2v, 8 * c + 2, fp32);
        o[3] = acc3 * rl + ldf(b2v, 8 * c + 3, fp32);
        o[4] = acc4 * rl + ldf(b2v, 8 * c + 4, fp32);
        o[5] = acc5 * rl + ldf(b2v, 8 * c + 5, fp32);
        o[6] = acc6 * rl + ldf(b2v, 8 * c + 6, fp32);
        o[7] = acc7 * rl + ldf(b2v, 8 * c + 7, fp32);
    }
    if (ginfo[1]) {
        if (hl < 8) {
            #pragma unroll
            for (int j = 0; j < 8; ++j) atomicAdd(&psum[8 * c + j], o[j]);
        }
        __syncthreads();
        if (tid < 64)
            atomicAdd(&pooled[((long)rep * NUM_GRAPHSC + ginfo[0]) * 64 + tid], psum[tid]);
        if (tid == 0) atomicAdd(&counts[rep * NUM_GRAPHSC + ginfo[0]], 8.f);
    } else {
        int g = batch32[n];
        if (hl < 8) {
            #pragma unroll
            for (int j = 0; j < 8; ++j)
                atomicAdd(&pooled[((long)rep * NUM_GRAPHSC + g) * 64 + 8 * c + j], o[j]);
        }
        if (hl == 0) atomicAdd(&counts[rep * NUM_GRAPHSC + g], 1.f);
    }
}

// ---------------- decoder MLP (sums pooled replicas) ----------------

__global__ __launch_bounds__(64) void dec_k(const float* __restrict__ pooled,
                                            const float* __restrict__ counts,
                                            const void* __restrict__ Wd1, const void* __restrict__ bd1,
                                            const void* __restrict__ Wd2, const void* __restrict__ bd2,
                                            const int* __restrict__ flags,
                                            void* __restrict__ out) {
    const int fp32 = flags[0];
    const int g = blockIdx.x, j = threadIdx.x;
    __shared__ float p[64], dh[64];
    float cnt = 0.f, ps = 0.f;
    #pragma unroll
    for (int r = 0; r < POOL_REP; ++r) {
        ps += pooled[((long)r * NUM_GRAPHSC + g) * 64 + j];
        if (j == 0) cnt += counts[r * NUM_GRAPHSC + g];
    }
    __shared__ float cnt_sh;
    if (j == 0) cnt_sh = cnt < 1.f ? 1.f : cnt;
    __syncthreads();
    p[j] = ps / cnt_sh;
    __syncthreads();
    float acc = ldf(bd1, j, fp32);
    for (int k = 0; k < 64; ++k) acc += p[k] * ldf(Wd1, k * 64 + j, fp32);
    dh[j] = acc > 0.f ? acc : 0.f;
    __syncthreads();
    if (j < 32) {
        float o = ldf(bd2, j, fp32);
        for (int k = 0; k < 64; ++k) o += dh[k] * ldf(Wd2, k * 32 + j, fp32);
        if (fp32) ((float*)out)[g * 32 + j] = o;
        else      ((bf16*)out)[g * 32 + j] = __float2bfloat16(o);
    }
}

extern "C" void kernel_launch(void* const* d_in, const int* in_sizes, int n_in,
                              void* d_out, int out_size, void* d_ws, size_t ws_size,
                              hipStream_t stream) {
    (void)in_sizes; (void)n_in; (void)out_size; (void)ws_size;
    const void* prot = d_in[0];
    const void* sp   = d_in[1];
    const void* lri  = d_in[2];
    const void* eidx = d_in[3];
    const void* batch= d_in[4];
    const void* W1   = d_in[5];
    const void* as1  = d_in[6];
    const void* ad1  = d_in[7];
    const void* b1   = d_in[8];
    const void* W2   = d_in[9];
    const void* as2  = d_in[10];
    const void* ad2  = d_in[11];
    const void* b2v  = d_in[12];
    const void* Wd1  = d_in[13];
    const void* bd1  = d_in[14];
    const void* Wd2  = d_in[15];
    const void* bd2  = d_in[16];

    char* w = (char*)d_ws;
    auto alloc = [&](size_t bytes) -> void* {
        char* p = w;
        w += (bytes + 255) & ~(size_t)255;
        return (void*)p;
    };
    int*   flags     = (int*)alloc(2 * 4);
    // --- contiguous zero region: pooled .. state ---
    float* pooled    = (float*)alloc((size_t)POOL_REP * NUM_GRAPHSC * 64 * 4);
    float* counts    = (float*)alloc((size_t)POOL_REP * NUM_GRAPHSC * 4);
    int*   scnt      = (int*)alloc((size_t)NSB * 4);
    int*   state     = (int*)alloc((size_t)NSB * 4);
    char*  zero_end  = w;
    // ----------------------------------------------
    int*   batch32   = (int*)alloc((size_t)N_NODESC * 4);
    int*   row_start = (int*)alloc((size_t)(N_NODESC + 1) * 4);
    unsigned* bucket2= (unsigned*)alloc((size_t)NSB * SBCAP * 4);
    unsigned short* col = (unsigned short*)alloc((size_t)N_EDGESC * 2);
    short* w1f       = (short*)alloc((size_t)16384 * 2);
    float* w1r       = (float*)alloc((size_t)256 * 4);
    short* w2f       = (short*)alloc((size_t)8192 * 2);
    short* xph0      = (short*)alloc((size_t)N_NODESC * 64 * 2);
    short* xph1      = (short*)alloc((size_t)N_NODESC * 64 * 2);
    float* alsrc1    = (float*)alloc((size_t)N_NODESC * 2 * 4);
    float* aldst1    = (float*)alloc((size_t)N_NODESC * 2 * 4);
    short* h1b       = (short*)alloc((size_t)N_NODESC * 128 * 2);
    short* xp2b      = (short*)alloc((size_t)N_NODESC * 64 * 2);
    float* alsrc2    = (float*)alloc((size_t)N_NODESC * 4);
    float* aldst2    = (float*)alloc((size_t)N_NODESC * 4);

    const int nzero = (int)((zero_end - (char*)pooled) / 4);
    const int nzblk = (nzero + 255) / 256;
    const int nbat  = (N_NODESC + 255) / 256;

    detect_k<<<1, 64, 0, stream>>>(prot, eidx, flags);
    prep2_k<<<97 + nzblk + nbat, 256, 0, stream>>>(W1, W2, flags, w1f, w1r, w2f,
                                                   (int*)pooled, nzero, nzblk,
                                                   batch, batch32);
    part_k<<<(N_EDGESC + P_EPB - 1) / P_EPB, 256, 0, stream>>>(eidx, flags, scnt, bucket2);
    csr_k<<<NSB, 256, 0, stream>>>(bucket2, scnt, state, row_start, col);

    const int nblk = (N_NODESC + 31) / 32;
    gemm1_k<<<nblk, 256, 0, stream>>>(prot, sp, lri, w1f, w1r, as1, ad1, flags,
                                      xph0, xph1, alsrc1, aldst1);
    agg1s_k<<<2 * AGG_NB, 256, 0, stream>>>(row_start, col, xph0, xph1,
                                            alsrc1, aldst1, b1, flags,
                                            (unsigned*)h1b);
    gemm2_k<<<nblk, 256, 0, stream>>>((const unsigned*)h1b, w2f, as2, ad2, flags,
                                      xp2b, alsrc2, aldst2);
    agg2p_k<<<AGG_NB, 256, 0, stream>>>(row_start, col, xp2b, alsrc2, aldst2,
                                        b2v, flags, batch32, pooled, counts);
    dec_k<<<NUM_GRAPHSC, 64, 0, stream>>>(pooled, counts, Wd1, bd1, Wd2, bd2, flags, d_out);
}

// Round 8
// 302.581 us; speedup vs baseline: 1.3796x; 1.0386x over previous
//
#include <hip/hip_runtime.h>
#include <hip/hip_bf16.h>

#define N_NODESC 50000
#define N_EDGESC 1600000
#define NUM_GRAPHSC 64
#define P_EPB 2048            // edges per block in part path
#define NPART ((N_EDGESC + P_EPB - 1) / P_EPB)   // 782
#define SUBW 196              // nodes per sub-bucket (256 buckets cover 50000)
#define NSB 256               // number of sub-buckets
#define SBCAP 8192            // per-sub-bucket capacity (avg 6250, max ~6600)
#define POOL_REP 32           // pooled replicas to kill atomic contention
#define AGG_NB 6250           // 50000 / 8 nodes per block (split-wave)

typedef __hip_bfloat16 bf16;
typedef short short8 __attribute__((ext_vector_type(8)));
typedef float floatx4 __attribute__((ext_vector_type(4)));

__device__ __forceinline__ float ldf(const void* p, long i, int fp32) {
    return fp32 ? ((const float*)p)[i] : __bfloat162float(((const bf16*)p)[i]);
}
__device__ __forceinline__ short f2s(float v) {
    bf16 h = __float2bfloat16(v);
    return *(short*)&h;
}
__device__ __forceinline__ unsigned pack2(float lo, float hi) {
    bf16 a = __float2bfloat16(lo), b = __float2bfloat16(hi);
    unsigned ua = *(unsigned short*)&a, ub = *(unsigned short*)&b;
    return (ub << 16) | ua;
}
__device__ __forceinline__ float ulo(unsigned u) { return __uint_as_float(u << 16); }
__device__ __forceinline__ float uhi(unsigned u) { return __uint_as_float(u & 0xffff0000u); }

// ---------------- inline dtype detection (per-block, ~100 loads) ----------------
__device__ __forceinline__ int detect_fp32_dev(const void* prot) {
    const bf16* pb = (const bf16*)prot;
    int sane = 0;
    for (int i = 0; i < 64; ++i) {
        float a = fabsf(__bfloat162float(pb[2 * i]));
        if (a > 1e-8f && a < 1e4f) sane++;
    }
    return (sane >= 48) ? 0 : 1;
}
__device__ __forceinline__ int detect_i64_dev(const void* eidx) {
    const unsigned* u = (const unsigned*)eidx;
    int zhi = 0;
    for (int i = 0; i < 32; ++i)
        if (u[2 * i + 1] == 0u) zhi++;
    return (zhi >= 30) ? 1 : 0;
}

// ---------------- mega: edge partition ∥ weight prep ∥ batch cvt (one launch) ----------------
// Blocks [0,NPART): 256-way edge partition into bucket2 (entry: s|off<<16, bucket
// byte used transiently in bits 24-31 to avoid the write-out binary search).
// Blocks [NPART, NPART+97): weight prep.  Rest: batch cvt.  All paths derive
// dtype flags inline; block NPART publishes flags for downstream kernels.
__global__ __launch_bounds__(256) void mega_k(const void* __restrict__ eidx,
                                              const void* __restrict__ prot,
                                              const void* __restrict__ batch,
                                              const void* __restrict__ W1,
                                              const void* __restrict__ W2,
                                              int* __restrict__ flags,
                                              short* __restrict__ w1f,
                                              float* __restrict__ w1r,
                                              short* __restrict__ w2f,
                                              int* __restrict__ b32,
                                              int* __restrict__ scnt,
                                              unsigned* __restrict__ bucket2,
                                              int nbat) {
    const int b = blockIdx.x, tid = threadIdx.x;
    __shared__ int cnt[NSB];
    __shared__ int sc[NSB];
    __shared__ int gbase[NSB];
    __shared__ int cur[NSB];
    __shared__ unsigned buf[P_EPB];
    __shared__ int sflag;

    if (b < NPART) {
        // ---- edge partition path ----
        if (tid == 0) sflag = detect_i64_dev(eidx);
        cnt[tid] = 0;
        __syncthreads();
        const int i64f = sflag;
        const long e0 = (long)b * P_EPB;
        unsigned ev[8];
        int bk[8];
        #pragma unroll
        for (int i = 0; i < 8; ++i) {
            long e = e0 + i * 256 + tid;
            bk[i] = -1;
            if (e < N_EDGESC) {
                int s, d;
                if (i64f) {
                    s = (int)((const long long*)eidx)[e];
                    d = (int)((const long long*)eidx)[N_EDGESC + e];
                } else {
                    s = ((const int*)eidx)[e];
                    d = ((const int*)eidx)[N_EDGESC + e];
                }
                int sub = (d >> 2) / 49;             // = d / 196 exact
                bk[i] = sub;
                ev[i] = (unsigned)s | ((unsigned)(d - sub * SUBW) << 16)
                                    | ((unsigned)sub << 24);
                atomicAdd(&cnt[sub], 1);
            }
        }
        __syncthreads();
        const int myc = cnt[tid];
        sc[tid] = myc;
        __syncthreads();
        #pragma unroll
        for (int off = 1; off < NSB; off <<= 1) {
            int t = (tid >= off) ? sc[tid - off] : 0;
            __syncthreads();
            sc[tid] += t;
            __syncthreads();
        }
        cnt[tid] = sc[tid] - myc;                    // exclusive prefix
        gbase[tid] = myc ? atomicAdd(&scnt[tid], myc) : 0;
        cur[tid] = sc[tid] - myc;
        __syncthreads();
        #pragma unroll
        for (int i = 0; i < 8; ++i) {
            if (bk[i] >= 0) {
                int p = atomicAdd(&cur[bk[i]], 1);
                buf[p] = ev[i];
            }
        }
        __syncthreads();
        const int total = sc[NSB - 1];
        for (int p = tid; p < total; p += 256) {
            unsigned v = buf[p];
            int lo = (int)(v >> 24);
            bucket2[(long)lo * SBCAP + gbase[lo] + (p - cnt[lo])] = v & 0xffffffu;
        }
        return;
    }
    const int wb = b - NPART;
    if (wb < 97) {
        if (tid == 0) {
            sflag = detect_fp32_dev(prot);
            if (wb == 0) {                           // publish flags for later kernels
                flags[0] = sflag;
                flags[1] = detect_i64_dev(eidx);
            }
        }
        __syncthreads();
        const int fp32 = sflag;
        if (wb < 64) {
            int idx = wb * 256 + tid;                // 16384
            int kp = idx >> 7, n = idx & 127;
            int krow = kp < 64 ? kp : 66 + (kp - 64);
            float v = ldf(W1, (long)krow * 128 + n, fp32);
            int c = n >> 4, nn = n & 15, t = kp >> 5, q = (kp >> 3) & 3, j = kp & 7;
            w1f[(((c * 4 + t) * 4 + q) * 16 + nn) * 8 + j] = f2s(v);
        } else if (wb == 64) {
            int which = tid >> 7, n = tid & 127;     // W1 rows 64,65 (spatial)
            w1r[which * 128 + n] = ldf(W1, (long)(64 + which) * 128 + n, fp32);
        } else {
            int idx = (wb - 65) * 256 + tid;         // 8192
            int k = idx >> 6, n = idx & 63;
            float v = ldf(W2, (long)k * 64 + n, fp32);
            int c = n >> 4, nn = n & 15, t = k >> 5, q = (k >> 3) & 3, j = k & 7;
            w2f[(((c * 4 + t) * 4 + q) * 16 + nn) * 8 + j] = f2s(v);
        }
        return;
    }
    // ---- batch cvt path ----
    if (tid == 0) sflag = detect_i64_dev(eidx);
    __syncthreads();
    const int i64f = sflag;
    int i = (wb - 97) * 256 + tid;
    if (i < N_NODESC)
        b32[i] = i64f ? (int)((const long long*)batch)[i] : ((const int*)batch)[i];
    (void)nbat;
}

// ---------------- csr ∥ gemm1 (one launch) ----------------
// Blocks [0,NSB): fused CSR build (histogram + decoupled-lookback + scatter).
// Dispatched first -> all 256 resident -> lookback spin-safe.
// Blocks [NSB, NSB+nblk): layer-1 MFMA GEMM + fused logits.
__global__ __launch_bounds__(256) void csrgemm1_k(
        const unsigned* __restrict__ bucket2, const int* __restrict__ scnt,
        int* __restrict__ state, int* __restrict__ row_start,
        unsigned short* __restrict__ col,
        const void* __restrict__ prot, const void* __restrict__ sp,
        const void* __restrict__ lri,
        const short* __restrict__ w1f, const float* __restrict__ w1r,
        const void* __restrict__ as1, const void* __restrict__ ad1,
        const int* __restrict__ flags,
        short* __restrict__ xph0, short* __restrict__ xph1,
        float* __restrict__ alsrc, float* __restrict__ aldst) {
    const int tid = threadIdx.x;
    __shared__ int lh[SUBW];
    __shared__ int sc[256];
    __shared__ int sprefix_sh;
    __shared__ __align__(16) short xs[32][136];
    __shared__ float xsp[32][2];
    __shared__ float sredc[32][8], dredc[32][8];

    if (blockIdx.x < NSB) {
        // ---- CSR path ----
        const int sb = blockIdx.x;
        const int lane = tid & 63;
        const int cnt = scnt[sb];
        const unsigned* B = bucket2 + (long)sb * SBCAP;
        const int nodebase = sb * SUBW;
        const int width = min(SUBW, N_NODESC - nodebase);
        for (int i = tid; i < SUBW; i += 256) lh[i] = 0;
        __syncthreads();
        for (int e = tid; e < cnt; e += 256) atomicAdd(&lh[B[e] >> 16], 1);
        __syncthreads();
        const int myc = (tid < SUBW) ? lh[tid] : 0;
        sc[tid] = myc;
        __syncthreads();
        for (int off = 1; off < 256; off <<= 1) {
            int t = (tid >= off) ? sc[tid - off] : 0;
            __syncthreads();
            sc[tid] += t;
            __syncthreads();
        }
        const int total = sc[255];
        if (tid == 0)
            __hip_atomic_store(&state[sb], (int)((1u << 30) | (unsigned)total),
                               __ATOMIC_RELEASE, __HIP_MEMORY_SCOPE_AGENT);
        if (tid < 64) {
            int prefix = 0;
            if (sb > 0) {
                int base = sb;
                for (;;) {
                    int t = base - 1 - lane;
                    int v = 0;
                    if (t >= 0) {
                        for (;;) {
                            v = __hip_atomic_load(&state[t], __ATOMIC_ACQUIRE,
                                                  __HIP_MEMORY_SCOPE_AGENT);
                            if ((unsigned)v >= (1u << 30)) break;
                            __builtin_amdgcn_s_sleep(1);
                        }
                    }
                    int flag = (int)(((unsigned)v) >> 30);
                    int val = v & 0x3fffffff;
                    unsigned long long pmask = __ballot(flag == 2 && t >= 0);
                    int stop_tid = pmask ? (__ffsll((long long)pmask) - 1) : 64;
                    int contrib = 0;
                    if (t >= 0 && lane <= stop_tid) contrib = val;
                    #pragma unroll
                    for (int off = 32; off; off >>= 1) contrib += __shfl_xor(contrib, off, 64);
                    prefix += contrib;
                    if (pmask || base <= 64) break;
                    base -= 64;
                }
            }
            if (tid == 0) {
                sprefix_sh = prefix;
                __hip_atomic_store(&state[sb],
                                   (int)((2u << 30) | (unsigned)(prefix + total)),
                                   __ATOMIC_RELEASE, __HIP_MEMORY_SCOPE_AGENT);
            }
        }
        __syncthreads();
        const int sprefix = sprefix_sh;
        if (tid < width) row_start[nodebase + tid] = sprefix + sc[tid] - myc;
        if (sb == NSB - 1 && tid == 0) row_start[N_NODESC] = sprefix + total;
        if (tid < SUBW) lh[tid] = sprefix + sc[tid] - myc;   // cursor
        __syncthreads();
        for (int e = tid; e < cnt; e += 256) {
            unsigned v = B[e];
            int pos = atomicAdd(&lh[v >> 16], 1);
            col[pos] = (unsigned short)(v & 0xffffu);
        }
        return;
    }

    // ---- gemm1 path ----
    const int fp32 = flags[0];
    const int nb = (blockIdx.x - NSB) * 32;
    if (!fp32) {
        #pragma unroll
        for (int i = 0; i < 2; ++i) {
            int cidx = i * 256 + tid;
            int r = cidx >> 4, cc = cidx & 15;
            int g = nb + r;
            short8 v = (short8){0, 0, 0, 0, 0, 0, 0, 0};
            if (g < N_NODESC) {
                const short* srcp = (cc < 8)
                    ? (const short*)prot + (long)g * 64 + cc * 8
                    : (const short*)lri + (long)g * 64 + (cc - 8) * 8;
                v = *(const short8*)srcp;
            }
            *(short8*)&xs[r][cc * 8] = v;
        }
    } else {
        #pragma unroll
        for (int i = 0; i < 16; ++i) {
            int idx = i * 256 + tid;
            int r = idx >> 7, k = idx & 127;
            int g = nb + r;
            float v = 0.f;
            if (g < N_NODESC)
                v = (k < 64) ? ((const float*)prot)[(long)g * 64 + k]
                             : ((const float*)lri)[(long)g * 64 + (k - 64)];
            xs[r][k] = f2s(v);
        }
    }
    if (tid < 64) {
        int r = tid >> 1, which = tid & 1;
        int g = nb + r;
        xsp[r][which] = (g < N_NODESC) ? ldf(sp, (long)g * 2 + which, fp32) : 0.f;
    }
    __syncthreads();

    const int wid = tid >> 6, lane = tid & 63;
    const int quad = lane >> 4, l16 = lane & 15;
    floatx4 acc[2][2];
    #pragma unroll
    for (int a = 0; a < 2; ++a)
        #pragma unroll
        for (int bb = 0; bb < 2; ++bb) acc[a][bb] = (floatx4){0.f, 0.f, 0.f, 0.f};

    const int c0 = 2 * wid;
    #pragma unroll
    for (int t = 0; t < 4; ++t) {
        short8 a0 = *(const short8*)&xs[l16][t * 32 + quad * 8];
        short8 a1 = *(const short8*)&xs[16 + l16][t * 32 + quad * 8];
        short8 b0 = *(const short8*)&w1f[(((c0 * 4 + t) * 4 + quad) * 16 + l16) * 8];
        short8 b1 = *(const short8*)&w1f[((((c0 + 1) * 4 + t) * 4 + quad) * 16 + l16) * 8];
        acc[0][0] = __builtin_amdgcn_mfma_f32_16x16x32_bf16(a0, b0, acc[0][0], 0, 0, 0);
        acc[0][1] = __builtin_amdgcn_mfma_f32_16x16x32_bf16(a0, b1, acc[0][1], 0, 0, 0);
        acc[1][0] = __builtin_amdgcn_mfma_f32_16x16x32_bf16(a1, b0, acc[1][0], 0, 0, 0);
        acc[1][1] = __builtin_amdgcn_mfma_f32_16x16x32_bf16(a1, b1, acc[1][1], 0, 0, 0);
    }
    #pragma unroll
    for (int ci = 0; ci < 2; ++ci) {
        int colg = (c0 + ci) * 16 + l16;
        float w0 = w1r[colg], w1v = w1r[128 + colg];
        float asv = ldf(as1, colg, fp32), adv = ldf(ad1, colg, fp32);
        short* xpd = (colg < 64) ? xph0 : xph1;
        const int cc = colg & 63;
        #pragma unroll
        for (int rt = 0; rt < 2; ++rt) {
            float sv[4], dv[4];
            #pragma unroll
            for (int reg = 0; reg < 4; ++reg) {
                int row = rt * 16 + quad * 4 + reg;
                int g = nb + row;
                float v = acc[rt][ci][reg] + xsp[row][0] * w0 + xsp[row][1] * w1v;
                if (g < N_NODESC) xpd[(long)g * 64 + cc] = f2s(v);
                sv[reg] = v * asv;
                dv[reg] = v * adv;
            }
            #pragma unroll
            for (int off = 1; off < 16; off <<= 1) {
                #pragma unroll
                for (int reg = 0; reg < 4; ++reg) {
                    sv[reg] += __shfl_xor(sv[reg], off, 64);
                    dv[reg] += __shfl_xor(dv[reg], off, 64);
                }
            }
            if (l16 == 0) {
                #pragma unroll
                for (int reg = 0; reg < 4; ++reg) {
                    int row = rt * 16 + quad * 4 + reg;
                    sredc[row][c0 + ci] = sv[reg];
                    dredc[row][c0 + ci] = dv[reg];
                }
            }
        }
    }
    __syncthreads();
    if (tid < 64) {
        int r = tid >> 1, h = tid & 1;
        int g = nb + r;
        if (g < N_NODESC) {
            alsrc[(long)h * N_NODESC + g] = sredc[r][4 * h] + sredc[r][4 * h + 1] +
                                            sredc[r][4 * h + 2] + sredc[r][4 * h + 3];
            aldst[(long)h * N_NODESC + g] = dredc[r][4 * h] + dredc[r][4 * h + 1] +
                                            dredc[r][4 * h + 2] + dredc[r][4 * h + 3];
        }
    }
}

// ---------------- Layer 1 aggregation: split-wave, both heads in one launch ----------------

__global__ __launch_bounds__(256) void agg1s_k(
        const int* __restrict__ row_start, const unsigned short* __restrict__ col,
        const short* __restrict__ xph0, const short* __restrict__ xph1,
        const float* __restrict__ als, const float* __restrict__ ald,
        const void* __restrict__ b1, const int* __restrict__ flags,
        unsigned* __restrict__ h1b32) {
    const int fp32 = flags[0];
    const int tid = threadIdx.x;
    const int wid = tid >> 6;
    const int lane = tid & 63;
    const int hw = lane >> 5;         // half-wave = node parity
    const int hl = lane & 31;
    const int head = blockIdx.x >= AGG_NB;
    const int b = blockIdx.x - head * AGG_NB;
    const int n = b * 8 + wid * 2 + hw;
    __shared__ float2 pbuf[4][2][32];
    float2* mybuf = pbuf[wid][hw];
    const short* xph = head ? xph1 : xph0;
    const float* alsh = als + (long)head * N_NODESC;
    const float* aldh = ald + (long)head * N_NODESC;
    const int e = hl >> 3;
    const int c = hl & 7;
    const char* xpb = (const char*)xph;
    const int c16 = c * 16;
    const float ad = aldh[n];
    float e0 = alsh[n] + ad;
    e0 = e0 > 0.f ? e0 : 0.2f * e0;
    const float pself = __expf(e0);
    const float pinit = e == 0 ? pself : 0.f;
    uint4 us = *(const uint4*)(xpb + (long)n * 128 + c16);
    float acc0 = pinit * ulo(us.x), acc1 = pinit * uhi(us.x);
    float acc2 = pinit * ulo(us.y), acc3 = pinit * uhi(us.y);
    float acc4 = pinit * ulo(us.z), acc5 = pinit * uhi(us.z);
    float acc6 = pinit * ulo(us.w), acc7 = pinit * uhi(us.w);
    float lp = 0.f;
    const int beg = row_start[n], end = row_start[n + 1];
    for (int base = beg; base < end; base += 32) {
        const int idx = base + hl;
        int s = 0;
        float p = 0.f;
        if (idx < end) {
            s = (int)col[idx];
            float t = alsh[s] + ad;
            t = t > 0.f ? t : 0.2f * t;
            p = __expf(t);
        }
        lp += p;
        mybuf[hl] = make_float2(p, __int_as_float(s << 7));
        int cnt = end - base; if (cnt > 32) cnt = 32;
        int quads = (cnt + 3) >> 2;
        int j = 0;
        for (; j + 4 <= quads; j += 4) {
            int a4[4]; float p4[4]; uint4 x[4];
            #pragma unroll
            for (int q = 0; q < 4; ++q) {
                float2 bv = mybuf[4 * (j + q) + e];
                a4[q] = __float_as_int(bv.y);
                p4[q] = bv.x;
            }
            #pragma unroll
            for (int q = 0; q < 4; ++q)
                x[q] = *(const uint4*)(xpb + a4[q] + c16);
            #pragma unroll
            for (int q = 0; q < 4; ++q) {
                acc0 = fmaf(p4[q], ulo(x[q].x), acc0);
                acc1 = fmaf(p4[q], uhi(x[q].x), acc1);
                acc2 = fmaf(p4[q], ulo(x[q].y), acc2);
                acc3 = fmaf(p4[q], uhi(x[q].y), acc3);
                acc4 = fmaf(p4[q], ulo(x[q].z), acc4);
                acc5 = fmaf(p4[q], uhi(x[q].z), acc5);
                acc6 = fmaf(p4[q], ulo(x[q].w), acc6);
                acc7 = fmaf(p4[q], uhi(x[q].w), acc7);
            }
        }
        for (; j < quads; ++j) {
            float2 bv = mybuf[4 * j + e];
            uint4 x = *(const uint4*)(xpb + __float_as_int(bv.y) + c16);
            float pv = bv.x;
            acc0 = fmaf(pv, ulo(x.x), acc0);
            acc1 = fmaf(pv, uhi(x.x), acc1);
            acc2 = fmaf(pv, ulo(x.y), acc2);
            acc3 = fmaf(pv, uhi(x.y), acc3);
            acc4 = fmaf(pv, ulo(x.z), acc4);
            acc5 = fmaf(pv, uhi(x.z), acc5);
            acc6 = fmaf(pv, ulo(x.w), acc6);
            acc7 = fmaf(pv, uhi(x.w), acc7);
        }
    }
    #pragma unroll
    for (int off = 16; off; off >>= 1) lp += __shfl_xor(lp, off, 64);
    #pragma unroll
    for (int off = 8; off <= 16; off <<= 1) {
        acc0 += __shfl_xor(acc0, off, 64);
        acc1 += __shfl_xor(acc1, off, 64);
        acc2 += __shfl_xor(acc2, off, 64);
        acc3 += __shfl_xor(acc3, off, 64);
        acc4 += __shfl_xor(acc4, off, 64);
        acc5 += __shfl_xor(acc5, off, 64);
        acc6 += __shfl_xor(acc6, off, 64);
        acc7 += __shfl_xor(acc7, off, 64);
    }
    if (hl < 8) {
        const float rl = 1.f / (lp + pself);
        const long bb = (long)head * 64 + 8 * c;
        float o0 = acc0 * rl + ldf(b1, bb + 0, fp32);
        float o1 = acc1 * rl + ldf(b1, bb + 1, fp32);
        float o2 = acc2 * rl + ldf(b1, bb + 2, fp32);
        float o3 = acc3 * rl + ldf(b1, bb + 3, fp32);
        float o4 = acc4 * rl + ldf(b1, bb + 4, fp32);
        float o5 = acc5 * rl + ldf(b1, bb + 5, fp32);
        float o6 = acc6 * rl + ldf(b1, bb + 6, fp32);
        float o7 = acc7 * rl + ldf(b1, bb + 7, fp32);
        uint4 o;
        o.x = pack2(o0, o1); o.y = pack2(o2, o3);
        o.z = pack2(o4, o5); o.w = pack2(o6, o7);
        *(uint4*)((char*)h1b32 + (long)n * 256 + head * 128 + c16) = o;
    }
}

// ---------------- Layer 2 GEMM via MFMA + fused logits (shuffle reduce) ----------------

__global__ __launch_bounds__(256) void gemm2_k(
        const unsigned* __restrict__ h1b32, const short* __restrict__ w2f,
        const void* __restrict__ as2, const void* __restrict__ ad2,
        const int* __restrict__ flags,
        short* __restrict__ xp2b, float* __restrict__ alsrc, float* __restrict__ aldst) {
    const int fp32 = flags[0];
    const int tid = threadIdx.x;
    const int nb = blockIdx.x * 32;
    __shared__ __align__(16) short xs[32][136];
    __shared__ float sredc[32][4], dredc[32][4];

    #pragma unroll
    for (int i = 0; i < 8; ++i) {
        int idx = i * 256 + tid;
        int r = idx >> 6, ii = idx & 63;
        int g = nb + r;
        unsigned val = (g < N_NODESC) ? h1b32[(long)g * 64 + ii] : 0u;
        ((unsigned*)&xs[r][0])[ii] = val;
    }
    __syncthreads();

    const int wid = tid >> 6, lane = tid & 63;
    const int quad = lane >> 4, l16 = lane & 15;
    floatx4 acc0 = (floatx4){0.f, 0.f, 0.f, 0.f};
    floatx4 acc1 = (floatx4){0.f, 0.f, 0.f, 0.f};
    #pragma unroll
    for (int t = 0; t < 4; ++t) {
        short8 a0 = *(const short8*)&xs[l16][t * 32 + quad * 8];
        short8 a1 = *(const short8*)&xs[16 + l16][t * 32 + quad * 8];
        short8 b = *(const short8*)&w2f[(((wid * 4 + t) * 4 + quad) * 16 + l16) * 8];
        acc0 = __builtin_amdgcn_mfma_f32_16x16x32_bf16(a0, b, acc0, 0, 0, 0);
        acc1 = __builtin_amdgcn_mfma_f32_16x16x32_bf16(a1, b, acc1, 0, 0, 0);
    }
    const int colg = wid * 16 + l16;
    const float asv = ldf(as2, colg, fp32), adv = ldf(ad2, colg, fp32);
    float sv0[4], dv0[4], sv1[4], dv1[4];
    #pragma unroll
    for (int reg = 0; reg < 4; ++reg) {
        int r0 = quad * 4 + reg;
        int g0 = nb + r0;
        int g1 = g0 + 16;
        if (g0 < N_NODESC) xp2b[(long)g0 * 64 + colg] = f2s(acc0[reg]);
        if (g1 < N_NODESC) xp2b[(long)g1 * 64 + colg] = f2s(acc1[reg]);
        sv0[reg] = acc0[reg] * asv; dv0[reg] = acc0[reg] * adv;
        sv1[reg] = acc1[reg] * asv; dv1[reg] = acc1[reg] * adv;
    }
    #pragma unroll
    for (int off = 1; off < 16; off <<= 1) {
        #pragma unroll
        for (int reg = 0; reg < 4; ++reg) {
            sv0[reg] += __shfl_xor(sv0[reg], off, 64);
            dv0[reg] += __shfl_xor(dv0[reg], off, 64);
            sv1[reg] += __shfl_xor(sv1[reg], off, 64);
            dv1[reg] += __shfl_xor(dv1[reg], off, 64);
        }
    }
    if (l16 == 0) {
        #pragma unroll
        for (int reg = 0; reg < 4; ++reg) {
            int r0 = quad * 4 + reg;
            sredc[r0][wid] = sv0[reg];      dredc[r0][wid] = dv0[reg];
            sredc[r0 + 16][wid] = sv1[reg]; dredc[r0 + 16][wid] = dv1[reg];
        }
    }
    __syncthreads();
    if (tid < 32) {
        int g = nb + tid;
        if (g < N_NODESC) {
            alsrc[g] = sredc[tid][0] + sredc[tid][1] + sredc[tid][2] + sredc[tid][3];
            aldst[g] = dredc[tid][0] + dredc[tid][1] + dredc[tid][2] + dredc[tid][3];
        }
    }
}

// ---------------- Layer 2 aggregation: split-wave + fused mean-pool (replicated) ----------------

__global__ __launch_bounds__(256) void agg2p_k(
        const int* __restrict__ row_start, const unsigned short* __restrict__ col,
        const short* __restrict__ xp2b, const float* __restrict__ alsrc,
        const float* __restrict__ aldst, const void* __restrict__ b2v,
        const int* __restrict__ flags, const int* __restrict__ batch32,
        float* __restrict__ pooled, float* __restrict__ counts) {
    const int fp32 = flags[0];
    const int tid = threadIdx.x;
    const int wid = tid >> 6;
    const int lane = tid & 63;
    const int hw = lane >> 5;
    const int hl = lane & 31;
    const int n = blockIdx.x * 8 + wid * 2 + hw;
    const int rep = blockIdx.x & (POOL_REP - 1);
    __shared__ float2 pbuf[4][2][32];
    __shared__ float psum[64];
    __shared__ int ginfo[2];
    if (tid < 64) psum[tid] = 0.f;
    if (tid == 0) {
        int g0 = batch32[blockIdx.x * 8];
        int g7 = batch32[blockIdx.x * 8 + 7];
        ginfo[0] = g0;
        ginfo[1] = (g0 == g7);
    }
    __syncthreads();
    float2* mybuf = pbuf[wid][hw];
    const int e = hl >> 3;
    const int c = hl & 7;
    const char* xpb = (const char*)xp2b;
    const int c16 = c * 16;
    const float ad = aldst[n];
    float e0 = alsrc[n] + ad;
    e0 = e0 > 0.f ? e0 : 0.2f * e0;
    const float pself = __expf(e0);
    const float pinit = e == 0 ? pself : 0.f;
    uint4 us = *(const uint4*)(xpb + (long)n * 128 + c16);
    float acc0 = pinit * ulo(us.x), acc1 = pinit * uhi(us.x);
    float acc2 = pinit * ulo(us.y), acc3 = pinit * uhi(us.y);
    float acc4 = pinit * ulo(us.z), acc5 = pinit * uhi(us.z);
    float acc6 = pinit * ulo(us.w), acc7 = pinit * uhi(us.w);
    float lp = 0.f;
    const int beg = row_start[n], end = row_start[n + 1];
    for (int base = beg; base < end; base += 32) {
        const int idx = base + hl;
        int s = 0;
        float p = 0.f;
        if (idx < end) {
            s = (int)col[idx];
            float t = alsrc[s] + ad;
            t = t > 0.f ? t : 0.2f * t;
            p = __expf(t);
        }
        lp += p;
        mybuf[hl] = make_float2(p, __int_as_float(s << 7));
        int cnt = end - base; if (cnt > 32) cnt = 32;
        int quads = (cnt + 3) >> 2;
        int j = 0;
        for (; j + 4 <= quads; j += 4) {
            int a4[4]; float p4[4]; uint4 x[4];
            #pragma unroll
            for (int q = 0; q < 4; ++q) {
                float2 bv = mybuf[4 * (j + q) + e];
                a4[q] = __float_as_int(bv.y);
                p4[q] = bv.x;
            }
            #pragma unroll
            for (int q = 0; q < 4; ++q)
                x[q] = *(const uint4*)(xpb + a4[q] + c16);
            #pragma unroll
            for (int q = 0; q < 4; ++q) {
                acc0 = fmaf(p4[q], ulo(x[q].x), acc0);
                acc1 = fmaf(p4[q], uhi(x[q].x), acc1);
                acc2 = fmaf(p4[q], ulo(x[q].y), acc2);
                acc3 = fmaf(p4[q], uhi(x[q].y), acc3);
                acc4 = fmaf(p4[q], ulo(x[q].z), acc4);
                acc5 = fmaf(p4[q], uhi(x[q].z), acc5);
                acc6 = fmaf(p4[q], ulo(x[q].w), acc6);
                acc7 = fmaf(p4[q], uhi(x[q].w), acc7);
            }
        }
        for (; j < quads; ++j) {
            float2 bv = mybuf[4 * j + e];
            uint4 x = *(const uint4*)(xpb + __float_as_int(bv.y) + c16);
            float pv = bv.x;
            acc0 = fmaf(pv, ulo(x.x), acc0);
            acc1 = fmaf(pv, uhi(x.x), acc1);
            acc2 = fmaf(pv, ulo(x.y), acc2);
            acc3 = fmaf(pv, uhi(x.y), acc3);
            acc4 = fmaf(pv, ulo(x.z), acc4);
            acc5 = fmaf(pv, uhi(x.z), acc5);
            acc6 = fmaf(pv, ulo(x.w), acc6);
            acc7 = fmaf(pv, uhi(x.w), acc7);
        }
    }
    #pragma unroll
    for (int off = 16; off; off >>= 1) lp += __shfl_xor(lp, off, 64);
    #pragma unroll
    for (int off = 8; off <= 16; off <<= 1) {
        acc0 += __shfl_xor(acc0, off, 64);
        acc1 += __shfl_xor(acc1, off, 64);
        acc2 += __shfl_xor(acc2, off, 64);
        acc3 += __shfl_xor(acc3, off, 64);
        acc4 += __shfl_xor(acc4, off, 64);
        acc5 += __shfl_xor(acc5, off, 64);
        acc6 += __shfl_xor(acc6, off, 64);
        acc7 += __shfl_xor(acc7, off, 64);
    }
    float o[8];
    if (hl < 8) {
        const float rl = 1.f / (lp + pself);
        o[0] = acc0 * rl + ldf(b2v, 8 * c + 0, fp32);
        o[1] = acc1 * rl + ldf(b2v, 8 * c + 1, fp32);
        o[2] = acc2 * rl + ldf(b2v, 8 * c + 2, fp32);
        o[3] = acc3 * rl + ldf(b2v, 8 * c + 3, fp32);
        o[4] = acc4 * rl + ldf(b2v, 8 * c + 4, fp32);
        o[5] = acc5 * rl + ldf(b2v, 8 * c + 5, fp32);
        o[6] = acc6 * rl + ldf(b2v, 8 * c + 6, fp32);
        o[7] = acc7 * rl + ldf(b2v, 8 * c + 7, fp32);
    }
    if (ginfo[1]) {
        if (hl < 8) {
            #pragma unroll
            for (int j = 0; j < 8; ++j) atomicAdd(&psum[8 * c + j], o[j]);
        }
        __syncthreads();
        if (tid < 64)
            atomicAdd(&pooled[((long)rep * NUM_GRAPHSC + ginfo[0]) * 64 + tid], psum[tid]);
        if (tid == 0) atomicAdd(&counts[rep * NUM_GRAPHSC + ginfo[0]], 8.f);
    } else {
        int g = batch32[n];
        if (hl < 8) {
            #pragma unroll
            for (int j = 0; j < 8; ++j)
                atomicAdd(&pooled[((long)rep * NUM_GRAPHSC + g) * 64 + 8 * c + j], o[j]);
        }
        if (hl == 0) atomicAdd(&counts[rep * NUM_GRAPHSC + g], 1.f);
    }
}

// ---------------- decoder MLP (sums pooled replicas) ----------------

__global__ __launch_bounds__(64) void dec_k(const float* __restrict__ pooled,
                                            const float* __restrict__ counts,
                                            const void* __restrict__ Wd1, const void* __restrict__ bd1,
                                            const void* __restrict__ Wd2, const void* __restrict__ bd2,
                                            const int* __restrict__ flags,
                                            void* __restrict__ out) {
    const int fp32 = flags[0];
    const int g = blockIdx.x, j = threadIdx.x;
    __shared__ float p[64], dh[64];
    float cnt = 0.f, ps = 0.f;
    #pragma unroll
    for (int r = 0; r < POOL_REP; ++r) {
        ps += pooled[((long)r * NUM_GRAPHSC + g) * 64 + j];
        if (j == 0) cnt += counts[r * NUM_GRAPHSC + g];
    }
    __shared__ float cnt_sh;
    if (j == 0) cnt_sh = cnt < 1.f ? 1.f : cnt;
    __syncthreads();
    p[j] = ps / cnt_sh;
    __syncthreads();
    float acc = ldf(bd1, j, fp32);
    for (int k = 0; k < 64; ++k) acc += p[k] * ldf(Wd1, k * 64 + j, fp32);
    dh[j] = acc > 0.f ? acc : 0.f;
    __syncthreads();
    if (j < 32) {
        float o = ldf(bd2, j, fp32);
        for (int k = 0; k < 64; ++k) o += dh[k] * ldf(Wd2, k * 32 + j, fp32);
        if (fp32) ((float*)out)[g * 32 + j] = o;
        else      ((bf16*)out)[g * 32 + j] = __float2bfloat16(o);
    }
}

extern "C" void kernel_launch(void* const* d_in, const int* in_sizes, int n_in,
                              void* d_out, int out_size, void* d_ws, size_t ws_size,
                              hipStream_t stream) {
    (void)in_sizes; (void)n_in; (void)out_size; (void)ws_size;
    const void* prot = d_in[0];
    const void* sp   = d_in[1];
    const void* lri  = d_in[2];
    const void* eidx = d_in[3];
    const void* batch= d_in[4];
    const void* W1   = d_in[5];
    const void* as1  = d_in[6];
    const void* ad1  = d_in[7];
    const void* b1   = d_in[8];
    const void* W2   = d_in[9];
    const void* as2  = d_in[10];
    const void* ad2  = d_in[11];
    const void* b2v  = d_in[12];
    const void* Wd1  = d_in[13];
    const void* bd1  = d_in[14];
    const void* Wd2  = d_in[15];
    const void* bd2  = d_in[16];

    char* w = (char*)d_ws;
    auto alloc = [&](size_t bytes) -> void* {
        char* p = w;
        w += (bytes + 255) & ~(size_t)255;
        return (void*)p;
    };
    int*   flags     = (int*)alloc(2 * 4);
    // --- contiguous memset region: pooled .. state ---
    float* pooled    = (float*)alloc((size_t)POOL_REP * NUM_GRAPHSC * 64 * 4);
    float* counts    = (float*)alloc((size_t)POOL_REP * NUM_GRAPHSC * 4);
    int*   scnt      = (int*)alloc((size_t)NSB * 4);
    int*   state     = (int*)alloc((size_t)NSB * 4);
    char*  zero_end  = w;
    // -------------------------------------------------
    int*   batch32   = (int*)alloc((size_t)N_NODESC * 4);
    int*   row_start = (int*)alloc((size_t)(N_NODESC + 1) * 4);
    unsigned* bucket2= (unsigned*)alloc((size_t)NSB * SBCAP * 4);
    unsigned short* col = (unsigned short*)alloc((size_t)N_EDGESC * 2);
    short* w1f       = (short*)alloc((size_t)16384 * 2);
    float* w1r       = (float*)alloc((size_t)256 * 4);
    short* w2f       = (short*)alloc((size_t)8192 * 2);
    short* xph0      = (short*)alloc((size_t)N_NODESC * 64 * 2);
    short* xph1      = (short*)alloc((size_t)N_NODESC * 64 * 2);
    float* alsrc1    = (float*)alloc((size_t)N_NODESC * 2 * 4);
    float* aldst1    = (float*)alloc((size_t)N_NODESC * 2 * 4);
    short* h1b       = (short*)alloc((size_t)N_NODESC * 128 * 2);
    short* xp2b      = (short*)alloc((size_t)N_NODESC * 64 * 2);
    float* alsrc2    = (float*)alloc((size_t)N_NODESC * 4);
    float* aldst2    = (float*)alloc((size_t)N_NODESC * 4);

    const int nbat = (N_NODESC + 255) / 256;
    const size_t zero_bytes = (size_t)(zero_end - (char*)pooled);

    hipMemsetAsync(pooled, 0, zero_bytes, stream);
    mega_k<<<NPART + 97 + nbat, 256, 0, stream>>>(eidx, prot, batch, W1, W2, flags,
                                                  w1f, w1r, w2f, batch32, scnt,
                                                  bucket2, nbat);
    const int nblk = (N_NODESC + 31) / 32;
    csrgemm1_k<<<NSB + nblk, 256, 0, stream>>>(bucket2, scnt, state, row_start, col,
                                               prot, sp, lri, w1f, w1r, as1, ad1,
                                               flags, xph0, xph1, alsrc1, aldst1);
    agg1s_k<<<2 * AGG_NB, 256, 0, stream>>>(row_start, col, xph0, xph1,
                                            alsrc1, aldst1, b1, flags,
                                            (unsigned*)h1b);
    gemm2_k<<<nblk, 256, 0, stream>>>((const unsigned*)h1b, w2f, as2, ad2, flags,
                                      xp2b, alsrc2, aldst2);
    agg2p_k<<<AGG_NB, 256, 0, stream>>>(row_start, col, xp2b, alsrc2, aldst2,
                                        b2v, flags, batch32, pooled, counts);
    dec_k<<<NUM_GRAPHSC, 64, 0, stream>>>(pooled, counts, Wd1, bd1, Wd2, bd2, flags, d_out);
}

// Round 9
// 281.235 us; speedup vs baseline: 1.4843x; 1.0759x over previous
//
#include <hip/hip_runtime.h>
#include <hip/hip_bf16.h>

#define N_NODESC 50000
#define N_EDGESC 1600000
#define NUM_GRAPHSC 64
#define P_EPB 2048            // edges per block in part path
#define NPART ((N_EDGESC + P_EPB - 1) / P_EPB)   // 782
#define SUBW 196              // nodes per sub-bucket (256 buckets cover 50000)
#define NSB 256               // number of sub-buckets
#define SBCAP 8192            // per-sub-bucket capacity (avg 6250, max ~6600)
#define POOL_REP 32           // pooled replicas to kill atomic contention
#define AGG_NB 6250           // 50000 / 8 nodes per block (split-wave)

typedef __hip_bfloat16 bf16;
typedef short short8 __attribute__((ext_vector_type(8)));
typedef float floatx4 __attribute__((ext_vector_type(4)));

__device__ __forceinline__ float ldf(const void* p, long i, int fp32) {
    return fp32 ? ((const float*)p)[i] : __bfloat162float(((const bf16*)p)[i]);
}
__device__ __forceinline__ short f2s(float v) {
    bf16 h = __float2bfloat16(v);
    return *(short*)&h;
}
__device__ __forceinline__ unsigned pack2(float lo, float hi) {
    bf16 a = __float2bfloat16(lo), b = __float2bfloat16(hi);
    unsigned ua = *(unsigned short*)&a, ub = *(unsigned short*)&b;
    return (ub << 16) | ua;
}
__device__ __forceinline__ float ulo(unsigned u) { return __uint_as_float(u << 16); }
__device__ __forceinline__ float uhi(unsigned u) { return __uint_as_float(u & 0xffff0000u); }

// ---------------- inline dtype detection (per-block, ~100 loads) ----------------
__device__ __forceinline__ int detect_fp32_dev(const void* prot) {
    const bf16* pb = (const bf16*)prot;
    int sane = 0;
    for (int i = 0; i < 64; ++i) {
        float a = fabsf(__bfloat162float(pb[2 * i]));
        if (a > 1e-8f && a < 1e4f) sane++;
    }
    return (sane >= 48) ? 0 : 1;
}
__device__ __forceinline__ int detect_i64_dev(const void* eidx) {
    const unsigned* u = (const unsigned*)eidx;
    int zhi = 0;
    for (int i = 0; i < 32; ++i)
        if (u[2 * i + 1] == 0u) zhi++;
    return (zhi >= 30) ? 1 : 0;
}

// ---------------- mega: edge partition ∥ weight prep ∥ batch cvt (one launch) ----------------
__global__ __launch_bounds__(256) void mega_k(const void* __restrict__ eidx,
                                              const void* __restrict__ prot,
                                              const void* __restrict__ batch,
                                              const void* __restrict__ W1,
                                              const void* __restrict__ W2,
                                              int* __restrict__ flags,
                                              short* __restrict__ w1f,
                                              float* __restrict__ w1r,
                                              short* __restrict__ w2f,
                                              int* __restrict__ b32,
                                              int* __restrict__ scnt,
                                              unsigned* __restrict__ bucket2,
                                              int nbat) {
    const int b = blockIdx.x, tid = threadIdx.x;
    __shared__ int cnt[NSB];
    __shared__ int sc[NSB];
    __shared__ int gbase[NSB];
    __shared__ int cur[NSB];
    __shared__ unsigned buf[P_EPB];
    __shared__ int sflag;

    if (b < NPART) {
        // ---- edge partition path ----
        if (tid == 0) sflag = detect_i64_dev(eidx);
        cnt[tid] = 0;
        __syncthreads();
        const int i64f = sflag;
        const long e0 = (long)b * P_EPB;
        unsigned ev[8];
        int bk[8];
        #pragma unroll
        for (int i = 0; i < 8; ++i) {
            long e = e0 + i * 256 + tid;
            bk[i] = -1;
            if (e < N_EDGESC) {
                int s, d;
                if (i64f) {
                    s = (int)((const long long*)eidx)[e];
                    d = (int)((const long long*)eidx)[N_EDGESC + e];
                } else {
                    s = ((const int*)eidx)[e];
                    d = ((const int*)eidx)[N_EDGESC + e];
                }
                int sub = (d >> 2) / 49;             // = d / 196 exact
                bk[i] = sub;
                ev[i] = (unsigned)s | ((unsigned)(d - sub * SUBW) << 16)
                                    | ((unsigned)sub << 24);
                atomicAdd(&cnt[sub], 1);
            }
        }
        __syncthreads();
        const int myc = cnt[tid];
        sc[tid] = myc;
        __syncthreads();
        #pragma unroll
        for (int off = 1; off < NSB; off <<= 1) {
            int t = (tid >= off) ? sc[tid - off] : 0;
            __syncthreads();
            sc[tid] += t;
            __syncthreads();
        }
        cnt[tid] = sc[tid] - myc;                    // exclusive prefix
        gbase[tid] = myc ? atomicAdd(&scnt[tid], myc) : 0;
        cur[tid] = sc[tid] - myc;
        __syncthreads();
        #pragma unroll
        for (int i = 0; i < 8; ++i) {
            if (bk[i] >= 0) {
                int p = atomicAdd(&cur[bk[i]], 1);
                buf[p] = ev[i];
            }
        }
        __syncthreads();
        const int total = sc[NSB - 1];
        for (int p = tid; p < total; p += 256) {
            unsigned v = buf[p];
            int lo = (int)(v >> 24);
            bucket2[(long)lo * SBCAP + gbase[lo] + (p - cnt[lo])] = v & 0xffffffu;
        }
        return;
    }
    const int wb = b - NPART;
    if (wb < 97) {
        if (tid == 0) {
            sflag = detect_fp32_dev(prot);
            if (wb == 0) {                           // publish flags for later kernels
                flags[0] = sflag;
                flags[1] = detect_i64_dev(eidx);
            }
        }
        __syncthreads();
        const int fp32 = sflag;
        if (wb < 64) {
            int idx = wb * 256 + tid;                // 16384
            int kp = idx >> 7, n = idx & 127;
            int krow = kp < 64 ? kp : 66 + (kp - 64);
            float v = ldf(W1, (long)krow * 128 + n, fp32);
            int c = n >> 4, nn = n & 15, t = kp >> 5, q = (kp >> 3) & 3, j = kp & 7;
            w1f[(((c * 4 + t) * 4 + q) * 16 + nn) * 8 + j] = f2s(v);
        } else if (wb == 64) {
            int which = tid >> 7, n = tid & 127;     // W1 rows 64,65 (spatial)
            w1r[which * 128 + n] = ldf(W1, (long)(64 + which) * 128 + n, fp32);
        } else {
            int idx = (wb - 65) * 256 + tid;         // 8192
            int k = idx >> 6, n = idx & 63;
            float v = ldf(W2, (long)k * 64 + n, fp32);
            int c = n >> 4, nn = n & 15, t = k >> 5, q = (k >> 3) & 3, j = k & 7;
            w2f[(((c * 4 + t) * 4 + q) * 16 + nn) * 8 + j] = f2s(v);
        }
        return;
    }
    // ---- batch cvt path ----
    if (tid == 0) sflag = detect_i64_dev(eidx);
    __syncthreads();
    const int i64f = sflag;
    int i = (wb - 97) * 256 + tid;
    if (i < N_NODESC)
        b32[i] = i64f ? (int)((const long long*)batch)[i] : ((const int*)batch)[i];
    (void)nbat;
}

// ---------------- csr ∥ gemm1 (one launch, NO cross-block sync) ----------------
// Blocks [0,NSB): CSR build. Bucket-level prefix computed per-block by a masked
// reduction over scnt[0..sb) — scnt is final after mega_k, so no lookback/spin.
// Blocks [NSB, NSB+nblk): layer-1 MFMA GEMM + fused logits.
__global__ __launch_bounds__(256) void csrgemm1_k(
        const unsigned* __restrict__ bucket2, const int* __restrict__ scnt,
        int* __restrict__ row_start, unsigned short* __restrict__ col,
        const void* __restrict__ prot, const void* __restrict__ sp,
        const void* __restrict__ lri,
        const short* __restrict__ w1f, const float* __restrict__ w1r,
        const void* __restrict__ as1, const void* __restrict__ ad1,
        const int* __restrict__ flags,
        short* __restrict__ xph0, short* __restrict__ xph1,
        float* __restrict__ alsrc, float* __restrict__ aldst) {
    const int tid = threadIdx.x;
    __shared__ int lh[SUBW];
    __shared__ int sc[256];
    __shared__ int ws[4];
    __shared__ __align__(16) short xs[32][136];
    __shared__ float xsp[32][2];
    __shared__ float sredc[32][8], dredc[32][8];

    if (blockIdx.x < NSB) {
        // ---- CSR path ----
        const int sb = blockIdx.x;
        const int lane = tid & 63;
        const int cnt = scnt[sb];
        const unsigned* B = bucket2 + (long)sb * SBCAP;
        const int nodebase = sb * SUBW;
        const int width = min(SUBW, N_NODESC - nodebase);
        // bucket-level prefix: sum scnt[0..sb) via block reduction (no spin)
        int v = (tid < sb) ? scnt[tid] : 0;
        #pragma unroll
        for (int off = 32; off; off >>= 1) v += __shfl_xor(v, off, 64);
        if (lane == 0) ws[tid >> 6] = v;
        for (int i = tid; i < SUBW; i += 256) lh[i] = 0;
        __syncthreads();
        const int sprefix = ws[0] + ws[1] + ws[2] + ws[3];
        for (int e = tid; e < cnt; e += 256) atomicAdd(&lh[B[e] >> 16], 1);
        __syncthreads();
        const int myc = (tid < SUBW) ? lh[tid] : 0;
        sc[tid] = myc;
        __syncthreads();
        for (int off = 1; off < 256; off <<= 1) {
            int t = (tid >= off) ? sc[tid - off] : 0;
            __syncthreads();
            sc[tid] += t;
            __syncthreads();
        }
        if (tid < width) row_start[nodebase + tid] = sprefix + sc[tid] - myc;
        if (sb == NSB - 1 && tid == 0) row_start[N_NODESC] = N_EDGESC;
        if (tid < SUBW) lh[tid] = sprefix + sc[tid] - myc;   // cursor
        __syncthreads();
        for (int e = tid; e < cnt; e += 256) {
            unsigned vv = B[e];
            int pos = atomicAdd(&lh[vv >> 16], 1);
            col[pos] = (unsigned short)(vv & 0xffffu);
        }
        return;
    }

    // ---- gemm1 path ----
    const int fp32 = flags[0];
    const int nb = (blockIdx.x - NSB) * 32;
    if (!fp32) {
        #pragma unroll
        for (int i = 0; i < 2; ++i) {
            int cidx = i * 256 + tid;
            int r = cidx >> 4, cc = cidx & 15;
            int g = nb + r;
            short8 v = (short8){0, 0, 0, 0, 0, 0, 0, 0};
            if (g < N_NODESC) {
                const short* srcp = (cc < 8)
                    ? (const short*)prot + (long)g * 64 + cc * 8
                    : (const short*)lri + (long)g * 64 + (cc - 8) * 8;
                v = *(const short8*)srcp;
            }
            *(short8*)&xs[r][cc * 8] = v;
        }
    } else {
        #pragma unroll
        for (int i = 0; i < 16; ++i) {
            int idx = i * 256 + tid;
            int r = idx >> 7, k = idx & 127;
            int g = nb + r;
            float v = 0.f;
            if (g < N_NODESC)
                v = (k < 64) ? ((const float*)prot)[(long)g * 64 + k]
                             : ((const float*)lri)[(long)g * 64 + (k - 64)];
            xs[r][k] = f2s(v);
        }
    }
    if (tid < 64) {
        int r = tid >> 1, which = tid & 1;
        int g = nb + r;
        xsp[r][which] = (g < N_NODESC) ? ldf(sp, (long)g * 2 + which, fp32) : 0.f;
    }
    __syncthreads();

    const int wid = tid >> 6, lane = tid & 63;
    const int quad = lane >> 4, l16 = lane & 15;
    floatx4 acc[2][2];
    #pragma unroll
    for (int a = 0; a < 2; ++a)
        #pragma unroll
        for (int bb = 0; bb < 2; ++bb) acc[a][bb] = (floatx4){0.f, 0.f, 0.f, 0.f};

    const int c0 = 2 * wid;
    #pragma unroll
    for (int t = 0; t < 4; ++t) {
        short8 a0 = *(const short8*)&xs[l16][t * 32 + quad * 8];
        short8 a1 = *(const short8*)&xs[16 + l16][t * 32 + quad * 8];
        short8 b0 = *(const short8*)&w1f[(((c0 * 4 + t) * 4 + quad) * 16 + l16) * 8];
        short8 b1 = *(const short8*)&w1f[((((c0 + 1) * 4 + t) * 4 + quad) * 16 + l16) * 8];
        acc[0][0] = __builtin_amdgcn_mfma_f32_16x16x32_bf16(a0, b0, acc[0][0], 0, 0, 0);
        acc[0][1] = __builtin_amdgcn_mfma_f32_16x16x32_bf16(a0, b1, acc[0][1], 0, 0, 0);
        acc[1][0] = __builtin_amdgcn_mfma_f32_16x16x32_bf16(a1, b0, acc[1][0], 0, 0, 0);
        acc[1][1] = __builtin_amdgcn_mfma_f32_16x16x32_bf16(a1, b1, acc[1][1], 0, 0, 0);
    }
    #pragma unroll
    for (int ci = 0; ci < 2; ++ci) {
        int colg = (c0 + ci) * 16 + l16;
        float w0 = w1r[colg], w1v = w1r[128 + colg];
        float asv = ldf(as1, colg, fp32), adv = ldf(ad1, colg, fp32);
        short* xpd = (colg < 64) ? xph0 : xph1;
        const int cc = colg & 63;
        #pragma unroll
        for (int rt = 0; rt < 2; ++rt) {
            float sv[4], dv[4];
            #pragma unroll
            for (int reg = 0; reg < 4; ++reg) {
                int row = rt * 16 + quad * 4 + reg;
                int g = nb + row;
                float v = acc[rt][ci][reg] + xsp[row][0] * w0 + xsp[row][1] * w1v;
                if (g < N_NODESC) xpd[(long)g * 64 + cc] = f2s(v);
                sv[reg] = v * asv;
                dv[reg] = v * adv;
            }
            #pragma unroll
            for (int off = 1; off < 16; off <<= 1) {
                #pragma unroll
                for (int reg = 0; reg < 4; ++reg) {
                    sv[reg] += __shfl_xor(sv[reg], off, 64);
                    dv[reg] += __shfl_xor(dv[reg], off, 64);
                }
            }
            if (l16 == 0) {
                #pragma unroll
                for (int reg = 0; reg < 4; ++reg) {
                    int row = rt * 16 + quad * 4 + reg;
                    sredc[row][c0 + ci] = sv[reg];
                    dredc[row][c0 + ci] = dv[reg];
                }
            }
        }
    }
    __syncthreads();
    if (tid < 64) {
        int r = tid >> 1, h = tid & 1;
        int g = nb + r;
        if (g < N_NODESC) {
            alsrc[(long)h * N_NODESC + g] = sredc[r][4 * h] + sredc[r][4 * h + 1] +
                                            sredc[r][4 * h + 2] + sredc[r][4 * h + 3];
            aldst[(long)h * N_NODESC + g] = dredc[r][4 * h] + dredc[r][4 * h + 1] +
                                            dredc[r][4 * h + 2] + dredc[r][4 * h + 3];
        }
    }
}

// ---------------- Layer 1 aggregation: split-wave, both heads in one launch ----------------

__global__ __launch_bounds__(256) void agg1s_k(
        const int* __restrict__ row_start, const unsigned short* __restrict__ col,
        const short* __restrict__ xph0, const short* __restrict__ xph1,
        const float* __restrict__ als, const float* __restrict__ ald,
        const void* __restrict__ b1, const int* __restrict__ flags,
        unsigned* __restrict__ h1b32) {
    const int fp32 = flags[0];
    const int tid = threadIdx.x;
    const int wid = tid >> 6;
    const int lane = tid & 63;
    const int hw = lane >> 5;         // half-wave = node parity
    const int hl = lane & 31;
    const int head = blockIdx.x >= AGG_NB;
    const int b = blockIdx.x - head * AGG_NB;
    const int n = b * 8 + wid * 2 + hw;
    __shared__ float2 pbuf[4][2][32];
    float2* mybuf = pbuf[wid][hw];
    const short* xph = head ? xph1 : xph0;
    const float* alsh = als + (long)head * N_NODESC;
    const float* aldh = ald + (long)head * N_NODESC;
    const int e = hl >> 3;
    const int c = hl & 7;
    const char* xpb = (const char*)xph;
    const int c16 = c * 16;
    const float ad = aldh[n];
    float e0 = alsh[n] + ad;
    e0 = e0 > 0.f ? e0 : 0.2f * e0;
    const float pself = __expf(e0);
    const float pinit = e == 0 ? pself : 0.f;
    uint4 us = *(const uint4*)(xpb + (long)n * 128 + c16);
    float acc0 = pinit * ulo(us.x), acc1 = pinit * uhi(us.x);
    float acc2 = pinit * ulo(us.y), acc3 = pinit * uhi(us.y);
    float acc4 = pinit * ulo(us.z), acc5 = pinit * uhi(us.z);
    float acc6 = pinit * ulo(us.w), acc7 = pinit * uhi(us.w);
    float lp = 0.f;
    const int beg = row_start[n], end = row_start[n + 1];
    for (int base = beg; base < end; base += 32) {
        const int idx = base + hl;
        int s = 0;
        float p = 0.f;
        if (idx < end) {
            s = (int)col[idx];
            float t = alsh[s] + ad;
            t = t > 0.f ? t : 0.2f * t;
            p = __expf(t);
        }
        lp += p;
        mybuf[hl] = make_float2(p, __int_as_float(s << 7));
        int cnt = end - base; if (cnt > 32) cnt = 32;
        int quads = (cnt + 3) >> 2;
        int j = 0;
        for (; j + 4 <= quads; j += 4) {
            int a4[4]; float p4[4]; uint4 x[4];
            #pragma unroll
            for (int q = 0; q < 4; ++q) {
                float2 bv = mybuf[4 * (j + q) + e];
                a4[q] = __float_as_int(bv.y);
                p4[q] = bv.x;
            }
            #pragma unroll
            for (int q = 0; q < 4; ++q)
                x[q] = *(const uint4*)(xpb + a4[q] + c16);
            #pragma unroll
            for (int q = 0; q < 4; ++q) {
                acc0 = fmaf(p4[q], ulo(x[q].x), acc0);
                acc1 = fmaf(p4[q], uhi(x[q].x), acc1);
                acc2 = fmaf(p4[q], ulo(x[q].y), acc2);
                acc3 = fmaf(p4[q], uhi(x[q].y), acc3);
                acc4 = fmaf(p4[q], ulo(x[q].z), acc4);
                acc5 = fmaf(p4[q], uhi(x[q].z), acc5);
                acc6 = fmaf(p4[q], ulo(x[q].w), acc6);
                acc7 = fmaf(p4[q], uhi(x[q].w), acc7);
            }
        }
        for (; j < quads; ++j) {
            float2 bv = mybuf[4 * j + e];
            uint4 x = *(const uint4*)(xpb + __float_as_int(bv.y) + c16);
            float pv = bv.x;
            acc0 = fmaf(pv, ulo(x.x), acc0);
            acc1 = fmaf(pv, uhi(x.x), acc1);
            acc2 = fmaf(pv, ulo(x.y), acc2);
            acc3 = fmaf(pv, uhi(x.y), acc3);
            acc4 = fmaf(pv, ulo(x.z), acc4);
            acc5 = fmaf(pv, uhi(x.z), acc5);
            acc6 = fmaf(pv, ulo(x.w), acc6);
            acc7 = fmaf(pv, uhi(x.w), acc7);
        }
    }
    #pragma unroll
    for (int off = 16; off; off >>= 1) lp += __shfl_xor(lp, off, 64);
    #pragma unroll
    for (int off = 8; off <= 16; off <<= 1) {
        acc0 += __shfl_xor(acc0, off, 64);
        acc1 += __shfl_xor(acc1, off, 64);
        acc2 += __shfl_xor(acc2, off, 64);
        acc3 += __shfl_xor(acc3, off, 64);
        acc4 += __shfl_xor(acc4, off, 64);
        acc5 += __shfl_xor(acc5, off, 64);
        acc6 += __shfl_xor(acc6, off, 64);
        acc7 += __shfl_xor(acc7, off, 64);
    }
    if (hl < 8) {
        const float rl = 1.f / (lp + pself);
        const long bb = (long)head * 64 + 8 * c;
        float o0 = acc0 * rl + ldf(b1, bb + 0, fp32);
        float o1 = acc1 * rl + ldf(b1, bb + 1, fp32);
        float o2 = acc2 * rl + ldf(b1, bb + 2, fp32);
        float o3 = acc3 * rl + ldf(b1, bb + 3, fp32);
        float o4 = acc4 * rl + ldf(b1, bb + 4, fp32);
        float o5 = acc5 * rl + ldf(b1, bb + 5, fp32);
        float o6 = acc6 * rl + ldf(b1, bb + 6, fp32);
        float o7 = acc7 * rl + ldf(b1, bb + 7, fp32);
        uint4 o;
        o.x = pack2(o0, o1); o.y = pack2(o2, o3);
        o.z = pack2(o4, o5); o.w = pack2(o6, o7);
        *(uint4*)((char*)h1b32 + (long)n * 256 + head * 128 + c16) = o;
    }
}

// ---------------- Layer 2 GEMM via MFMA + fused logits (shuffle reduce) ----------------

__global__ __launch_bounds__(256) void gemm2_k(
        const unsigned* __restrict__ h1b32, const short* __restrict__ w2f,
        const void* __restrict__ as2, const void* __restrict__ ad2,
        const int* __restrict__ flags,
        short* __restrict__ xp2b, float* __restrict__ alsrc, float* __restrict__ aldst) {
    const int fp32 = flags[0];
    const int tid = threadIdx.x;
    const int nb = blockIdx.x * 32;
    __shared__ __align__(16) short xs[32][136];
    __shared__ float sredc[32][4], dredc[32][4];

    #pragma unroll
    for (int i = 0; i < 8; ++i) {
        int idx = i * 256 + tid;
        int r = idx >> 6, ii = idx & 63;
        int g = nb + r;
        unsigned val = (g < N_NODESC) ? h1b32[(long)g * 64 + ii] : 0u;
        ((unsigned*)&xs[r][0])[ii] = val;
    }
    __syncthreads();

    const int wid = tid >> 6, lane = tid & 63;
    const int quad = lane >> 4, l16 = lane & 15;
    floatx4 acc0 = (floatx4){0.f, 0.f, 0.f, 0.f};
    floatx4 acc1 = (floatx4){0.f, 0.f, 0.f, 0.f};
    #pragma unroll
    for (int t = 0; t < 4; ++t) {
        short8 a0 = *(const short8*)&xs[l16][t * 32 + quad * 8];
        short8 a1 = *(const short8*)&xs[16 + l16][t * 32 + quad * 8];
        short8 b = *(const short8*)&w2f[(((wid * 4 + t) * 4 + quad) * 16 + l16) * 8];
        acc0 = __builtin_amdgcn_mfma_f32_16x16x32_bf16(a0, b, acc0, 0, 0, 0);
        acc1 = __builtin_amdgcn_mfma_f32_16x16x32_bf16(a1, b, acc1, 0, 0, 0);
    }
    const int colg = wid * 16 + l16;
    const float asv = ldf(as2, colg, fp32), adv = ldf(ad2, colg, fp32);
    float sv0[4], dv0[4], sv1[4], dv1[4];
    #pragma unroll
    for (int reg = 0; reg < 4; ++reg) {
        int r0 = quad * 4 + reg;
        int g0 = nb + r0;
        int g1 = g0 + 16;
        if (g0 < N_NODESC) xp2b[(long)g0 * 64 + colg] = f2s(acc0[reg]);
        if (g1 < N_NODESC) xp2b[(long)g1 * 64 + colg] = f2s(acc1[reg]);
        sv0[reg] = acc0[reg] * asv; dv0[reg] = acc0[reg] * adv;
        sv1[reg] = acc1[reg] * asv; dv1[reg] = acc1[reg] * adv;
    }
    #pragma unroll
    for (int off = 1; off < 16; off <<= 1) {
        #pragma unroll
        for (int reg = 0; reg < 4; ++reg) {
            sv0[reg] += __shfl_xor(sv0[reg], off, 64);
            dv0[reg] += __shfl_xor(dv0[reg], off, 64);
            sv1[reg] += __shfl_xor(sv1[reg], off, 64);
            dv1[reg] += __shfl_xor(dv1[reg], off, 64);
        }
    }
    if (l16 == 0) {
        #pragma unroll
        for (int reg = 0; reg < 4; ++reg) {
            int r0 = quad * 4 + reg;
            sredc[r0][wid] = sv0[reg];      dredc[r0][wid] = dv0[reg];
            sredc[r0 + 16][wid] = sv1[reg]; dredc[r0 + 16][wid] = dv1[reg];
        }
    }
    __syncthreads();
    if (tid < 32) {
        int g = nb + tid;
        if (g < N_NODESC) {
            alsrc[g] = sredc[tid][0] + sredc[tid][1] + sredc[tid][2] + sredc[tid][3];
            aldst[g] = dredc[tid][0] + dredc[tid][1] + dredc[tid][2] + dredc[tid][3];
        }
    }
}

// ---------------- Layer 2 aggregation: split-wave + fused mean-pool (replicated) ----------------

__global__ __launch_bounds__(256) void agg2p_k(
        const int* __restrict__ row_start, const unsigned short* __restrict__ col,
        const short* __restrict__ xp2b, const float* __restrict__ alsrc,
        const float* __restrict__ aldst, const void* __restrict__ b2v,
        const int* __restrict__ flags, const int* __restrict__ batch32,
        float* __restrict__ pooled, float* __restrict__ counts) {
    const int fp32 = flags[0];
    const int tid = threadIdx.x;
    const int wid = tid >> 6;
    const int lane = tid & 63;
    const int hw = lane >> 5;
    const int hl = lane & 31;
    const int n = blockIdx.x * 8 + wid * 2 + hw;
    const int rep = blockIdx.x & (POOL_REP - 1);
    __shared__ float2 pbuf[4][2][32];
    __shared__ float psum[64];
    __shared__ int ginfo[2];
    if (tid < 64) psum[tid] = 0.f;
    if (tid == 0) {
        int g0 = batch32[blockIdx.x * 8];
        int g7 = batch32[blockIdx.x * 8 + 7];
        ginfo[0] = g0;
        ginfo[1] = (g0 == g7);
    }
    __syncthreads();
    float2* mybuf = pbuf[wid][hw];
    const int e = hl >> 3;
    const int c = hl & 7;
    const char* xpb = (const char*)xp2b;
    const int c16 = c * 16;
    const float ad = aldst[n];
    float e0 = alsrc[n] + ad;
    e0 = e0 > 0.f ? e0 : 0.2f * e0;
    const float pself = __expf(e0);
    const float pinit = e == 0 ? pself : 0.f;
    uint4 us = *(const uint4*)(xpb + (long)n * 128 + c16);
    float acc0 = pinit * ulo(us.x), acc1 = pinit * uhi(us.x);
    float acc2 = pinit * ulo(us.y), acc3 = pinit * uhi(us.y);
    float acc4 = pinit * ulo(us.z), acc5 = pinit * uhi(us.z);
    float acc6 = pinit * ulo(us.w), acc7 = pinit * uhi(us.w);
    float lp = 0.f;
    const int beg = row_start[n], end = row_start[n + 1];
    for (int base = beg; base < end; base += 32) {
        const int idx = base + hl;
        int s = 0;
        float p = 0.f;
        if (idx < end) {
            s = (int)col[idx];
            float t = alsrc[s] + ad;
            t = t > 0.f ? t : 0.2f * t;
            p = __expf(t);
        }
        lp += p;
        mybuf[hl] = make_float2(p, __int_as_float(s << 7));
        int cnt = end - base; if (cnt > 32) cnt = 32;
        int quads = (cnt + 3) >> 2;
        int j = 0;
        for (; j + 4 <= quads; j += 4) {
            int a4[4]; float p4[4]; uint4 x[4];
            #pragma unroll
            for (int q = 0; q < 4; ++q) {
                float2 bv = mybuf[4 * (j + q) + e];
                a4[q] = __float_as_int(bv.y);
                p4[q] = bv.x;
            }
            #pragma unroll
            for (int q = 0; q < 4; ++q)
                x[q] = *(const uint4*)(xpb + a4[q] + c16);
            #pragma unroll
            for (int q = 0; q < 4; ++q) {
                acc0 = fmaf(p4[q], ulo(x[q].x), acc0);
                acc1 = fmaf(p4[q], uhi(x[q].x), acc1);
                acc2 = fmaf(p4[q], ulo(x[q].y), acc2);
                acc3 = fmaf(p4[q], uhi(x[q].y), acc3);
                acc4 = fmaf(p4[q], ulo(x[q].z), acc4);
                acc5 = fmaf(p4[q], uhi(x[q].z), acc5);
                acc6 = fmaf(p4[q], ulo(x[q].w), acc6);
                acc7 = fmaf(p4[q], uhi(x[q].w), acc7);
            }
        }
        for (; j < quads; ++j) {
            float2 bv = mybuf[4 * j + e];
            uint4 x = *(const uint4*)(xpb + __float_as_int(bv.y) + c16);
            float pv = bv.x;
            acc0 = fmaf(pv, ulo(x.x), acc0);
            acc1 = fmaf(pv, uhi(x.x), acc1);
            acc2 = fmaf(pv, ulo(x.y), acc2);
            acc3 = fmaf(pv, uhi(x.y), acc3);
            acc4 = fmaf(pv, ulo(x.z), acc4);
            acc5 = fmaf(pv, uhi(x.z), acc5);
            acc6 = fmaf(pv, ulo(x.w), acc6);
            acc7 = fmaf(pv, uhi(x.w), acc7);
        }
    }
    #pragma unroll
    for (int off = 16; off; off >>= 1) lp += __shfl_xor(lp, off, 64);
    #pragma unroll
    for (int off = 8; off <= 16; off <<= 1) {
        acc0 += __shfl_xor(acc0, off, 64);
        acc1 += __shfl_xor(acc1, off, 64);
        acc2 += __shfl_xor(acc2, off, 64);
        acc3 += __shfl_xor(acc3, off, 64);
        acc4 += __shfl_xor(acc4, off, 64);
        acc5 += __shfl_xor(acc5, off, 64);
        acc6 += __shfl_xor(acc6, off, 64);
        acc7 += __shfl_xor(acc7, off, 64);
    }
    float o[8];
    if (hl < 8) {
        const float rl = 1.f / (lp + pself);
        o[0] = acc0 * rl + ldf(b2v, 8 * c + 0, fp32);
        o[1] = acc1 * rl + ldf(b2v, 8 * c + 1, fp32);
        o[2] = acc2 * rl + ldf(b2v, 8 * c + 2, fp32);
        o[3] = acc3 * rl + ldf(b2v, 8 * c + 3, fp32);
        o[4] = acc4 * rl + ldf(b2v, 8 * c + 4, fp32);
        o[5] = acc5 * rl + ldf(b2v, 8 * c + 5, fp32);
        o[6] = acc6 * rl + ldf(b2v, 8 * c + 6, fp32);
        o[7] = acc7 * rl + ldf(b2v, 8 * c + 7, fp32);
    }
    if (ginfo[1]) {
        if (hl < 8) {
            #pragma unroll
            for (int j = 0; j < 8; ++j) atomicAdd(&psum[8 * c + j], o[j]);
        }
        __syncthreads();
        if (tid < 64)
            atomicAdd(&pooled[((long)rep * NUM_GRAPHSC + ginfo[0]) * 64 + tid], psum[tid]);
        if (tid == 0) atomicAdd(&counts[rep * NUM_GRAPHSC + ginfo[0]], 8.f);
    } else {
        int g = batch32[n];
        if (hl < 8) {
            #pragma unroll
            for (int j = 0; j < 8; ++j)
                atomicAdd(&pooled[((long)rep * NUM_GRAPHSC + g) * 64 + 8 * c + j], o[j]);
        }
        if (hl == 0) atomicAdd(&counts[rep * NUM_GRAPHSC + g], 1.f);
    }
}

// ---------------- decoder MLP (sums pooled replicas) ----------------

__global__ __launch_bounds__(64) void dec_k(const float* __restrict__ pooled,
                                            const float* __restrict__ counts,
                                            const void* __restrict__ Wd1, const void* __restrict__ bd1,
                                            const void* __restrict__ Wd2, const void* __restrict__ bd2,
                                            const int* __restrict__ flags,
                                            void* __restrict__ out) {
    const int fp32 = flags[0];
    const int g = blockIdx.x, j = threadIdx.x;
    __shared__ float p[64], dh[64];
    float cnt = 0.f, ps = 0.f;
    #pragma unroll
    for (int r = 0; r < POOL_REP; ++r) {
        ps += pooled[((long)r * NUM_GRAPHSC + g) * 64 + j];
        if (j == 0) cnt += counts[r * NUM_GRAPHSC + g];
    }
    __shared__ float cnt_sh;
    if (j == 0) cnt_sh = cnt < 1.f ? 1.f : cnt;
    __syncthreads();
    p[j] = ps / cnt_sh;
    __syncthreads();
    float acc = ldf(bd1, j, fp32);
    for (int k = 0; k < 64; ++k) acc += p[k] * ldf(Wd1, k * 64 + j, fp32);
    dh[j] = acc > 0.f ? acc : 0.f;
    __syncthreads();
    if (j < 32) {
        float o = ldf(bd2, j, fp32);
        for (int k = 0; k < 64; ++k) o += dh[k] * ldf(Wd2, k * 32 + j, fp32);
        if (fp32) ((float*)out)[g * 32 + j] = o;
        else      ((bf16*)out)[g * 32 + j] = __float2bfloat16(o);
    }
}

extern "C" void kernel_launch(void* const* d_in, const int* in_sizes, int n_in,
                              void* d_out, int out_size, void* d_ws, size_t ws_size,
                              hipStream_t stream) {
    (void)in_sizes; (void)n_in; (void)out_size; (void)ws_size;
    const void* prot = d_in[0];
    const void* sp   = d_in[1];
    const void* lri  = d_in[2];
    const void* eidx = d_in[3];
    const void* batch= d_in[4];
    const void* W1   = d_in[5];
    const void* as1  = d_in[6];
    const void* ad1  = d_in[7];
    const void* b1   = d_in[8];
    const void* W2   = d_in[9];
    const void* as2  = d_in[10];
    const void* ad2  = d_in[11];
    const void* b2v  = d_in[12];
    const void* Wd1  = d_in[13];
    const void* bd1  = d_in[14];
    const void* Wd2  = d_in[15];
    const void* bd2  = d_in[16];

    char* w = (char*)d_ws;
    auto alloc = [&](size_t bytes) -> void* {
        char* p = w;
        w += (bytes + 255) & ~(size_t)255;
        return (void*)p;
    };
    int*   flags     = (int*)alloc(2 * 4);
    // --- contiguous memset region: pooled .. scnt ---
    float* pooled    = (float*)alloc((size_t)POOL_REP * NUM_GRAPHSC * 64 * 4);
    float* counts    = (float*)alloc((size_t)POOL_REP * NUM_GRAPHSC * 4);
    int*   scnt      = (int*)alloc((size_t)NSB * 4);
    char*  zero_end  = w;
    // -------------------------------------------------
    int*   batch32   = (int*)alloc((size_t)N_NODESC * 4);
    int*   row_start = (int*)alloc((size_t)(N_NODESC + 1) * 4);
    unsigned* bucket2= (unsigned*)alloc((size_t)NSB * SBCAP * 4);
    unsigned short* col = (unsigned short*)alloc((size_t)N_EDGESC * 2);
    short* w1f       = (short*)alloc((size_t)16384 * 2);
    float* w1r       = (float*)alloc((size_t)256 * 4);
    short* w2f       = (short*)alloc((size_t)8192 * 2);
    short* xph0      = (short*)alloc((size_t)N_NODESC * 64 * 2);
    short* xph1      = (short*)alloc((size_t)N_NODESC * 64 * 2);
    float* alsrc1    = (float*)alloc((size_t)N_NODESC * 2 * 4);
    float* aldst1    = (float*)alloc((size_t)N_NODESC * 2 * 4);
    short* h1b       = (short*)alloc((size_t)N_NODESC * 128 * 2);
    short* xp2b      = (short*)alloc((size_t)N_NODESC * 64 * 2);
    float* alsrc2    = (float*)alloc((size_t)N_NODESC * 4);
    float* aldst2    = (float*)alloc((size_t)N_NODESC * 4);

    const int nbat = (N_NODESC + 255) / 256;
    const size_t zero_bytes = (size_t)(zero_end - (char*)pooled);

    hipMemsetAsync(pooled, 0, zero_bytes, stream);
    mega_k<<<NPART + 97 + nbat, 256, 0, stream>>>(eidx, prot, batch, W1, W2, flags,
                                                  w1f, w1r, w2f, batch32, scnt,
                                                  bucket2, nbat);
    const int nblk = (N_NODESC + 31) / 32;
    csrgemm1_k<<<NSB + nblk, 256, 0, stream>>>(bucket2, scnt, row_start, col,
                                               prot, sp, lri, w1f, w1r, as1, ad1,
                                               flags, xph0, xph1, alsrc1, aldst1);
    agg1s_k<<<2 * AGG_NB, 256, 0, stream>>>(row_start, col, xph0, xph1,
                                            alsrc1, aldst1, b1, flags,
                                            (unsigned*)h1b);
    gemm2_k<<<nblk, 256, 0, stream>>>((const unsigned*)h1b, w2f, as2, ad2, flags,
                                      xp2b, alsrc2, aldst2);
    agg2p_k<<<AGG_NB, 256, 0, stream>>>(row_start, col, xp2b, alsrc2, aldst2,
                                        b2v, flags, batch32, pooled, counts);
    dec_k<<<NUM_GRAPHSC, 64, 0, stream>>>(pooled, counts, Wd1, bd1, Wd2, bd2, flags, d_out);
}

// Round 12
// 274.659 us; speedup vs baseline: 1.5199x; 1.0239x over previous
//
#include <hip/hip_runtime.h>
#include <hip/hip_bf16.h>

#define N_NODESC 50000
#define N_EDGESC 1600000
#define NUM_GRAPHSC 64
#define P_EPB 2048            // edges per block in part path
#define NPART ((N_EDGESC + P_EPB - 1) / P_EPB)   // 782
#define SUBW 196              // nodes per sub-bucket (256 buckets cover 50000)
#define NSB 256               // number of sub-buckets
#define SBCAP 8192            // per-sub-bucket capacity (avg 6250, max ~6600)
#define POOL_REP 32           // pooled replicas to kill atomic contention
#define AGG_NB 6250           // 50000 / 8 nodes per block (split-wave)

typedef __hip_bfloat16 bf16;
typedef short short8 __attribute__((ext_vector_type(8)));
typedef float floatx4 __attribute__((ext_vector_type(4)));

__device__ __forceinline__ float ldf(const void* p, long i, int fp32) {
    return fp32 ? ((const float*)p)[i] : __bfloat162float(((const bf16*)p)[i]);
}
__device__ __forceinline__ short f2s(float v) {
    bf16 h = __float2bfloat16(v);
    return *(short*)&h;
}
__device__ __forceinline__ unsigned pack2(float lo, float hi) {
    bf16 a = __float2bfloat16(lo), b = __float2bfloat16(hi);
    unsigned ua = *(unsigned short*)&a, ub = *(unsigned short*)&b;
    return (ub << 16) | ua;
}
__device__ __forceinline__ float ulo(unsigned u) { return __uint_as_float(u << 16); }
__device__ __forceinline__ float uhi(unsigned u) { return __uint_as_float(u & 0xffff0000u); }

// ---------------- inline dtype detection (per-block, ~100 loads) ----------------
__device__ __forceinline__ int detect_fp32_dev(const void* prot) {
    const bf16* pb = (const bf16*)prot;
    int sane = 0;
    for (int i = 0; i < 64; ++i) {
        float a = fabsf(__bfloat162float(pb[2 * i]));
        if (a > 1e-8f && a < 1e4f) sane++;
    }
    return (sane >= 48) ? 0 : 1;
}
__device__ __forceinline__ int detect_i64_dev(const void* eidx) {
    const unsigned* u = (const unsigned*)eidx;
    int zhi = 0;
    for (int i = 0; i < 32; ++i)
        if (u[2 * i + 1] == 0u) zhi++;
    return (zhi >= 30) ? 1 : 0;
}

// ---------------- mega: edge partition ∥ weight prep ∥ batch cvt (one launch) ----------------
__global__ __launch_bounds__(256) void mega_k(const void* __restrict__ eidx,
                                              const void* __restrict__ prot,
                                              const void* __restrict__ batch,
                                              const void* __restrict__ W1,
                                              const void* __restrict__ W2,
                                              int* __restrict__ flags,
                                              short* __restrict__ w1f,
                                              float* __restrict__ w1r,
                                              short* __restrict__ w2f,
                                              int* __restrict__ b32,
                                              int* __restrict__ scnt,
                                              unsigned* __restrict__ bucket2,
                                              int nbat) {
    const int b = blockIdx.x, tid = threadIdx.x;
    __shared__ int cnt[NSB];
    __shared__ int sc[NSB];
    __shared__ int gbase[NSB];
    __shared__ int cur[NSB];
    __shared__ unsigned buf[P_EPB];
    __shared__ int sflag;

    if (b < NPART) {
        // ---- edge partition path ----
        if (tid == 0) sflag = detect_i64_dev(eidx);
        cnt[tid] = 0;
        __syncthreads();
        const int i64f = sflag;
        const long e0 = (long)b * P_EPB;
        unsigned ev[8];
        int bk[8];
        #pragma unroll
        for (int i = 0; i < 8; ++i) {
            long e = e0 + i * 256 + tid;
            bk[i] = -1;
            if (e < N_EDGESC) {
                int s, d;
                if (i64f) {
                    s = (int)((const long long*)eidx)[e];
                    d = (int)((const long long*)eidx)[N_EDGESC + e];
                } else {
                    s = ((const int*)eidx)[e];
                    d = ((const int*)eidx)[N_EDGESC + e];
                }
                int sub = (d >> 2) / 49;             // = d / 196 exact
                bk[i] = sub;
                ev[i] = (unsigned)s | ((unsigned)(d - sub * SUBW) << 16)
                                    | ((unsigned)sub << 24);
                atomicAdd(&cnt[sub], 1);
            }
        }
        __syncthreads();
        const int myc = cnt[tid];
        sc[tid] = myc;
        __syncthreads();
        #pragma unroll
        for (int off = 1; off < NSB; off <<= 1) {
            int t = (tid >= off) ? sc[tid - off] : 0;
            __syncthreads();
            sc[tid] += t;
            __syncthreads();
        }
        cnt[tid] = sc[tid] - myc;                    // exclusive prefix
        gbase[tid] = myc ? atomicAdd(&scnt[tid], myc) : 0;
        cur[tid] = sc[tid] - myc;
        __syncthreads();
        #pragma unroll
        for (int i = 0; i < 8; ++i) {
            if (bk[i] >= 0) {
                int p = atomicAdd(&cur[bk[i]], 1);
                buf[p] = ev[i];
            }
        }
        __syncthreads();
        const int total = sc[NSB - 1];
        for (int p = tid; p < total; p += 256) {
            unsigned v = buf[p];
            int lo = (int)(v >> 24);
            bucket2[(long)lo * SBCAP + gbase[lo] + (p - cnt[lo])] = v & 0xffffffu;
        }
        return;
    }
    const int wb = b - NPART;
    if (wb < 97) {
        if (tid == 0) {
            sflag = detect_fp32_dev(prot);
            if (wb == 0) {                           // publish flags for later kernels
                flags[0] = sflag;
                flags[1] = detect_i64_dev(eidx);
            }
        }
        __syncthreads();
        const int fp32 = sflag;
        if (wb < 64) {
            int idx = wb * 256 + tid;                // 16384
            int kp = idx >> 7, n = idx & 127;
            int krow = kp < 64 ? kp : 66 + (kp - 64);
            float v = ldf(W1, (long)krow * 128 + n, fp32);
            int c = n >> 4, nn = n & 15, t = kp >> 5, q = (kp >> 3) & 3, j = kp & 7;
            w1f[(((c * 4 + t) * 4 + q) * 16 + nn) * 8 + j] = f2s(v);
        } else if (wb == 64) {
            int which = tid >> 7, n = tid & 127;     // W1 rows 64,65 (spatial)
            w1r[which * 128 + n] = ldf(W1, (long)(64 + which) * 128 + n, fp32);
        } else {
            int idx = (wb - 65) * 256 + tid;         // 8192
            int k = idx >> 6, n = idx & 63;
            float v = ldf(W2, (long)k * 64 + n, fp32);
            int c = n >> 4, nn = n & 15, t = k >> 5, q = (k >> 3) & 3, j = k & 7;
            w2f[(((c * 4 + t) * 4 + q) * 16 + nn) * 8 + j] = f2s(v);
        }
        return;
    }
    // ---- batch cvt path ----
    if (tid == 0) sflag = detect_i64_dev(eidx);
    __syncthreads();
    const int i64f = sflag;
    int i = (wb - 97) * 256 + tid;
    if (i < N_NODESC)
        b32[i] = i64f ? (int)((const long long*)batch)[i] : ((const int*)batch)[i];
    (void)nbat;
}

// ---------------- csr ∥ gemm1 (one launch, NO cross-block sync) ----------------
// Blocks [0,NSB): CSR build. Bucket-level prefix computed per-block by a masked
// reduction over scnt[0..sb) — scnt is final after mega_k, so no lookback/spin.
// Blocks [NSB, NSB+nblk): layer-1 MFMA GEMM + fused logits.
__global__ __launch_bounds__(256) void csrgemm1_k(
        const unsigned* __restrict__ bucket2, const int* __restrict__ scnt,
        int* __restrict__ row_start, unsigned short* __restrict__ col,
        const void* __restrict__ prot, const void* __restrict__ sp,
        const void* __restrict__ lri,
        const short* __restrict__ w1f, const float* __restrict__ w1r,
        const void* __restrict__ as1, const void* __restrict__ ad1,
        const int* __restrict__ flags,
        short* __restrict__ xph0, short* __restrict__ xph1,
        float* __restrict__ alsrc, float* __restrict__ aldst) {
    const int tid = threadIdx.x;
    __shared__ int lh[SUBW];
    __shared__ int sc[256];
    __shared__ int ws[4];
    __shared__ __align__(16) short xs[32][136];
    __shared__ float xsp[32][2];
    __shared__ float sredc[32][8], dredc[32][8];

    if (blockIdx.x < NSB) {
        // ---- CSR path ----
        const int sb = blockIdx.x;
        const int lane = tid & 63;
        const int cnt = scnt[sb];
        const unsigned* B = bucket2 + (long)sb * SBCAP;
        const int nodebase = sb * SUBW;
        const int width = min(SUBW, N_NODESC - nodebase);
        // bucket-level prefix: sum scnt[0..sb) via block reduction (no spin)
        int v = (tid < sb) ? scnt[tid] : 0;
        #pragma unroll
        for (int off = 32; off; off >>= 1) v += __shfl_xor(v, off, 64);
        if (lane == 0) ws[tid >> 6] = v;
        for (int i = tid; i < SUBW; i += 256) lh[i] = 0;
        __syncthreads();
        const int sprefix = ws[0] + ws[1] + ws[2] + ws[3];
        for (int e = tid; e < cnt; e += 256) atomicAdd(&lh[B[e] >> 16], 1);
        __syncthreads();
        const int myc = (tid < SUBW) ? lh[tid] : 0;
        sc[tid] = myc;
        __syncthreads();
        for (int off = 1; off < 256; off <<= 1) {
            int t = (tid >= off) ? sc[tid - off] : 0;
            __syncthreads();
            sc[tid] += t;
            __syncthreads();
        }
        if (tid < width) row_start[nodebase + tid] = sprefix + sc[tid] - myc;
        if (sb == NSB - 1 && tid == 0) row_start[N_NODESC] = N_EDGESC;
        if (tid < SUBW) lh[tid] = sprefix + sc[tid] - myc;   // cursor
        __syncthreads();
        for (int e = tid; e < cnt; e += 256) {
            unsigned vv = B[e];
            int pos = atomicAdd(&lh[vv >> 16], 1);
            col[pos] = (unsigned short)(vv & 0xffffu);
        }
        return;
    }

    // ---- gemm1 path ----
    const int fp32 = flags[0];
    const int nb = (blockIdx.x - NSB) * 32;
    if (!fp32) {
        #pragma unroll
        for (int i = 0; i < 2; ++i) {
            int cidx = i * 256 + tid;
            int r = cidx >> 4, cc = cidx & 15;
            int g = nb + r;
            short8 v = (short8){0, 0, 0, 0, 0, 0, 0, 0};
            if (g < N_NODESC) {
                const short* srcp = (cc < 8)
                    ? (const short*)prot + (long)g * 64 + cc * 8
                    : (const short*)lri + (long)g * 64 + (cc - 8) * 8;
                v = *(const short8*)srcp;
            }
            *(short8*)&xs[r][cc * 8] = v;
        }
    } else {
        #pragma unroll
        for (int i = 0; i < 16; ++i) {
            int idx = i * 256 + tid;
            int r = idx >> 7, k = idx & 127;
            int g = nb + r;
            float v = 0.f;
            if (g < N_NODESC)
                v = (k < 64) ? ((const float*)prot)[(long)g * 64 + k]
                             : ((const float*)lri)[(long)g * 64 + (k - 64)];
            xs[r][k] = f2s(v);
        }
    }
    if (tid < 64) {
        int r = tid >> 1, which = tid & 1;
        int g = nb + r;
        xsp[r][which] = (g < N_NODESC) ? ldf(sp, (long)g * 2 + which, fp32) : 0.f;
    }
    __syncthreads();

    const int wid = tid >> 6, lane = tid & 63;
    const int quad = lane >> 4, l16 = lane & 15;
    floatx4 acc[2][2];
    #pragma unroll
    for (int a = 0; a < 2; ++a)
        #pragma unroll
        for (int bb = 0; bb < 2; ++bb) acc[a][bb] = (floatx4){0.f, 0.f, 0.f, 0.f};

    const int c0 = 2 * wid;
    #pragma unroll
    for (int t = 0; t < 4; ++t) {
        short8 a0 = *(const short8*)&xs[l16][t * 32 + quad * 8];
        short8 a1 = *(const short8*)&xs[16 + l16][t * 32 + quad * 8];
        short8 b0 = *(const short8*)&w1f[(((c0 * 4 + t) * 4 + quad) * 16 + l16) * 8];
        short8 b1 = *(const short8*)&w1f[((((c0 + 1) * 4 + t) * 4 + quad) * 16 + l16) * 8];
        acc[0][0] = __builtin_amdgcn_mfma_f32_16x16x32_bf16(a0, b0, acc[0][0], 0, 0, 0);
        acc[0][1] = __builtin_amdgcn_mfma_f32_16x16x32_bf16(a0, b1, acc[0][1], 0, 0, 0);
        acc[1][0] = __builtin_amdgcn_mfma_f32_16x16x32_bf16(a1, b0, acc[1][0], 0, 0, 0);
        acc[1][1] = __builtin_amdgcn_mfma_f32_16x16x32_bf16(a1, b1, acc[1][1], 0, 0, 0);
    }
    #pragma unroll
    for (int ci = 0; ci < 2; ++ci) {
        int colg = (c0 + ci) * 16 + l16;
        float w0 = w1r[colg], w1v = w1r[128 + colg];
        float asv = ldf(as1, colg, fp32), adv = ldf(ad1, colg, fp32);
        short* xpd = (colg < 64) ? xph0 : xph1;
        const int cc = colg & 63;
        #pragma unroll
        for (int rt = 0; rt < 2; ++rt) {
            float sv[4], dv[4];
            #pragma unroll
            for (int reg = 0; reg < 4; ++reg) {
                int row = rt * 16 + quad * 4 + reg;
                int g = nb + row;
                float v = acc[rt][ci][reg] + xsp[row][0] * w0 + xsp[row][1] * w1v;
                if (g < N_NODESC) xpd[(long)g * 64 + cc] = f2s(v);
                sv[reg] = v * asv;
                dv[reg] = v * adv;
            }
            #pragma unroll
            for (int off = 1; off < 16; off <<= 1) {
                #pragma unroll
                for (int reg = 0; reg < 4; ++reg) {
                    sv[reg] += __shfl_xor(sv[reg], off, 64);
                    dv[reg] += __shfl_xor(dv[reg], off, 64);
                }
            }
            if (l16 == 0) {
                #pragma unroll
                for (int reg = 0; reg < 4; ++reg) {
                    int row = rt * 16 + quad * 4 + reg;
                    sredc[row][c0 + ci] = sv[reg];
                    dredc[row][c0 + ci] = dv[reg];
                }
            }
        }
    }
    __syncthreads();
    if (tid < 64) {
        int r = tid >> 1, h = tid & 1;
        int g = nb + r;
        if (g < N_NODESC) {
            alsrc[(long)h * N_NODESC + g] = sredc[r][4 * h] + sredc[r][4 * h + 1] +
                                            sredc[r][4 * h + 2] + sredc[r][4 * h + 3];
            aldst[(long)h * N_NODESC + g] = dredc[r][4 * h] + dredc[r][4 * h + 1] +
                                            dredc[r][4 * h + 2] + dredc[r][4 * h + 3];
        }
    }
}

// ---------------- Layer 1 aggregation: split-wave, both heads in one launch ----------------

__global__ __launch_bounds__(256) void agg1s_k(
        const int* __restrict__ row_start, const unsigned short* __restrict__ col,
        const short* __restrict__ xph0, const short* __restrict__ xph1,
        const float* __restrict__ als, const float* __restrict__ ald,
        const void* __restrict__ b1, const int* __restrict__ flags,
        unsigned* __restrict__ h1b32) {
    const int fp32 = flags[0];
    const int tid = threadIdx.x;
    const int wid = tid >> 6;
    const int lane = tid & 63;
    const int hw = lane >> 5;         // half-wave = node parity
    const int hl = lane & 31;
    const int head = blockIdx.x >= AGG_NB;
    const int b = blockIdx.x - head * AGG_NB;
    const int n = b * 8 + wid * 2 + hw;
    __shared__ float2 pbuf[4][2][32];
    float2* mybuf = pbuf[wid][hw];
    const short* xph = head ? xph1 : xph0;
    const float* alsh = als + (long)head * N_NODESC;
    const float* aldh = ald + (long)head * N_NODESC;
    const int e = hl >> 3;
    const int c = hl & 7;
    const char* xpb = (const char*)xph;
    const int c16 = c * 16;
    const float ad = aldh[n];
    float e0 = alsh[n] + ad;
    e0 = e0 > 0.f ? e0 : 0.2f * e0;
    const float pself = __expf(e0);
    const float pinit = e == 0 ? pself : 0.f;
    uint4 us = *(const uint4*)(xpb + (long)n * 128 + c16);
    float acc0 = pinit * ulo(us.x), acc1 = pinit * uhi(us.x);
    float acc2 = pinit * ulo(us.y), acc3 = pinit * uhi(us.y);
    float acc4 = pinit * ulo(us.z), acc5 = pinit * uhi(us.z);
    float acc6 = pinit * ulo(us.w), acc7 = pinit * uhi(us.w);
    float lp = 0.f;
    const int beg = row_start[n], end = row_start[n + 1];
    for (int base = beg; base < end; base += 32) {
        const int idx = base + hl;
        int s = 0;
        float p = 0.f;
        if (idx < end) {
            s = (int)col[idx];
            float t = alsh[s] + ad;
            t = t > 0.f ? t : 0.2f * t;
            p = __expf(t);
        }
        lp += p;
        mybuf[hl] = make_float2(p, __int_as_float(s << 7));
        int cnt = end - base; if (cnt > 32) cnt = 32;
        int quads = (cnt + 3) >> 2;
        int j = 0;
        for (; j + 4 <= quads; j += 4) {
            int a4[4]; float p4[4]; uint4 x[4];
            #pragma unroll
            for (int q = 0; q < 4; ++q) {
                float2 bv = mybuf[4 * (j + q) + e];
                a4[q] = __float_as_int(bv.y);
                p4[q] = bv.x;
            }
            #pragma unroll
            for (int q = 0; q < 4; ++q)
                x[q] = *(const uint4*)(xpb + a4[q] + c16);
            #pragma unroll
            for (int q = 0; q < 4; ++q) {
                acc0 = fmaf(p4[q], ulo(x[q].x), acc0);
                acc1 = fmaf(p4[q], uhi(x[q].x), acc1);
                acc2 = fmaf(p4[q], ulo(x[q].y), acc2);
                acc3 = fmaf(p4[q], uhi(x[q].y), acc3);
                acc4 = fmaf(p4[q], ulo(x[q].z), acc4);
                acc5 = fmaf(p4[q], uhi(x[q].z), acc5);
                acc6 = fmaf(p4[q], ulo(x[q].w), acc6);
                acc7 = fmaf(p4[q], uhi(x[q].w), acc7);
            }
        }
        for (; j < quads; ++j) {
            float2 bv = mybuf[4 * j + e];
            uint4 x = *(const uint4*)(xpb + __float_as_int(bv.y) + c16);
            float pv = bv.x;
            acc0 = fmaf(pv, ulo(x.x), acc0);
            acc1 = fmaf(pv, uhi(x.x), acc1);
            acc2 = fmaf(pv, ulo(x.y), acc2);
            acc3 = fmaf(pv, uhi(x.y), acc3);
            acc4 = fmaf(pv, ulo(x.z), acc4);
            acc5 = fmaf(pv, uhi(x.z), acc5);
            acc6 = fmaf(pv, ulo(x.w), acc6);
            acc7 = fmaf(pv, uhi(x.w), acc7);
        }
    }
    #pragma unroll
    for (int off = 16; off; off >>= 1) lp += __shfl_xor(lp, off, 64);
    #pragma unroll
    for (int off = 8; off <= 16; off <<= 1) {
        acc0 += __shfl_xor(acc0, off, 64);
        acc1 += __shfl_xor(acc1, off, 64);
        acc2 += __shfl_xor(acc2, off, 64);
        acc3 += __shfl_xor(acc3, off, 64);
        acc4 += __shfl_xor(acc4, off, 64);
        acc5 += __shfl_xor(acc5, off, 64);
        acc6 += __shfl_xor(acc6, off, 64);
        acc7 += __shfl_xor(acc7, off, 64);
    }
    if (hl < 8) {
        const float rl = 1.f / (lp + pself);
        const long bb = (long)head * 64 + 8 * c;
        float o0 = acc0 * rl + ldf(b1, bb + 0, fp32);
        float o1 = acc1 * rl + ldf(b1, bb + 1, fp32);
        float o2 = acc2 * rl + ldf(b1, bb + 2, fp32);
        float o3 = acc3 * rl + ldf(b1, bb + 3, fp32);
        float o4 = acc4 * rl + ldf(b1, bb + 4, fp32);
        float o5 = acc5 * rl + ldf(b1, bb + 5, fp32);
        float o6 = acc6 * rl + ldf(b1, bb + 6, fp32);
        float o7 = acc7 * rl + ldf(b1, bb + 7, fp32);
        uint4 o;
        o.x = pack2(o0, o1); o.y = pack2(o2, o3);
        o.z = pack2(o4, o5); o.w = pack2(o6, o7);
        *(uint4*)((char*)h1b32 + (long)n * 256 + head * 128 + c16) = o;
    }
}

// ---------------- Layer 2 GEMM via MFMA + fused logits (shuffle reduce) ----------------

__global__ __launch_bounds__(256) void gemm2_k(
        const unsigned* __restrict__ h1b32, const short* __restrict__ w2f,
        const void* __restrict__ as2, const void* __restrict__ ad2,
        const int* __restrict__ flags,
        short* __restrict__ xp2b, float* __restrict__ alsrc, float* __restrict__ aldst) {
    const int fp32 = flags[0];
    const int tid = threadIdx.x;
    const int nb = blockIdx.x * 32;
    __shared__ __align__(16) short xs[32][136];
    __shared__ float sredc[32][4], dredc[32][4];

    #pragma unroll
    for (int i = 0; i < 8; ++i) {
        int idx = i * 256 + tid;
        int r = idx >> 6, ii = idx & 63;
        int g = nb + r;
        unsigned val = (g < N_NODESC) ? h1b32[(long)g * 64 + ii] : 0u;
        ((unsigned*)&xs[r][0])[ii] = val;
    }
    __syncthreads();

    const int wid = tid >> 6, lane = tid & 63;
    const int quad = lane >> 4, l16 = lane & 15;
    floatx4 acc0 = (floatx4){0.f, 0.f, 0.f, 0.f};
    floatx4 acc1 = (floatx4){0.f, 0.f, 0.f, 0.f};
    #pragma unroll
    for (int t = 0; t < 4; ++t) {
        short8 a0 = *(const short8*)&xs[l16][t * 32 + quad * 8];
        short8 a1 = *(const short8*)&xs[16 + l16][t * 32 + quad * 8];
        short8 b = *(const short8*)&w2f[(((wid * 4 + t) * 4 + quad) * 16 + l16) * 8];
        acc0 = __builtin_amdgcn_mfma_f32_16x16x32_bf16(a0, b, acc0, 0, 0, 0);
        acc1 = __builtin_amdgcn_mfma_f32_16x16x32_bf16(a1, b, acc1, 0, 0, 0);
    }
    const int colg = wid * 16 + l16;
    const float asv = ldf(as2, colg, fp32), adv = ldf(ad2, colg, fp32);
    float sv0[4], dv0[4], sv1[4], dv1[4];
    #pragma unroll
    for (int reg = 0; reg < 4; ++reg) {
        int r0 = quad * 4 + reg;
        int g0 = nb + r0;
        int g1 = g0 + 16;
        if (g0 < N_NODESC) xp2b[(long)g0 * 64 + colg] = f2s(acc0[reg]);
        if (g1 < N_NODESC) xp2b[(long)g1 * 64 + colg] = f2s(acc1[reg]);
        sv0[reg] = acc0[reg] * asv; dv0[reg] = acc0[reg] * adv;
        sv1[reg] = acc1[reg] * asv; dv1[reg] = acc1[reg] * adv;
    }
    #pragma unroll
    for (int off = 1; off < 16; off <<= 1) {
        #pragma unroll
        for (int reg = 0; reg < 4; ++reg) {
            sv0[reg] += __shfl_xor(sv0[reg], off, 64);
            dv0[reg] += __shfl_xor(dv0[reg], off, 64);
            sv1[reg] += __shfl_xor(sv1[reg], off, 64);
            dv1[reg] += __shfl_xor(dv1[reg], off, 64);
        }
    }
    if (l16 == 0) {
        #pragma unroll
        for (int reg = 0; reg < 4; ++reg) {
            int r0 = quad * 4 + reg;
            sredc[r0][wid] = sv0[reg];      dredc[r0][wid] = dv0[reg];
            sredc[r0 + 16][wid] = sv1[reg]; dredc[r0 + 16][wid] = dv1[reg];
        }
    }
    __syncthreads();
    if (tid < 32) {
        int g = nb + tid;
        if (g < N_NODESC) {
            alsrc[g] = sredc[tid][0] + sredc[tid][1] + sredc[tid][2] + sredc[tid][3];
            aldst[g] = dredc[tid][0] + dredc[tid][1] + dredc[tid][2] + dredc[tid][3];
        }
    }
}

// ---------------- Layer 2 aggregation: split-wave + fused mean-pool (replicated) ----------------

__global__ __launch_bounds__(256) void agg2p_k(
        const int* __restrict__ row_start, const unsigned short* __restrict__ col,
        const short* __restrict__ xp2b, const float* __restrict__ alsrc,
        const float* __restrict__ aldst, const void* __restrict__ b2v,
        const int* __restrict__ flags, const int* __restrict__ batch32,
        float* __restrict__ pooled, float* __restrict__ counts) {
    const int fp32 = flags[0];
    const int tid = threadIdx.x;
    const int wid = tid >> 6;
    const int lane = tid & 63;
    const int hw = lane >> 5;
    const int hl = lane & 31;
    const int n = blockIdx.x * 8 + wid * 2 + hw;
    const int rep = blockIdx.x & (POOL_REP - 1);
    __shared__ float2 pbuf[4][2][32];
    __shared__ float psum[64];
    __shared__ int ginfo[2];
    if (tid < 64) psum[tid] = 0.f;
    if (tid == 0) {
        int g0 = batch32[blockIdx.x * 8];
        int g7 = batch32[blockIdx.x * 8 + 7];
        ginfo[0] = g0;
        ginfo[1] = (g0 == g7);
    }
    __syncthreads();
    float2* mybuf = pbuf[wid][hw];
    const int e = hl >> 3;
    const int c = hl & 7;
    const char* xpb = (const char*)xp2b;
    const int c16 = c * 16;
    const float ad = aldst[n];
    float e0 = alsrc[n] + ad;
    e0 = e0 > 0.f ? e0 : 0.2f * e0;
    const float pself = __expf(e0);
    const float pinit = e == 0 ? pself : 0.f;
    uint4 us = *(const uint4*)(xpb + (long)n * 128 + c16);
    float acc0 = pinit * ulo(us.x), acc1 = pinit * uhi(us.x);
    float acc2 = pinit * ulo(us.y), acc3 = pinit * uhi(us.y);
    float acc4 = pinit * ulo(us.z), acc5 = pinit * uhi(us.z);
    float acc6 = pinit * ulo(us.w), acc7 = pinit * uhi(us.w);
    float lp = 0.f;
    const int beg = row_start[n], end = row_start[n + 1];
    for (int base = beg; base < end; base += 32) {
        const int idx = base + hl;
        int s = 0;
        float p = 0.f;
        if (idx < end) {
            s = (int)col[idx];
            float t = alsrc[s] + ad;
            t = t > 0.f ? t : 0.2f * t;
            p = __expf(t);
        }
        lp += p;
        mybuf[hl] = make_float2(p, __int_as_float(s << 7));
        int cnt = end - base; if (cnt > 32) cnt = 32;
        int quads = (cnt + 3) >> 2;
        int j = 0;
        for (; j + 4 <= quads; j += 4) {
            int a4[4]; float p4[4]; uint4 x[4];
            #pragma unroll
            for (int q = 0; q < 4; ++q) {
                float2 bv = mybuf[4 * (j + q) + e];
                a4[q] = __float_as_int(bv.y);
                p4[q] = bv.x;
            }
            #pragma unroll
            for (int q = 0; q < 4; ++q)
                x[q] = *(const uint4*)(xpb + a4[q] + c16);
            #pragma unroll
            for (int q = 0; q < 4; ++q) {
                acc0 = fmaf(p4[q], ulo(x[q].x), acc0);
                acc1 = fmaf(p4[q], uhi(x[q].x), acc1);
                acc2 = fmaf(p4[q], ulo(x[q].y), acc2);
                acc3 = fmaf(p4[q], uhi(x[q].y), acc3);
                acc4 = fmaf(p4[q], ulo(x[q].z), acc4);
                acc5 = fmaf(p4[q], uhi(x[q].z), acc5);
                acc6 = fmaf(p4[q], ulo(x[q].w), acc6);
                acc7 = fmaf(p4[q], uhi(x[q].w), acc7);
            }
        }
        for (; j < quads; ++j) {
            float2 bv = mybuf[4 * j + e];
            uint4 x = *(const uint4*)(xpb + __float_as_int(bv.y) + c16);
            float pv = bv.x;
            acc0 = fmaf(pv, ulo(x.x), acc0);
            acc1 = fmaf(pv, uhi(x.x), acc1);
            acc2 = fmaf(pv, ulo(x.y), acc2);
            acc3 = fmaf(pv, uhi(x.y), acc3);
            acc4 = fmaf(pv, ulo(x.z), acc4);
            acc5 = fmaf(pv, uhi(x.z), acc5);
            acc6 = fmaf(pv, ulo(x.w), acc6);
            acc7 = fmaf(pv, uhi(x.w), acc7);
        }
    }
    #pragma unroll
    for (int off = 16; off; off >>= 1) lp += __shfl_xor(lp, off, 64);
    #pragma unroll
    for (int off = 8; off <= 16; off <<= 1) {
        acc0 += __shfl_xor(acc0, off, 64);
        acc1 += __shfl_xor(acc1, off, 64);
        acc2 += __shfl_xor(acc2, off, 64);
        acc3 += __shfl_xor(acc3, off, 64);
        acc4 += __shfl_xor(acc4, off, 64);
        acc5 += __shfl_xor(acc5, off, 64);
        acc6 += __shfl_xor(acc6, off, 64);
        acc7 += __shfl_xor(acc7, off, 64);
    }
    float o[8];
    if (hl < 8) {
        const float rl = 1.f / (lp + pself);
        o[0] = acc0 * rl + ldf(b2v, 8 * c + 0, fp32);
        o[1] = acc1 * rl + ldf(b2v, 8 * c + 1, fp32);
        o[2] = acc2 * rl + ldf(b2v, 8 * c + 2, fp32);
        o[3] = acc3 * rl + ldf(b2v, 8 * c + 3, fp32);
        o[4] = acc4 * rl + ldf(b2v, 8 * c + 4, fp32);
        o[5] = acc5 * rl + ldf(b2v, 8 * c + 5, fp32);
        o[6] = acc6 * rl + ldf(b2v, 8 * c + 6, fp32);
        o[7] = acc7 * rl + ldf(b2v, 8 * c + 7, fp32);
    }
    if (ginfo[1]) {
        if (hl < 8) {
            #pragma unroll
            for (int j = 0; j < 8; ++j) atomicAdd(&psum[8 * c + j], o[j]);
        }
        __syncthreads();
        if (tid < 64)
            atomicAdd(&pooled[((long)rep * NUM_GRAPHSC + ginfo[0]) * 64 + tid], psum[tid]);
        if (tid == 0) atomicAdd(&counts[rep * NUM_GRAPHSC + ginfo[0]], 8.f);
    } else {
        int g = batch32[n];
        if (hl < 8) {
            #pragma unroll
            for (int j = 0; j < 8; ++j)
                atomicAdd(&pooled[((long)rep * NUM_GRAPHSC + g) * 64 + 8 * c + j], o[j]);
        }
        if (hl == 0) atomicAdd(&counts[rep * NUM_GRAPHSC + g], 1.f);
    }
}

// ---------------- decoder MLP (sums pooled replicas) ----------------

__global__ __launch_bounds__(64) void dec_k(const float* __restrict__ pooled,
                                            const float* __restrict__ counts,
                                            const void* __restrict__ Wd1, const void* __restrict__ bd1,
                                            const void* __restrict__ Wd2, const void* __restrict__ bd2,
                                            const int* __restrict__ flags,
                                            void* __restrict__ out) {
    const int fp32 = flags[0];
    const int g = blockIdx.x, j = threadIdx.x;
    __shared__ float p[64], dh[64];
    float cnt = 0.f, ps = 0.f;
    #pragma unroll
    for (int r = 0; r < POOL_REP; ++r) {
        ps += pooled[((long)r * NUM_GRAPHSC + g) * 64 + j];
        if (j == 0) cnt += counts[r * NUM_GRAPHSC + g];
    }
    __shared__ float cnt_sh;
    if (j == 0) cnt_sh = cnt < 1.f ? 1.f : cnt;
    __syncthreads();
    p[j] = ps / cnt_sh;
    __syncthreads();
    float acc = ldf(bd1, j, fp32);
    for (int k = 0; k < 64; ++k) acc += p[k] * ldf(Wd1, k * 64 + j, fp32);
    dh[j] = acc > 0.f ? acc : 0.f;
    __syncthreads();
    if (j < 32) {
        float o = ldf(bd2, j, fp32);
        for (int k = 0; k < 64; ++k) o += dh[k] * ldf(Wd2, k * 32 + j, fp32);
        if (fp32) ((float*)out)[g * 32 + j] = o;
        else      ((bf16*)out)[g * 32 + j] = __float2bfloat16(o);
    }
}

extern "C" void kernel_launch(void* const* d_in, const int* in_sizes, int n_in,
                              void* d_out, int out_size, void* d_ws, size_t ws_size,
                              hipStream_t stream) {
    (void)in_sizes; (void)n_in; (void)out_size; (void)ws_size;
    const void* prot = d_in[0];
    const void* sp   = d_in[1];
    const void* lri  = d_in[2];
    const void* eidx = d_in[3];
    const void* batch= d_in[4];
    const void* W1   = d_in[5];
    const void* as1  = d_in[6];
    const void* ad1  = d_in[7];
    const void* b1   = d_in[8];
    const void* W2   = d_in[9];
    const void* as2  = d_in[10];
    const void* ad2  = d_in[11];
    const void* b2v  = d_in[12];
    const void* Wd1  = d_in[13];
    const void* bd1  = d_in[14];
    const void* Wd2  = d_in[15];
    const void* bd2  = d_in[16];

    char* w = (char*)d_ws;
    auto alloc = [&](size_t bytes) -> void* {
        char* p = w;
        w += (bytes + 255) & ~(size_t)255;
        return (void*)p;
    };
    int*   flags     = (int*)alloc(2 * 4);
    // --- contiguous memset region: pooled .. scnt ---
    float* pooled    = (float*)alloc((size_t)POOL_REP * NUM_GRAPHSC * 64 * 4);
    float* counts    = (float*)alloc((size_t)POOL_REP * NUM_GRAPHSC * 4);
    int*   scnt      = (int*)alloc((size_t)NSB * 4);
    char*  zero_end  = w;
    // -------------------------------------------------
    int*   batch32   = (int*)alloc((size_t)N_NODESC * 4);
    int*   row_start = (int*)alloc((size_t)(N_NODESC + 1) * 4);
    unsigned* bucket2= (unsigned*)alloc((size_t)NSB * SBCAP * 4);
    unsigned short* col = (unsigned short*)alloc((size_t)N_EDGESC * 2);
    short* w1f       = (short*)alloc((size_t)16384 * 2);
    float* w1r       = (float*)alloc((size_t)256 * 4);
    short* w2f       = (short*)alloc((size_t)8192 * 2);
    short* xph0      = (short*)alloc((size_t)N_NODESC * 64 * 2);
    short* xph1      = (short*)alloc((size_t)N_NODESC * 64 * 2);
    float* alsrc1    = (float*)alloc((size_t)N_NODESC * 2 * 4);
    float* aldst1    = (float*)alloc((size_t)N_NODESC * 2 * 4);
    short* h1b       = (short*)alloc((size_t)N_NODESC * 128 * 2);
    short* xp2b      = (short*)alloc((size_t)N_NODESC * 64 * 2);
    float* alsrc2    = (float*)alloc((size_t)N_NODESC * 4);
    float* aldst2    = (float*)alloc((size_t)N_NODESC * 4);

    const int nbat = (N_NODESC + 255) / 256;
    const size_t zero_bytes = (size_t)(zero_end - (char*)pooled);

    hipMemsetAsync(pooled, 0, zero_bytes, stream);
    mega_k<<<NPART + 97 + nbat, 256, 0, stream>>>(eidx, prot, batch, W1, W2, flags,
                                                  w1f, w1r, w2f, batch32, scnt,
                                                  bucket2, nbat);
    const int nblk = (N_NODESC + 31) / 32;
    csrgemm1_k<<<NSB + nblk, 256, 0, stream>>>(bucket2, scnt, row_start, col,
                                               prot, sp, lri, w1f, w1r, as1, ad1,
                                               flags, xph0, xph1, alsrc1, aldst1);
    agg1s_k<<<2 * AGG_NB, 256, 0, stream>>>(row_start, col, xph0, xph1,
                                            alsrc1, aldst1, b1, flags,
                                            (unsigned*)h1b);
    gemm2_k<<<nblk, 256, 0, stream>>>((const unsigned*)h1b, w2f, as2, ad2, flags,
                                      xp2b, alsrc2, aldst2);
    agg2p_k<<<AGG_NB, 256, 0, stream>>>(row_start, col, xp2b, alsrc2, aldst2,
                                        b2v, flags, batch32, pooled, counts);
    dec_k<<<NUM_GRAPHSC, 64, 0, stream>>>(pooled, counts, Wd1, bd1, Wd2, bd2, flags, d_out);
}